// Round 1
// baseline (774.430 us; speedup 1.0000x reference)
//
#include <hip/hip_runtime.h>
#include <hip/hip_bf16.h>
#include <string.h>
#include <stdint.h>

typedef __hip_bfloat16 bf16_t;
typedef float f32x4 __attribute__((ext_vector_type(4)));
typedef short bf16x8 __attribute__((ext_vector_type(8)));

#define AS_GLOBAL __attribute__((address_space(1)))
#define AS_LDS    __attribute__((address_space(3)))

static constexpr int Bn = 32, Ln = 4096, Cn = 64, Hn = 720, HPn = 768;
static constexpr float EPSf = 1e-5f;

// ---------------- workspace layout (bytes) ----------------
static constexpr size_t OFF_WT   = 0;                               // bf16 [2][768][4096]
static constexpr size_t SZ_WT    = (size_t)2 * HPn * Ln * 2;
static constexpr size_t OFF_ZT   = OFF_WT + SZ_WT;                  // bf16 [2][32][64][4096]
static constexpr size_t SZ_ZT    = (size_t)2 * Bn * Cn * Ln * 2;
static constexpr size_t OFF_OSR  = OFF_ZT + SZ_ZT;                  // f32 [2][32][720][64]
static constexpr size_t SZ_OSR   = (size_t)2 * Bn * Hn * Cn * 4;
static constexpr size_t OFF_M    = OFF_OSR + SZ_OSR;                // f32 [2][64][64]
static constexpr size_t OFF_CV   = OFF_M + 2 * 64 * 64 * 4;        // f32 [2][64]
static constexpr size_t OFF_S    = OFF_CV + 2 * 64 * 4;            // f32 [2][768]
static constexpr size_t OFF_MEAN = OFF_S + 2 * 768 * 4;            // f32 [32][64]
static constexpr size_t OFF_RSTD = OFF_MEAN + (size_t)Bn * Cn * 4;
static constexpr size_t OFF_STDV = OFF_RSTD + (size_t)Bn * Cn * 4;

static constexpr size_t OSR_PATH = (size_t)Bn * Hn * Cn;           // elements per path

// ---------------- kernel 1: fold the two 64->512->64 MLPs ----------------
__global__ void k_prep_small(const float* __restrict__ se_w, const float* __restrict__ sp_w,
                             const float* __restrict__ se_b, const float* __restrict__ sp_b,
                             const float* __restrict__ te_w, const float* __restrict__ tp_w,
                             const float* __restrict__ te_b, const float* __restrict__ tp_b,
                             float* __restrict__ M, float* __restrict__ cvec) {
  int p = blockIdx.x;
  const float* ew = p ? te_w : se_w;   // (64,512)
  const float* pw = p ? tp_w : sp_w;   // (512,64)
  const float* eb = p ? te_b : se_b;   // (512,)
  const float* pb = p ? tp_b : sp_b;   // (64,)
  int t = threadIdx.x;
  for (int idx = t; idx < 64 * 64; idx += blockDim.x) {
    int cp = idx >> 6, c = idx & 63;
    float s = 0.f;
    for (int d = 0; d < 512; ++d) s = fmaf(ew[cp * 512 + d], pw[d * 64 + c], s);
    M[p * 4096 + idx] = s;
  }
  if (t < 64) {
    float s = pb[t];
    for (int d = 0; d < 512; ++d) s = fmaf(eb[d], pw[d * 64 + t], s);
    cvec[p * 64 + t] = s;
  }
}

// ---------------- kernel 2: transpose tw -> Wt[h][l] bf16 (+colsum) ----------------
__global__ void k_wprep(const float* __restrict__ st_w, const float* __restrict__ tt_w,
                        bf16_t* __restrict__ Wt, float* __restrict__ S) {
  int p = blockIdx.z;
  const float* W = p ? tt_w : st_w;          // (4096, 720)
  int l0 = blockIdx.x * 64, h0 = blockIdx.y * 64;
  __shared__ float tile[64][65];
  int row = threadIdx.x >> 6, col = threadIdx.x & 63;
  int h = h0 + col;
  float partial = 0.f;
  for (int r = row; r < 64; r += 4) {
    float v = (h < Hn) ? W[(size_t)(l0 + r) * Hn + h] : 0.f;
    tile[r][col] = v;
    partial += v;
  }
  if (h < Hn) atomicAdd(&S[p * 768 + h], partial);
  __syncthreads();
  for (int a = row; a < 64; a += 4) {
    float v = tile[col][a];                  // transposed read (pad 65 -> no conflict)
    Wt[(size_t)(p * HPn + h0 + a) * Ln + l0 + col] = __float2bfloat16(v);
  }
}

// ---------------- kernel 3: per-(b,c) mean / std ----------------
__global__ void k_stats(const float* __restrict__ x, float* __restrict__ mean,
                        float* __restrict__ rstd, float* __restrict__ stdv) {
  int b = blockIdx.x;
  int t = threadIdx.x;
  int c4 = (t & 15) * 4, seg = t >> 4;       // 16 segs x 256 l each
  const float* xb = x + (size_t)b * Ln * Cn;
  float s0 = 0, s1 = 0, s2 = 0, s3 = 0, q0 = 0, q1 = 0, q2 = 0, q3 = 0;
#pragma unroll 4
  for (int i = 0; i < 256; ++i) {
    int l = seg * 256 + i;
    float4 v = *reinterpret_cast<const float4*>(xb + (size_t)l * Cn + c4);
    s0 += v.x; s1 += v.y; s2 += v.z; s3 += v.w;
    q0 = fmaf(v.x, v.x, q0); q1 = fmaf(v.y, v.y, q1);
    q2 = fmaf(v.z, v.z, q2); q3 = fmaf(v.w, v.w, q3);
  }
  __shared__ float rs[256][4];
  __shared__ float rq[256][4];
  rs[t][0] = s0; rs[t][1] = s1; rs[t][2] = s2; rs[t][3] = s3;
  rq[t][0] = q0; rq[t][1] = q1; rq[t][2] = q2; rq[t][3] = q3;
  __syncthreads();
  for (int off = 128; off >= 16; off >>= 1) {
    if (t < off) {
      for (int k = 0; k < 4; ++k) { rs[t][k] += rs[t + off][k]; rq[t][k] += rq[t + off][k]; }
    }
    __syncthreads();
  }
  if (t < 16) {
    for (int k = 0; k < 4; ++k) {
      int c = t * 4 + k;
      float m = rs[t][k] * (1.f / 4096.f);
      float var = rq[t][k] * (1.f / 4096.f) - m * m;
      float sd = sqrtf(var + EPSf);
      mean[b * Cn + c] = m;
      stdv[b * Cn + c] = sd;
      rstd[b * Cn + c] = 1.f / sd;
    }
  }
}

// ---------------- kernel 4: normalize + EMA scan + transposed bf16 dump ----------------
__global__ void __launch_bounds__(64) k_scan(const float* __restrict__ x, const float* __restrict__ alpha,
                                             const float* __restrict__ rev_w, const float* __restrict__ rev_b,
                                             const float* __restrict__ mean, const float* __restrict__ rstd,
                                             bf16_t* __restrict__ Zt) {
  int b = blockIdx.x, c = threadIdx.x;
  float mn = mean[b * Cn + c], rs = rstd[b * Cn + c];
  float w = rev_w[c], rb = rev_b[c];
  float a = 1.f / (1.f + expf(-alpha[c]));
  float k1 = 1.f - a;
  __shared__ unsigned tile[64][64];
  const float* xb = x + (size_t)b * Ln * Cn;
  bf16_t* zs = Zt + (size_t)b * Cn * Ln;                       // path 0: seasonal
  bf16_t* zt = Zt + (size_t)(Bn + b) * Cn * Ln;                // path 1: trend
  float tr = 0.f;
  for (int ch = 0; ch < 64; ++ch) {
#pragma unroll 4
    for (int j = 0; j < 64; ++j) {
      int l = ch * 64 + j;
      float xv = xb[(size_t)l * Cn + c];
      float xn = fmaf((xv - mn) * rs, w, rb);
      tr = (l == 0) ? xn : fmaf(a, tr, k1 * xn);
      float se = xn - tr;
      bf16_t hs = __float2bfloat16(se), ht = __float2bfloat16(tr);
      unsigned short us, ut;
      memcpy(&us, &hs, 2); memcpy(&ut, &ht, 2);
      tile[j][c ^ (j & 31)] = (unsigned)us | ((unsigned)ut << 16);   // XOR swizzle
    }
    __syncthreads();
    int jj = threadIdx.x;
    for (int cc = 0; cc < 64; ++cc) {
      unsigned v = tile[jj][cc ^ (jj & 31)];
      unsigned short us = (unsigned short)(v & 0xffff), ut = (unsigned short)(v >> 16);
      bf16_t hs, ht;
      memcpy(&hs, &us, 2); memcpy(&ht, &ut, 2);
      zs[(size_t)cc * Ln + ch * 64 + jj] = hs;                 // coalesced 128B / wave
      zt[(size_t)cc * Ln + ch * 64 + jj] = ht;
    }
    __syncthreads();
  }
}

// ---------------- kernel 5: bf16 MFMA GEMM  Osr[p,b,h,c] = sum_l Wt[p,h,l]*Zt[p,b,c,l] ----------------
__device__ __forceinline__ void gload16(const bf16_t* g, bf16_t* l) {
  __builtin_amdgcn_global_load_lds((const AS_GLOBAL uint32_t*)g, (AS_LDS uint32_t*)l, 16, 0, 0);
}

__global__ void __launch_bounds__(256) k_gemm(const bf16_t* __restrict__ Wt, const bf16_t* __restrict__ Zt,
                                              float* __restrict__ Osr) {
  int p = blockIdx.z;
  const bf16_t* A  = Wt + (size_t)p * HPn * Ln;      // [768][4096]
  const bf16_t* Bz = Zt + (size_t)p * (Bn * Cn) * Ln; // [2048][4096]
  int h0 = blockIdx.y * 128, n0 = blockIdx.x * 128;
  __shared__ __align__(16) bf16_t Al[128 * 32];
  __shared__ __align__(16) bf16_t Bl[128 * 32];
  int tid = threadIdx.x, wid = tid >> 6, lane = tid & 63;
  int wr = wid >> 1, wc = wid & 1;
  int srow = lane >> 2;              // 0..15
  int koff = (lane & 3) * 8;         // 0,8,16,24
  int fr = lane & 15, hi = lane >> 4;
  f32x4 acc[4][4];
#pragma unroll
  for (int i = 0; i < 4; ++i)
#pragma unroll
    for (int j = 0; j < 4; ++j) acc[i][j] = (f32x4){0.f, 0.f, 0.f, 0.f};

  for (int k0 = 0; k0 < Ln; k0 += 32) {
    __syncthreads();                 // prior ds_reads done before overwrite
#pragma unroll
    for (int j = 0; j < 2; ++j) {
      int blk = j * 4 + wid;         // 0..7 -> rows blk*16..+15
      int m = blk * 16 + srow;
      gload16(A  + (size_t)(h0 + m) * Ln + k0 + koff, &Al[blk * 512]);
      gload16(Bz + (size_t)(n0 + m) * Ln + k0 + koff, &Bl[blk * 512]);
    }
    __syncthreads();                 // drains vmcnt -> tile ready
    bf16x8 afr[4], bfr[4];
#pragma unroll
    for (int i = 0; i < 4; ++i)
      afr[i] = *reinterpret_cast<const bf16x8*>(&Al[(wr * 64 + i * 16 + fr) * 32 + hi * 8]);
#pragma unroll
    for (int i = 0; i < 4; ++i)
      bfr[i] = *reinterpret_cast<const bf16x8*>(&Bl[(wc * 64 + i * 16 + fr) * 32 + hi * 8]);
#pragma unroll
    for (int i = 0; i < 4; ++i)
#pragma unroll
      for (int j = 0; j < 4; ++j)
        acc[i][j] = __builtin_amdgcn_mfma_f32_16x16x32_bf16(afr[i], bfr[j], acc[i][j], 0, 0, 0);
  }

#pragma unroll
  for (int i = 0; i < 4; ++i) {
#pragma unroll
    for (int j = 0; j < 4; ++j) {
#pragma unroll
      for (int r = 0; r < 4; ++r) {
        int m = wr * 64 + i * 16 + hi * 4 + r;
        int h = h0 + m;
        if (h < Hn) {
          int n = n0 + wc * 64 + j * 16 + fr;
          int bidx = n >> 6, c = n & 63;
          Osr[(((size_t)p * Bn + bidx) * Hn + h) * Cn + c] = acc[i][j][r];
        }
      }
    }
  }
}

// ---------------- kernel 6: epilogue — apply M, biases, inverse RevIN ----------------
__global__ void __launch_bounds__(256) k_epi(const float* __restrict__ Osr, const float* __restrict__ M,
                                             const float* __restrict__ cvec, const float* __restrict__ S,
                                             const float* __restrict__ st_b, const float* __restrict__ tt_b,
                                             const float* __restrict__ rev_w, const float* __restrict__ rev_b,
                                             const float* __restrict__ mean, const float* __restrict__ stdv,
                                             float* __restrict__ out) {
  __shared__ float Msh[2][64][64];    // 32 KB
  __shared__ float rowS[4][64];
  __shared__ float rowT[4][64];
  int t = threadIdx.x;
  for (int i = t; i < 8192; i += 256) ((float*)Msh)[i] = M[i];
  int g = t >> 6, c = t & 63;
  float w = rev_w[c], rb = rev_b[c];
  float cs = cvec[c], ct = cvec[64 + c];
  int base = blockIdx.x * 16;
  for (int it = 0; it < 4; ++it) {
    int r = base + it * 4 + g;        // r = b*720 + h
    int b = r / 720, h = r % 720;
    __syncthreads();                  // also covers Msh load at it=0
    rowS[g][c] = Osr[((size_t)b * Hn + h) * Cn + c];
    rowT[g][c] = Osr[OSR_PATH + ((size_t)b * Hn + h) * Cn + c];
    __syncthreads();
    float acc = cs * S[h] + ct * S[768 + h] + st_b[h] + tt_b[h];
    for (int cp = 0; cp < 64; ++cp)
      acc = fmaf(rowS[g][cp], Msh[0][cp][c], fmaf(rowT[g][cp], Msh[1][cp][c], acc));
    float o = (acc - rb) / (w + EPSf) * stdv[b * Cn + c] + mean[b * Cn + c];
    out[(size_t)r * 64 + c] = o;
  }
}

// ---------------- launch ----------------
extern "C" void kernel_launch(void* const* d_in, const int* in_sizes, int n_in,
                              void* d_out, int out_size, void* d_ws, size_t ws_size,
                              hipStream_t stream) {
  const float* x     = (const float*)d_in[0];
  const float* alpha = (const float*)d_in[1];
  const float* rev_w = (const float*)d_in[2];
  const float* rev_b = (const float*)d_in[3];
  const float* se_w  = (const float*)d_in[4];
  const float* se_b  = (const float*)d_in[5];
  const float* sp_w  = (const float*)d_in[6];
  const float* sp_b  = (const float*)d_in[7];
  const float* st_w  = (const float*)d_in[8];
  const float* st_b  = (const float*)d_in[9];
  const float* te_w  = (const float*)d_in[10];
  const float* te_b  = (const float*)d_in[11];
  const float* tp_w  = (const float*)d_in[12];
  const float* tp_b  = (const float*)d_in[13];
  const float* tt_w  = (const float*)d_in[14];
  const float* tt_b  = (const float*)d_in[15];
  float* out = (float*)d_out;

  char* ws = (char*)d_ws;
  bf16_t* Wt   = (bf16_t*)(ws + OFF_WT);
  bf16_t* Zt   = (bf16_t*)(ws + OFF_ZT);
  float*  Osr  = (float*)(ws + OFF_OSR);
  float*  Mbuf = (float*)(ws + OFF_M);
  float*  cvec = (float*)(ws + OFF_CV);
  float*  S    = (float*)(ws + OFF_S);
  float*  mean = (float*)(ws + OFF_MEAN);
  float*  rstd = (float*)(ws + OFF_RSTD);
  float*  stdv = (float*)(ws + OFF_STDV);

  hipMemsetAsync(S, 0, 2 * 768 * 4, stream);

  k_prep_small<<<2, 256, 0, stream>>>(se_w, sp_w, se_b, sp_b, te_w, tp_w, te_b, tp_b, Mbuf, cvec);
  k_wprep<<<dim3(64, 12, 2), 256, 0, stream>>>(st_w, tt_w, Wt, S);
  k_stats<<<32, 256, 0, stream>>>(x, mean, rstd, stdv);
  k_scan<<<32, 64, 0, stream>>>(x, alpha, rev_w, rev_b, mean, rstd, Zt);
  k_gemm<<<dim3(16, 6, 2), 256, 0, stream>>>(Wt, Zt, Osr);
  k_epi<<<1440, 256, 0, stream>>>(Osr, Mbuf, cvec, S, st_b, tt_b, rev_w, rev_b, mean, stdv, out);
}

// Round 2
// 192.238 us; speedup vs baseline: 4.0285x; 4.0285x over previous
//
#include <hip/hip_runtime.h>
#include <hip/hip_bf16.h>
#include <string.h>
#include <stdint.h>

typedef __hip_bfloat16 bf16_t;
typedef float f32x4 __attribute__((ext_vector_type(4)));
typedef short bf16x8 __attribute__((ext_vector_type(8)));

#define AS_GLOBAL __attribute__((address_space(1)))
#define AS_LDS    __attribute__((address_space(3)))

static constexpr int Bn = 32, Ln = 4096, Cn = 64, Hn = 720, HPn = 768;
static constexpr float EPSf = 1e-5f;

static constexpr size_t OSR_SLICE = (size_t)Bn * Hn * Cn;   // f32 elements per K-slice per path

__device__ __forceinline__ short f2bf(float f) {
  bf16_t h = __float2bfloat16(f);
  unsigned short u; memcpy(&u, &h, 2);
  return (short)u;
}

// ---------------- kernel 1: fold the two 64->512->64 MLPs ----------------
__global__ void k_prep_small(const float* __restrict__ se_w, const float* __restrict__ sp_w,
                             const float* __restrict__ se_b, const float* __restrict__ sp_b,
                             const float* __restrict__ te_w, const float* __restrict__ tp_w,
                             const float* __restrict__ te_b, const float* __restrict__ tp_b,
                             float* __restrict__ M, float* __restrict__ cvec) {
  int p = blockIdx.x >> 4, sub = blockIdx.x & 15;
  const float* ew = p ? te_w : se_w;   // (64,512)
  const float* pw = p ? tp_w : sp_w;   // (512,64)
  const float* eb = p ? te_b : se_b;   // (512,)
  const float* pb = p ? tp_b : sp_b;   // (64,)
  int idx = sub * 256 + threadIdx.x;   // 0..4095
  int cp = idx >> 6, c = idx & 63;
  float s = 0.f;
  for (int d = 0; d < 512; ++d) s = fmaf(ew[cp * 512 + d], pw[d * 64 + c], s);
  M[p * 4096 + idx] = s;
  if (sub == 0 && threadIdx.x < 64) {
    int t = threadIdx.x;
    float sb = pb[t];
    for (int d = 0; d < 512; ++d) sb = fmaf(eb[d], pw[d * 64 + t], sb);
    cvec[p * 64 + t] = sb;
  }
}

// ---------------- kernel 2: transpose tw -> Wt[h][l] bf16 (+colsum) ----------------
__global__ void k_wprep(const float* __restrict__ st_w, const float* __restrict__ tt_w,
                        bf16_t* __restrict__ Wt, float* __restrict__ S) {
  int p = blockIdx.z;
  const float* W = p ? tt_w : st_w;          // (4096, 720)
  int l0 = blockIdx.x * 64, h0 = blockIdx.y * 64;
  __shared__ float tile[64][65];
  int row = threadIdx.x >> 6, col = threadIdx.x & 63;
  int h = h0 + col;
  float partial = 0.f;
  for (int r = row; r < 64; r += 4) {
    float v = (h < Hn) ? W[(size_t)(l0 + r) * Hn + h] : 0.f;
    tile[r][col] = v;
    partial += v;
  }
  if (h < Hn) atomicAdd(&S[p * 768 + h], partial);
  __syncthreads();
  for (int a = row; a < 64; a += 4) {
    float v = tile[col][a];                  // transposed read (pad 65 -> no conflict)
    Wt[(size_t)(p * HPn + h0 + a) * Ln + l0 + col] = __float2bfloat16(v);
  }
}

// ---------------- kernel 3a: per-(b,c,seg) raw-x scan partials + stats partials ----------------
__global__ void __launch_bounds__(64) k_scanA(const float* __restrict__ x, const float* __restrict__ alpha,
                                              float* __restrict__ Praw, float* __restrict__ Ssum,
                                              float* __restrict__ Ssq) {
  int b = blockIdx.x, s = blockIdx.y, c = threadIdx.x;
  float a = 1.f / (1.f + expf(-alpha[c]));
  float k1 = 1.f - a;
  const float* xb = x + ((size_t)b * Ln + s * 64) * Cn + c;
  float pr = 0.f, sm = 0.f, sq = 0.f;
#pragma unroll 8
  for (int j = 0; j < 64; ++j) {
    float v = xb[(size_t)j * Cn];
    sm += v;
    sq = fmaf(v, v, sq);
    pr = fmaf(a, pr, k1 * v);
  }
  int idx = (b * 64 + s) * 64 + c;
  Praw[idx] = pr; Ssum[idx] = sm; Ssq[idx] = sq;
}

// ---------------- kernel 3b: stats finalize + 64-step carry scan ----------------
__global__ void __launch_bounds__(64) k_scanB(const float* __restrict__ x, const float* __restrict__ alpha,
                                              const float* __restrict__ rev_w, const float* __restrict__ rev_b,
                                              const float* __restrict__ Praw, const float* __restrict__ Ssum,
                                              const float* __restrict__ Ssq,
                                              float* __restrict__ mean, float* __restrict__ rstd,
                                              float* __restrict__ stdv, float* __restrict__ CarryIn) {
  int b = blockIdx.x, c = threadIdx.x;
  float sm = 0.f, sq = 0.f;
  for (int s = 0; s < 64; ++s) {
    int idx = (b * 64 + s) * 64 + c;
    sm += Ssum[idx]; sq += Ssq[idx];
  }
  float mn = sm * (1.f / 4096.f);
  float var = sq * (1.f / 4096.f) - mn * mn;
  float sd = sqrtf(var + EPSf);
  float rs = 1.f / sd;
  mean[b * 64 + c] = mn; stdv[b * 64 + c] = sd; rstd[b * 64 + c] = rs;

  float w = rev_w[c], rb = rev_b[c];
  float g = rs * w, d = rb - mn * g;         // xn = g*x + d
  float a = 1.f / (1.f + expf(-alpha[c]));
  float a2 = a * a, a4 = a2 * a2, a8 = a4 * a4, a16 = a8 * a8, a32 = a16 * a16;
  float a64 = a32 * a32;
  float k1s = 1.f - a64;                      // sum of (1-a)*a^k, k=0..63
  float carry = fmaf(g, x[((size_t)b * Ln) * Cn + c], d);   // xn[0]
  for (int s = 0; s < 64; ++s) {
    int idx = (b * 64 + s) * 64 + c;
    CarryIn[idx] = carry;
    float P = fmaf(g, Praw[idx], d * k1s);
    carry = fmaf(a64, carry, P);
  }
}

// ---------------- kernel 3c: apply scan + write seasonal/trend transposed bf16 ----------------
__global__ void __launch_bounds__(64) k_scanC(const float* __restrict__ x, const float* __restrict__ alpha,
                                              const float* __restrict__ rev_w, const float* __restrict__ rev_b,
                                              const float* __restrict__ mean, const float* __restrict__ rstd,
                                              const float* __restrict__ CarryIn, bf16_t* __restrict__ Zt) {
  int b = blockIdx.x, s = blockIdx.y, c = threadIdx.x;
  float mn = mean[b * 64 + c], rs = rstd[b * 64 + c];
  float w = rev_w[c], rb = rev_b[c];
  float g = rs * w, d = rb - mn * g;
  float a = 1.f / (1.f + expf(-alpha[c]));
  float k1 = 1.f - a;
  float tr = CarryIn[(b * 64 + s) * 64 + c];
  const float* xb = x + ((size_t)b * Ln + s * 64) * Cn + c;
  bf16_t* zs = Zt + ((size_t)b * Cn + c) * Ln + s * 64;          // path 0: seasonal
  bf16_t* zt = zs + (size_t)Bn * Cn * Ln;                        // path 1: trend
#pragma unroll
  for (int jo = 0; jo < 8; ++jo) {
    bf16x8 vs, vt;
#pragma unroll
    for (int ji = 0; ji < 8; ++ji) {
      float v = xb[(size_t)(jo * 8 + ji) * Cn];
      float xn = fmaf(g, v, d);
      tr = fmaf(a, tr, k1 * xn);
      float se = xn - tr;
      vs[ji] = f2bf(se);
      vt[ji] = f2bf(tr);
    }
    *reinterpret_cast<bf16x8*>(zs + jo * 8) = vs;   // 16B per lane, per-thread-contiguous 128B run
    *reinterpret_cast<bf16x8*>(zt + jo * 8) = vt;
  }
}

// ---------------- kernel 5: bf16 MFMA GEMM  Osr[z,b,h,c] = sum_{l in slice} Wt[p,h,l]*Zt[p,b,c,l] ----------------
__device__ __forceinline__ void gload16(const bf16_t* g, bf16_t* l) {
  __builtin_amdgcn_global_load_lds((const AS_GLOBAL uint32_t*)g, (AS_LDS uint32_t*)l, 16, 0, 0);
}

template <int KS>
__global__ void __launch_bounds__(256) k_gemm(const bf16_t* __restrict__ Wt, const bf16_t* __restrict__ Zt,
                                              float* __restrict__ Osr) {
  int z = blockIdx.z;
  int p = z / KS, kq = z % KS;
  const bf16_t* A  = Wt + (size_t)p * HPn * Ln;       // [768][4096]
  const bf16_t* Bz = Zt + (size_t)p * (Bn * Cn) * Ln; // [2048][4096]
  int h0 = blockIdx.y * 128, n0 = blockIdx.x * 128;
  int kbase = kq * (Ln / KS), kend = kbase + (Ln / KS);
  __shared__ __align__(16) bf16_t Al[128 * 32];
  __shared__ __align__(16) bf16_t Bl[128 * 32];
  int tid = threadIdx.x, wid = tid >> 6, lane = tid & 63;
  int wr = wid >> 1, wc = wid & 1;
  int srow = lane >> 2;              // 0..15
  int koff = (lane & 3) * 8;         // 0,8,16,24
  int fr = lane & 15, hi = lane >> 4;
  f32x4 acc[4][4];
#pragma unroll
  for (int i = 0; i < 4; ++i)
#pragma unroll
    for (int j = 0; j < 4; ++j) acc[i][j] = (f32x4){0.f, 0.f, 0.f, 0.f};

  for (int k0 = kbase; k0 < kend; k0 += 32) {
    __syncthreads();                 // prior ds_reads done before overwrite
#pragma unroll
    for (int j = 0; j < 2; ++j) {
      int blk = j * 4 + wid;         // 0..7 -> rows blk*16..+15
      int m = blk * 16 + srow;
      gload16(A  + (size_t)(h0 + m) * Ln + k0 + koff, &Al[blk * 512]);
      gload16(Bz + (size_t)(n0 + m) * Ln + k0 + koff, &Bl[blk * 512]);
    }
    __syncthreads();                 // drains vmcnt -> tile ready
    bf16x8 afr[4], bfr[4];
#pragma unroll
    for (int i = 0; i < 4; ++i)
      afr[i] = *reinterpret_cast<const bf16x8*>(&Al[(wr * 64 + i * 16 + fr) * 32 + hi * 8]);
#pragma unroll
    for (int i = 0; i < 4; ++i)
      bfr[i] = *reinterpret_cast<const bf16x8*>(&Bl[(wc * 64 + i * 16 + fr) * 32 + hi * 8]);
#pragma unroll
    for (int i = 0; i < 4; ++i)
#pragma unroll
      for (int j = 0; j < 4; ++j)
        acc[i][j] = __builtin_amdgcn_mfma_f32_16x16x32_bf16(afr[i], bfr[j], acc[i][j], 0, 0, 0);
  }

#pragma unroll
  for (int i = 0; i < 4; ++i) {
#pragma unroll
    for (int j = 0; j < 4; ++j) {
#pragma unroll
      for (int r = 0; r < 4; ++r) {
        int m = wr * 64 + i * 16 + hi * 4 + r;
        int h = h0 + m;
        if (h < Hn) {
          int n = n0 + wc * 64 + j * 16 + fr;
          int bidx = n >> 6, c = n & 63;
          Osr[(((size_t)z * Bn + bidx) * Hn + h) * Cn + c] = acc[i][j][r];
        }
      }
    }
  }
}

// ---------------- kernel 6: epilogue — sum K-slices, apply M, biases, inverse RevIN ----------------
template <int KS>
__global__ void __launch_bounds__(256) k_epi(const float* __restrict__ Osr, const float* __restrict__ M,
                                             const float* __restrict__ cvec, const float* __restrict__ S,
                                             const float* __restrict__ st_b, const float* __restrict__ tt_b,
                                             const float* __restrict__ rev_w, const float* __restrict__ rev_b,
                                             const float* __restrict__ mean, const float* __restrict__ stdv,
                                             float* __restrict__ out) {
  __shared__ float Msh[2][64][64];    // 32 KB
  __shared__ float rowS[4][64];
  __shared__ float rowT[4][64];
  int t = threadIdx.x;
  for (int i = t; i < 8192; i += 256) ((float*)Msh)[i] = M[i];
  int g = t >> 6, c = t & 63;
  float w = rev_w[c], rb = rev_b[c];
  float cs = cvec[c], ct = cvec[64 + c];
  int base = blockIdx.x * 16;
  for (int it = 0; it < 4; ++it) {
    int r = base + it * 4 + g;        // r = b*720 + h
    int b = r / 720, h = r % 720;
    __syncthreads();                  // also covers Msh load at it=0
    float vs = 0.f, vt = 0.f;
#pragma unroll
    for (int kq = 0; kq < KS; ++kq) {
      vs += Osr[(((size_t)kq * Bn + b) * Hn + h) * Cn + c];
      vt += Osr[(((size_t)(KS + kq) * Bn + b) * Hn + h) * Cn + c];
    }
    rowS[g][c] = vs;
    rowT[g][c] = vt;
    __syncthreads();
    float acc = cs * S[h] + ct * S[768 + h] + st_b[h] + tt_b[h];
    for (int cp = 0; cp < 64; ++cp)
      acc = fmaf(rowS[g][cp], Msh[0][cp][c], fmaf(rowT[g][cp], Msh[1][cp][c], acc));
    float o = (acc - rb) / (w + EPSf) * stdv[b * Cn + c] + mean[b * Cn + c];
    out[(size_t)r * 64 + c] = o;
  }
}

// ---------------- launch ----------------
extern "C" void kernel_launch(void* const* d_in, const int* in_sizes, int n_in,
                              void* d_out, int out_size, void* d_ws, size_t ws_size,
                              hipStream_t stream) {
  const float* x     = (const float*)d_in[0];
  const float* alpha = (const float*)d_in[1];
  const float* rev_w = (const float*)d_in[2];
  const float* rev_b = (const float*)d_in[3];
  const float* se_w  = (const float*)d_in[4];
  const float* se_b  = (const float*)d_in[5];
  const float* sp_w  = (const float*)d_in[6];
  const float* sp_b  = (const float*)d_in[7];
  const float* st_w  = (const float*)d_in[8];
  const float* st_b  = (const float*)d_in[9];
  const float* te_w  = (const float*)d_in[10];
  const float* te_b  = (const float*)d_in[11];
  const float* tp_w  = (const float*)d_in[12];
  const float* tp_b  = (const float*)d_in[13];
  const float* tt_w  = (const float*)d_in[14];
  const float* tt_b  = (const float*)d_in[15];
  float* out = (float*)d_out;

  const size_t SZ_WT  = (size_t)2 * HPn * Ln * 2;          // 12.58 MB
  const size_t SZ_ZT  = (size_t)2 * Bn * Cn * Ln * 2;      // 33.55 MB
  const size_t SZ_SC  = (size_t)Bn * 64 * 64 * 4;          // 0.5 MB per scan scratch buf
  const size_t TAIL   = 2 * 64 * 64 * 4 + 2 * 64 * 4 + 2 * 768 * 4 + 3 * (size_t)Bn * Cn * 4;

  // KS=4 needs 8 Osr slices; KS=1 needs 2 (matching round-1 footprint).
  const size_t NEED4 = SZ_WT + SZ_ZT + 8 * OSR_SLICE * 4 + TAIL;
  const int KS = (ws_size >= NEED4) ? 4 : 1;
  const size_t SZ_OSR = (size_t)(2 * KS) * OSR_SLICE * 4;

  char* ws = (char*)d_ws;
  bf16_t* Wt   = (bf16_t*)(ws);
  bf16_t* Zt   = (bf16_t*)(ws + SZ_WT);
  float*  Osr  = (float*)(ws + SZ_WT + SZ_ZT);
  // scan scratch aliases Osr (dead before k_gemm writes Osr)
  float*  Praw  = Osr;
  float*  Ssum  = (float*)((char*)Praw + SZ_SC);
  float*  Ssq   = (float*)((char*)Ssum + SZ_SC);
  float*  Carry = (float*)((char*)Ssq + SZ_SC);
  char* tail = ws + SZ_WT + SZ_ZT + SZ_OSR;
  float* Mbuf = (float*)tail;                 tail += 2 * 64 * 64 * 4;
  float* cvec = (float*)tail;                 tail += 2 * 64 * 4;
  float* S    = (float*)tail;                 tail += 2 * 768 * 4;
  float* mean = (float*)tail;                 tail += (size_t)Bn * Cn * 4;
  float* rstd = (float*)tail;                 tail += (size_t)Bn * Cn * 4;
  float* stdv = (float*)tail;

  hipMemsetAsync(S, 0, 2 * 768 * 4, stream);

  k_prep_small<<<32, 256, 0, stream>>>(se_w, sp_w, se_b, sp_b, te_w, tp_w, te_b, tp_b, Mbuf, cvec);
  k_wprep<<<dim3(64, 12, 2), 256, 0, stream>>>(st_w, tt_w, Wt, S);
  k_scanA<<<dim3(32, 64), 64, 0, stream>>>(x, alpha, Praw, Ssum, Ssq);
  k_scanB<<<32, 64, 0, stream>>>(x, alpha, rev_w, rev_b, Praw, Ssum, Ssq, mean, rstd, stdv, Carry);
  k_scanC<<<dim3(32, 64), 64, 0, stream>>>(x, alpha, rev_w, rev_b, mean, rstd, Carry, Zt);
  if (KS == 4) {
    k_gemm<4><<<dim3(16, 6, 8), 256, 0, stream>>>(Wt, Zt, Osr);
    k_epi<4><<<1440, 256, 0, stream>>>(Osr, Mbuf, cvec, S, st_b, tt_b, rev_w, rev_b, mean, stdv, out);
  } else {
    k_gemm<1><<<dim3(16, 6, 2), 256, 0, stream>>>(Wt, Zt, Osr);
    k_epi<1><<<1440, 256, 0, stream>>>(Osr, Mbuf, cvec, S, st_b, tt_b, rev_w, rev_b, mean, stdv, out);
  }
}

// Round 3
// 170.855 us; speedup vs baseline: 4.5327x; 1.1252x over previous
//
#include <hip/hip_runtime.h>
#include <hip/hip_bf16.h>
#include <string.h>
#include <stdint.h>

typedef __hip_bfloat16 bf16_t;
typedef float f32x4 __attribute__((ext_vector_type(4)));
typedef short bf16x8 __attribute__((ext_vector_type(8)));

#define AS_GLOBAL __attribute__((address_space(1)))
#define AS_LDS    __attribute__((address_space(3)))

static constexpr int Bn = 32, Ln = 4096, Cn = 64, Hn = 720, HPn = 768;
static constexpr float EPSf = 1e-5f;

static constexpr size_t OSR_SLICE = (size_t)Bn * Hn * Cn;   // f32 elements per K-slice per path

__device__ __forceinline__ short f2bf(float f) {
  bf16_t h = __float2bfloat16(f);
  unsigned short u; memcpy(&u, &h, 2);
  return (short)u;
}

// ---------------- kernel 1: fold the two 64->512->64 MLPs ----------------
__global__ void k_prep_small(const float* __restrict__ se_w, const float* __restrict__ sp_w,
                             const float* __restrict__ se_b, const float* __restrict__ sp_b,
                             const float* __restrict__ te_w, const float* __restrict__ tp_w,
                             const float* __restrict__ te_b, const float* __restrict__ tp_b,
                             float* __restrict__ M, float* __restrict__ cvec) {
  int p = blockIdx.x >> 4, sub = blockIdx.x & 15;
  const float* ew = p ? te_w : se_w;   // (64,512)
  const float* pw = p ? tp_w : sp_w;   // (512,64)
  const float* eb = p ? te_b : se_b;   // (512,)
  const float* pb = p ? tp_b : sp_b;   // (64,)
  int idx = sub * 256 + threadIdx.x;   // 0..4095
  int cp = idx >> 6, c = idx & 63;
  float s = 0.f;
  for (int d = 0; d < 512; ++d) s = fmaf(ew[cp * 512 + d], pw[d * 64 + c], s);
  M[p * 4096 + idx] = s;
  if (sub == 0 && threadIdx.x < 64) {
    int t = threadIdx.x;
    float sb = pb[t];
    for (int d = 0; d < 512; ++d) sb = fmaf(eb[d], pw[d * 64 + t], sb);
    cvec[p * 64 + t] = sb;
  }
}

// ---------------- kernel 2: transpose tw -> Wt[h][l] bf16 (+colsum) ----------------
__global__ void k_wprep(const float* __restrict__ st_w, const float* __restrict__ tt_w,
                        bf16_t* __restrict__ Wt, float* __restrict__ S) {
  int p = blockIdx.z;
  const float* W = p ? tt_w : st_w;          // (4096, 720)
  int l0 = blockIdx.x * 64, h0 = blockIdx.y * 64;
  __shared__ float tile[64][65];
  int row = threadIdx.x >> 6, col = threadIdx.x & 63;
  int h = h0 + col;
  float partial = 0.f;
  for (int r = row; r < 64; r += 4) {
    float v = (h < Hn) ? W[(size_t)(l0 + r) * Hn + h] : 0.f;
    tile[r][col] = v;
    partial += v;
  }
  if (h < Hn) atomicAdd(&S[p * 768 + h], partial);
  __syncthreads();
  for (int a = row; a < 64; a += 4) {
    float v = tile[col][a];                  // transposed read (pad 65 -> no conflict)
    Wt[(size_t)(p * HPn + h0 + a) * Ln + l0 + col] = __float2bfloat16(v);
  }
}

// ---------------- kernel 3a: per-(b,c,seg) raw-x scan partials + stats partials ----------------
__global__ void __launch_bounds__(64) k_scanA(const float* __restrict__ x, const float* __restrict__ alpha,
                                              float* __restrict__ Praw, float* __restrict__ Ssum,
                                              float* __restrict__ Ssq) {
  int b = blockIdx.x, s = blockIdx.y, c = threadIdx.x;
  float a = 1.f / (1.f + expf(-alpha[c]));
  float k1 = 1.f - a;
  const float* xb = x + ((size_t)b * Ln + s * 64) * Cn + c;
  float pr = 0.f, sm = 0.f, sq = 0.f;
#pragma unroll 8
  for (int j = 0; j < 64; ++j) {
    float v = xb[(size_t)j * Cn];
    sm += v;
    sq = fmaf(v, v, sq);
    pr = fmaf(a, pr, k1 * v);
  }
  int idx = (b * 64 + s) * 64 + c;
  Praw[idx] = pr; Ssum[idx] = sm; Ssq[idx] = sq;
}

// ---------------- kernel 3b: stats finalize + 64-step carry scan ----------------
__global__ void __launch_bounds__(64) k_scanB(const float* __restrict__ x, const float* __restrict__ alpha,
                                              const float* __restrict__ rev_w, const float* __restrict__ rev_b,
                                              const float* __restrict__ Praw, const float* __restrict__ Ssum,
                                              const float* __restrict__ Ssq,
                                              float* __restrict__ mean, float* __restrict__ rstd,
                                              float* __restrict__ stdv, float* __restrict__ CarryIn) {
  int b = blockIdx.x, c = threadIdx.x;
  float sm = 0.f, sq = 0.f;
#pragma unroll 8
  for (int s = 0; s < 64; ++s) {
    int idx = (b * 64 + s) * 64 + c;
    sm += Ssum[idx]; sq += Ssq[idx];
  }
  float mn = sm * (1.f / 4096.f);
  float var = sq * (1.f / 4096.f) - mn * mn;
  float sd = sqrtf(var + EPSf);
  float rs = 1.f / sd;
  mean[b * 64 + c] = mn; stdv[b * 64 + c] = sd; rstd[b * 64 + c] = rs;

  float w = rev_w[c], rb = rev_b[c];
  float g = rs * w, d = rb - mn * g;         // xn = g*x + d
  float a = 1.f / (1.f + expf(-alpha[c]));
  float a2 = a * a, a4 = a2 * a2, a8 = a4 * a4, a16 = a8 * a8, a32 = a16 * a16;
  float a64 = a32 * a32;
  float dk1s = d * (1.f - a64);               // d * sum of (1-a)*a^k
  float carry = fmaf(g, x[((size_t)b * Ln) * Cn + c], d);   // xn[0]
  for (int so = 0; so < 8; ++so) {
    float pv[8];
#pragma unroll
    for (int i = 0; i < 8; ++i)
      pv[i] = Praw[((size_t)(b * 64 + so * 8 + i)) * 64 + c];   // batched, independent loads
#pragma unroll
    for (int i = 0; i < 8; ++i) {
      CarryIn[((size_t)(b * 64 + so * 8 + i)) * 64 + c] = carry;
      carry = fmaf(a64, carry, fmaf(g, pv[i], dk1s));
    }
  }
}

// ---------------- kernel 3c: apply scan + write seasonal/trend transposed bf16 ----------------
__global__ void __launch_bounds__(64) k_scanC(const float* __restrict__ x, const float* __restrict__ alpha,
                                              const float* __restrict__ rev_w, const float* __restrict__ rev_b,
                                              const float* __restrict__ mean, const float* __restrict__ rstd,
                                              const float* __restrict__ CarryIn, bf16_t* __restrict__ Zt) {
  int b = blockIdx.x, s = blockIdx.y, c = threadIdx.x;
  float mn = mean[b * 64 + c], rs = rstd[b * 64 + c];
  float w = rev_w[c], rb = rev_b[c];
  float g = rs * w, d = rb - mn * g;
  float a = 1.f / (1.f + expf(-alpha[c]));
  float k1 = 1.f - a;
  float tr = CarryIn[(b * 64 + s) * 64 + c];
  const float* xb = x + ((size_t)b * Ln + s * 64) * Cn + c;
  bf16_t* zs = Zt + ((size_t)b * Cn + c) * Ln + s * 64;          // path 0: seasonal
  bf16_t* zt = zs + (size_t)Bn * Cn * Ln;                        // path 1: trend
#pragma unroll
  for (int jo = 0; jo < 8; ++jo) {
    bf16x8 vs, vt;
#pragma unroll
    for (int ji = 0; ji < 8; ++ji) {
      float v = xb[(size_t)(jo * 8 + ji) * Cn];
      float xn = fmaf(g, v, d);
      tr = fmaf(a, tr, k1 * xn);
      float se = xn - tr;
      vs[ji] = f2bf(se);
      vt[ji] = f2bf(tr);
    }
    *reinterpret_cast<bf16x8*>(zs + jo * 8) = vs;   // 16B per lane, per-thread-contiguous 128B run
    *reinterpret_cast<bf16x8*>(zt + jo * 8) = vt;
  }
}

// ---------------- kernel 5: bf16 MFMA GEMM  Osr[z,b,h,c] = sum_{l in slice} Wt[p,h,l]*Zt[p,b,c,l] ----
// 128x128 tile, BK=32, triple-buffered LDS (48KB), single barrier + counted vmcnt per K-step,
// XOR-swizzled LDS (linear gload_lds dest + inverse-swizzled global source + swizzled ds_read).
__device__ __forceinline__ void gload16(const bf16_t* g, bf16_t* l) {
  __builtin_amdgcn_global_load_lds((const AS_GLOBAL uint32_t*)g, (AS_LDS uint32_t*)l, 16, 0, 0);
}

template <int KS>
__global__ void __launch_bounds__(256, 3) k_gemm(const bf16_t* __restrict__ Wt, const bf16_t* __restrict__ Zt,
                                                 float* __restrict__ Osr) {
  int z = blockIdx.z;
  int p = z / KS, kq = z % KS;
  const bf16_t* A  = Wt + (size_t)p * HPn * Ln;       // [768][4096]
  const bf16_t* Bz = Zt + (size_t)p * (Bn * Cn) * Ln; // [2048][4096]
  int h0 = blockIdx.y * 128, n0 = blockIdx.x * 128;
  int kbase = kq * (Ln / KS);
  const int NT = (Ln / KS) / 32;                      // K-steps of 32
  __shared__ __align__(16) bf16_t Al[3][128 * 32];
  __shared__ __align__(16) bf16_t Bl[3][128 * 32];
  int tid = threadIdx.x, wid = tid >> 6, lane = tid & 63;
  int wr = wid >> 1, wc = wid & 1;
  int fr = lane & 15, hi = lane >> 4;
  f32x4 acc[4][4];
#pragma unroll
  for (int i = 0; i < 4; ++i)
#pragma unroll
    for (int j = 0; j < 4; ++j) acc[i][j] = (f32x4){0.f, 0.f, 0.f, 0.f};

  // stage K-step kt into buffer bufi. LDS dest is linear (wave-uniform base + lane*16B);
  // global source k-chunk is XOR-swizzled by row so the swizzled ds_read below is conflict-free.
  auto STAGE = [&](int bufi, int kt) {
    int k0 = kbase + kt * 32;
#pragma unroll
    for (int j = 0; j < 2; ++j) {
      int blk = j * 4 + wid;                 // 0..7 -> rows blk*16..+15
      int m = blk * 16 + (lane >> 2);
      int ks = (lane & 3) ^ (m & 3);         // inverse swizzle on the SOURCE
      gload16(A  + (size_t)(h0 + m) * Ln + k0 + ks * 8, &Al[bufi][blk * 512]);
      gload16(Bz + (size_t)(n0 + m) * Ln + k0 + ks * 8, &Bl[bufi][blk * 512]);
    }
  };

  auto COMPUTE = [&](int bufi) {
    bf16x8 afr[4], bfr[4];
    int sw = (hi ^ (fr & 3)) * 8;            // swizzled k-chunk position (R&3 == fr&3)
#pragma unroll
    for (int i = 0; i < 4; ++i) {
      int R = wr * 64 + i * 16 + fr;
      afr[i] = *reinterpret_cast<const bf16x8*>(&Al[bufi][R * 32 + sw]);
    }
#pragma unroll
    for (int i = 0; i < 4; ++i) {
      int R = wc * 64 + i * 16 + fr;
      bfr[i] = *reinterpret_cast<const bf16x8*>(&Bl[bufi][R * 32 + sw]);
    }
    __builtin_amdgcn_s_setprio(1);
#pragma unroll
    for (int i = 0; i < 4; ++i)
#pragma unroll
      for (int j = 0; j < 4; ++j)
        acc[i][j] = __builtin_amdgcn_mfma_f32_16x16x32_bf16(afr[i], bfr[j], acc[i][j], 0, 0, 0);
    __builtin_amdgcn_s_setprio(0);
  };

  STAGE(0, 0);
  STAGE(1, 1);
  int cur = 0, nxt2 = 2;                     // t%3 and (t+2)%3, maintained incrementally
  for (int t = 0; t < NT; ++t) {
    __builtin_amdgcn_sched_barrier(0);
    if (t + 1 < NT) { asm volatile("s_waitcnt vmcnt(4)" ::: "memory"); }   // tile t done; t+1 in flight
    else            { asm volatile("s_waitcnt vmcnt(0)" ::: "memory"); }
    __builtin_amdgcn_s_barrier();            // all waves' tile-t loads landed; t-1 reads finished
    __builtin_amdgcn_sched_barrier(0);
    if (t + 2 < NT) STAGE(nxt2, t + 2);      // overwrites buffer consumed at t-1: safe after barrier
    COMPUTE(cur);
    cur = nxt2 == 2 ? (cur == 2 ? 0 : cur + 1) : cur + 1;  // cur = (t+1)%3
    cur = (cur > 2) ? 0 : cur;
    nxt2 = (nxt2 == 2) ? 0 : nxt2 + 1;
    if (cur > 2) cur = 0;
  }

#pragma unroll
  for (int i = 0; i < 4; ++i) {
#pragma unroll
    for (int j = 0; j < 4; ++j) {
#pragma unroll
      for (int r = 0; r < 4; ++r) {
        int m = wr * 64 + i * 16 + hi * 4 + r;
        int h = h0 + m;
        if (h < Hn) {
          int n = n0 + wc * 64 + j * 16 + fr;
          int bidx = n >> 6, c = n & 63;
          Osr[(((size_t)z * Bn + bidx) * Hn + h) * Cn + c] = acc[i][j][r];
        }
      }
    }
  }
}

// ---------------- kernel 6: epilogue — sum K-slices, apply M, biases, inverse RevIN ----------------
template <int KS>
__global__ void __launch_bounds__(256) k_epi(const float* __restrict__ Osr, const float* __restrict__ M,
                                             const float* __restrict__ cvec, const float* __restrict__ S,
                                             const float* __restrict__ st_b, const float* __restrict__ tt_b,
                                             const float* __restrict__ rev_w, const float* __restrict__ rev_b,
                                             const float* __restrict__ mean, const float* __restrict__ stdv,
                                             float* __restrict__ out) {
  __shared__ float Msh[2][64][64];    // 32 KB
  __shared__ float rowS[4][64];
  __shared__ float rowT[4][64];
  int t = threadIdx.x;
  for (int i = t; i < 8192; i += 256) ((float*)Msh)[i] = M[i];
  int g = t >> 6, c = t & 63;
  float w = rev_w[c], rb = rev_b[c];
  float cs = cvec[c], ct = cvec[64 + c];
  int base = blockIdx.x * 16;
  for (int it = 0; it < 4; ++it) {
    int r = base + it * 4 + g;        // r = b*720 + h
    int b = r / 720, h = r % 720;
    __syncthreads();                  // also covers Msh load at it=0
    float vs = 0.f, vt = 0.f;
#pragma unroll
    for (int kq = 0; kq < KS; ++kq) {
      vs += Osr[(((size_t)kq * Bn + b) * Hn + h) * Cn + c];
      vt += Osr[(((size_t)(KS + kq) * Bn + b) * Hn + h) * Cn + c];
    }
    rowS[g][c] = vs;
    rowT[g][c] = vt;
    __syncthreads();
    float acc = cs * S[h] + ct * S[768 + h] + st_b[h] + tt_b[h];
    for (int cp = 0; cp < 64; ++cp)
      acc = fmaf(rowS[g][cp], Msh[0][cp][c], fmaf(rowT[g][cp], Msh[1][cp][c], acc));
    float o = (acc - rb) / (w + EPSf) * stdv[b * Cn + c] + mean[b * Cn + c];
    out[(size_t)r * 64 + c] = o;
  }
}

// ---------------- launch ----------------
extern "C" void kernel_launch(void* const* d_in, const int* in_sizes, int n_in,
                              void* d_out, int out_size, void* d_ws, size_t ws_size,
                              hipStream_t stream) {
  const float* x     = (const float*)d_in[0];
  const float* alpha = (const float*)d_in[1];
  const float* rev_w = (const float*)d_in[2];
  const float* rev_b = (const float*)d_in[3];
  const float* se_w  = (const float*)d_in[4];
  const float* se_b  = (const float*)d_in[5];
  const float* sp_w  = (const float*)d_in[6];
  const float* sp_b  = (const float*)d_in[7];
  const float* st_w  = (const float*)d_in[8];
  const float* st_b  = (const float*)d_in[9];
  const float* te_w  = (const float*)d_in[10];
  const float* te_b  = (const float*)d_in[11];
  const float* tp_w  = (const float*)d_in[12];
  const float* tp_b  = (const float*)d_in[13];
  const float* tt_w  = (const float*)d_in[14];
  const float* tt_b  = (const float*)d_in[15];
  float* out = (float*)d_out;

  const size_t SZ_WT  = (size_t)2 * HPn * Ln * 2;          // 12.58 MB
  const size_t SZ_ZT  = (size_t)2 * Bn * Cn * Ln * 2;      // 33.55 MB
  const size_t SZ_SC  = (size_t)Bn * 64 * 64 * 4;          // 0.5 MB per scan scratch buf
  const size_t TAIL   = 2 * 64 * 64 * 4 + 2 * 64 * 4 + 2 * 768 * 4 + 3 * (size_t)Bn * Cn * 4;

  // KS=4 needs 8 Osr slices; KS=1 needs 2 (matching round-1 footprint).
  const size_t NEED4 = SZ_WT + SZ_ZT + 8 * OSR_SLICE * 4 + TAIL;
  const int KS = (ws_size >= NEED4) ? 4 : 1;
  const size_t SZ_OSR = (size_t)(2 * KS) * OSR_SLICE * 4;

  char* ws = (char*)d_ws;
  bf16_t* Wt   = (bf16_t*)(ws);
  bf16_t* Zt   = (bf16_t*)(ws + SZ_WT);
  float*  Osr  = (float*)(ws + SZ_WT + SZ_ZT);
  // scan scratch aliases Osr (dead before k_gemm writes Osr)
  float*  Praw  = Osr;
  float*  Ssum  = (float*)((char*)Praw + SZ_SC);
  float*  Ssq   = (float*)((char*)Ssum + SZ_SC);
  float*  Carry = (float*)((char*)Ssq + SZ_SC);
  char* tail = ws + SZ_WT + SZ_ZT + SZ_OSR;
  float* Mbuf = (float*)tail;                 tail += 2 * 64 * 64 * 4;
  float* cvec = (float*)tail;                 tail += 2 * 64 * 4;
  float* S    = (float*)tail;                 tail += 2 * 768 * 4;
  float* mean = (float*)tail;                 tail += (size_t)Bn * Cn * 4;
  float* rstd = (float*)tail;                 tail += (size_t)Bn * Cn * 4;
  float* stdv = (float*)tail;

  hipMemsetAsync(S, 0, 2 * 768 * 4, stream);

  k_prep_small<<<32, 256, 0, stream>>>(se_w, sp_w, se_b, sp_b, te_w, tp_w, te_b, tp_b, Mbuf, cvec);
  k_wprep<<<dim3(64, 12, 2), 256, 0, stream>>>(st_w, tt_w, Wt, S);
  k_scanA<<<dim3(32, 64), 64, 0, stream>>>(x, alpha, Praw, Ssum, Ssq);
  k_scanB<<<32, 64, 0, stream>>>(x, alpha, rev_w, rev_b, Praw, Ssum, Ssq, mean, rstd, stdv, Carry);
  k_scanC<<<dim3(32, 64), 64, 0, stream>>>(x, alpha, rev_w, rev_b, mean, rstd, Carry, Zt);
  if (KS == 4) {
    k_gemm<4><<<dim3(16, 6, 8), 256, 0, stream>>>(Wt, Zt, Osr);
    k_epi<4><<<1440, 256, 0, stream>>>(Osr, Mbuf, cvec, S, st_b, tt_b, rev_w, rev_b, mean, stdv, out);
  } else {
    k_gemm<1><<<dim3(16, 6, 2), 256, 0, stream>>>(Wt, Zt, Osr);
    k_epi<1><<<1440, 256, 0, stream>>>(Osr, Mbuf, cvec, S, st_b, tt_b, rev_w, rev_b, mean, stdv, out);
  }
}

// Round 4
// 152.407 us; speedup vs baseline: 5.0813x; 1.1210x over previous
//
#include <hip/hip_runtime.h>
#include <hip/hip_bf16.h>
#include <string.h>
#include <stdint.h>

typedef __hip_bfloat16 bf16_t;
typedef float f32x4 __attribute__((ext_vector_type(4)));
typedef short bf16x8 __attribute__((ext_vector_type(8)));

#define AS_GLOBAL __attribute__((address_space(1)))
#define AS_LDS    __attribute__((address_space(3)))

static constexpr int Bn = 32, Ln = 4096, Cn = 64, Hn = 720, HPn = 768;
static constexpr float EPSf = 1e-5f;

static constexpr size_t OSR_SLICE = (size_t)Bn * Hn * Cn;   // f32 elements per K-slice per path

__device__ __forceinline__ short f2bf(float f) {
  bf16_t h = __float2bfloat16(f);
  unsigned short u; memcpy(&u, &h, 2);
  return (short)u;
}

__device__ __forceinline__ float sigm(float v) { return 1.f / (1.f + expf(-v)); }

// ---------------- kernel 1: fold the two 64->512->64 MLPs ----------------
__global__ void k_prep_small(const float* __restrict__ se_w, const float* __restrict__ sp_w,
                             const float* __restrict__ se_b, const float* __restrict__ sp_b,
                             const float* __restrict__ te_w, const float* __restrict__ tp_w,
                             const float* __restrict__ te_b, const float* __restrict__ tp_b,
                             float* __restrict__ M, float* __restrict__ cvec) {
  int p = blockIdx.x >> 4, sub = blockIdx.x & 15;
  const float* ew = p ? te_w : se_w;   // (64,512)
  const float* pw = p ? tp_w : sp_w;   // (512,64)
  const float* eb = p ? te_b : se_b;   // (512,)
  const float* pb = p ? tp_b : sp_b;   // (64,)
  int idx = sub * 256 + threadIdx.x;   // 0..4095
  int cp = idx >> 6, c = idx & 63;
  float s = 0.f;
  for (int d = 0; d < 512; ++d) s = fmaf(ew[cp * 512 + d], pw[d * 64 + c], s);
  M[p * 4096 + idx] = s;
  if (sub == 0 && threadIdx.x < 64) {
    int t = threadIdx.x;
    float sb = pb[t];
    for (int d = 0; d < 512; ++d) sb = fmaf(eb[d], pw[d * 64 + t], sb);
    cvec[p * 64 + t] = sb;
  }
}

// ---------------- kernel 2: transpose tw -> Wt[h][l] bf16 (+colsum) ----------------
__global__ void k_wprep(const float* __restrict__ st_w, const float* __restrict__ tt_w,
                        bf16_t* __restrict__ Wt, float* __restrict__ S) {
  int p = blockIdx.z;
  const float* W = p ? tt_w : st_w;          // (4096, 720)
  int l0 = blockIdx.x * 64, h0 = blockIdx.y * 64;
  __shared__ float tile[64][65];
  int row = threadIdx.x >> 6, col = threadIdx.x & 63;
  int h = h0 + col;
  float partial = 0.f;
  for (int r = row; r < 64; r += 4) {
    float v = (h < Hn) ? W[(size_t)(l0 + r) * Hn + h] : 0.f;
    tile[r][col] = v;
    partial += v;
  }
  if (h < Hn) atomicAdd(&S[p * 768 + h], partial);
  __syncthreads();
  for (int a = row; a < 64; a += 4) {
    float v = tile[col][a];                  // transposed read (pad 65 -> no conflict)
    Wt[(size_t)(p * HPn + h0 + a) * Ln + l0 + col] = __float2bfloat16(v);
  }
}

// ---------------- kernel 3a: (c-quad x l-sub16) raw-x partials + LDS seg reduce ----------------
__global__ void __launch_bounds__(64) k_scanA(const float* __restrict__ x, const float* __restrict__ alpha,
                                              float* __restrict__ Psub, float* __restrict__ Pseg,
                                              float* __restrict__ Ssum, float* __restrict__ Ssq) {
  int b = blockIdx.x, s = blockIdx.y, t = threadIdx.x;
  int c4 = (t & 15) * 4, sub = t >> 4;
  float a[4], k1[4];
#pragma unroll
  for (int i = 0; i < 4; ++i) { a[i] = sigm(alpha[c4 + i]); k1[i] = 1.f - a[i]; }
  const float* xb = x + ((size_t)b * Ln + s * 64 + sub * 16) * Cn + c4;
  float pr[4] = {0.f, 0.f, 0.f, 0.f}, sm[4] = {0.f, 0.f, 0.f, 0.f}, sq[4] = {0.f, 0.f, 0.f, 0.f};
#pragma unroll
  for (int j = 0; j < 16; ++j) {
    f32x4 v = *reinterpret_cast<const f32x4*>(xb + (size_t)j * Cn);
#pragma unroll
    for (int i = 0; i < 4; ++i) {
      sm[i] += v[i];
      sq[i] = fmaf(v[i], v[i], sq[i]);
      pr[i] = fmaf(a[i], pr[i], k1[i] * v[i]);
    }
  }
  *reinterpret_cast<f32x4*>(&Psub[(((size_t)b * 64 + s) * 4 + sub) * 64 + c4]) =
      (f32x4){pr[0], pr[1], pr[2], pr[3]};
  __shared__ float lp[4][64], ls[4][64], lq[4][64];
#pragma unroll
  for (int i = 0; i < 4; ++i) { lp[sub][c4 + i] = pr[i]; ls[sub][c4 + i] = sm[i]; lq[sub][c4 + i] = sq[i]; }
  __syncthreads();
  int c = t;
  float av = sigm(alpha[c]);
  float a16 = av * av; a16 *= a16; a16 *= a16; a16 *= a16;   // a^16
  float P = ((lp[0][c] * a16 + lp[1][c]) * a16 + lp[2][c]) * a16 + lp[3][c];
  int idx = (b * 64 + s) * 64 + c;
  Pseg[idx] = P;
  Ssum[idx] = ls[0][c] + ls[1][c] + ls[2][c] + ls[3][c];
  Ssq[idx]  = lq[0][c] + lq[1][c] + lq[2][c] + lq[3][c];
}

// ---------------- kernel 3b: stats finalize + 64-step carry scan ----------------
__global__ void __launch_bounds__(64) k_scanB(const float* __restrict__ x, const float* __restrict__ alpha,
                                              const float* __restrict__ rev_w, const float* __restrict__ rev_b,
                                              const float* __restrict__ Pseg, const float* __restrict__ Ssum,
                                              const float* __restrict__ Ssq,
                                              float* __restrict__ mean, float* __restrict__ rstd,
                                              float* __restrict__ stdv, float* __restrict__ CarryIn) {
  int b = blockIdx.x, c = threadIdx.x;
  float sm = 0.f, sq = 0.f;
#pragma unroll 8
  for (int s = 0; s < 64; ++s) {
    int idx = (b * 64 + s) * 64 + c;
    sm += Ssum[idx]; sq += Ssq[idx];
  }
  float mn = sm * (1.f / 4096.f);
  float var = sq * (1.f / 4096.f) - mn * mn;
  float sd = sqrtf(var + EPSf);
  float rs = 1.f / sd;
  mean[b * 64 + c] = mn; stdv[b * 64 + c] = sd; rstd[b * 64 + c] = rs;

  float w = rev_w[c], rb = rev_b[c];
  float g = rs * w, d = rb - mn * g;         // xn = g*x + d
  float a = sigm(alpha[c]);
  float a2 = a * a, a4 = a2 * a2, a8 = a4 * a4, a16 = a8 * a8, a32 = a16 * a16;
  float a64 = a32 * a32;
  float dk1s = d * (1.f - a64);               // d * sum of (1-a)*a^k
  float carry = fmaf(g, x[((size_t)b * Ln) * Cn + c], d);   // xn[0]
  for (int so = 0; so < 8; ++so) {
    float pv[8];
#pragma unroll
    for (int i = 0; i < 8; ++i)
      pv[i] = Pseg[((size_t)(b * 64 + so * 8 + i)) * 64 + c];   // batched, independent loads
#pragma unroll
    for (int i = 0; i < 8; ++i) {
      CarryIn[((size_t)(b * 64 + so * 8 + i)) * 64 + c] = carry;
      carry = fmaf(a64, carry, fmaf(g, pv[i], dk1s));
    }
  }
}

// ---------------- kernel 3c: (c-quad x l-sub16) apply scan, write transposed bf16 ----------------
__global__ void __launch_bounds__(64) k_scanC(const float* __restrict__ x, const float* __restrict__ alpha,
                                              const float* __restrict__ rev_w, const float* __restrict__ rev_b,
                                              const float* __restrict__ mean, const float* __restrict__ rstd,
                                              const float* __restrict__ CarryIn, const float* __restrict__ Psub,
                                              bf16_t* __restrict__ Zt) {
  int b = blockIdx.x, s = blockIdx.y, t = threadIdx.x;
  int c4 = (t & 15) * 4, sub = t >> 4;
  float g[4], d[4], a[4], k1[4], a16[4], dk[4], tr[4];
#pragma unroll
  for (int i = 0; i < 4; ++i) {
    int c = c4 + i;
    float rs = rstd[b * 64 + c];
    g[i] = rs * rev_w[c]; d[i] = rev_b[c] - mean[b * 64 + c] * g[i];
    a[i] = sigm(alpha[c]); k1[i] = 1.f - a[i];
    float v = a[i] * a[i]; v *= v; v *= v; v *= v;
    a16[i] = v;
    dk[i] = d[i] * (1.f - v);
  }
  f32x4 cs = *reinterpret_cast<const f32x4*>(&CarryIn[((size_t)b * 64 + s) * 64 + c4]);
#pragma unroll
  for (int i = 0; i < 4; ++i) tr[i] = cs[i];
  for (int k = 0; k < sub; ++k) {            // compose prior subs (<=3 iters, masked)
    f32x4 p = *reinterpret_cast<const f32x4*>(&Psub[(((size_t)b * 64 + s) * 4 + k) * 64 + c4]);
#pragma unroll
    for (int i = 0; i < 4; ++i) tr[i] = fmaf(a16[i], tr[i], fmaf(g[i], p[i], dk[i]));
  }
  const float* xb = x + ((size_t)b * Ln + s * 64 + sub * 16) * Cn + c4;
  bf16x8 vs[4][2], vt[4][2];
#pragma unroll
  for (int j = 0; j < 16; ++j) {
    f32x4 v = *reinterpret_cast<const f32x4*>(xb + (size_t)j * Cn);
#pragma unroll
    for (int i = 0; i < 4; ++i) {
      float xn = fmaf(g[i], v[i], d[i]);
      tr[i] = fmaf(a[i], tr[i], k1[i] * xn);
      vs[i][j >> 3][j & 7] = f2bf(xn - tr[i]);
      vt[i][j >> 3][j & 7] = f2bf(tr[i]);
    }
  }
#pragma unroll
  for (int i = 0; i < 4; ++i) {
    int c = c4 + i;
    bf16_t* zs = Zt + ((size_t)b * 64 + c) * Ln + s * 64 + sub * 16;
    bf16_t* zt = zs + (size_t)Bn * Cn * Ln;
    *reinterpret_cast<bf16x8*>(zs) = vs[i][0];
    *reinterpret_cast<bf16x8*>(zs + 8) = vs[i][1];
    *reinterpret_cast<bf16x8*>(zt) = vt[i][0];
    *reinterpret_cast<bf16x8*>(zt + 8) = vt[i][1];
  }
}

// ---------------- kernel 5: bf16 MFMA GEMM  Osr[z,b,h,c] = sum_{l in slice} Wt[p,h,l]*Zt[p,b,c,l] ----
// 128x128 tile, 2 waves (128 thr) each owning 128x64 output; BK=32; triple-buffered LDS;
// single barrier + counted vmcnt(8) per K-step; phase-correct XOR swizzle:
//   LDS slot (row m, pos u) holds k-chunk u ^ ((m>>1)&3); read pos = hi ^ ((fr>>1)&3).
//   -> any aligned 8-lane group covers all 8 bank-quads exactly once (conflict-free).
__device__ __forceinline__ void gload16(const bf16_t* g, bf16_t* l) {
  __builtin_amdgcn_global_load_lds((const AS_GLOBAL uint32_t*)g, (AS_LDS uint32_t*)l, 16, 0, 0);
}

template <int KS>
__global__ void __launch_bounds__(128) k_gemm(const bf16_t* __restrict__ Wt, const bf16_t* __restrict__ Zt,
                                              float* __restrict__ Osr) {
  int z = blockIdx.z;
  int p = z / KS, kq = z % KS;
  const bf16_t* A  = Wt + (size_t)p * HPn * Ln;       // [768][4096]
  const bf16_t* Bz = Zt + (size_t)p * (Bn * Cn) * Ln; // [2048][4096]
  int h0 = blockIdx.y * 128, n0 = blockIdx.x * 128;
  int kbase = kq * (Ln / KS);
  const int NT = (Ln / KS) / 32;                      // K-steps of 32
  __shared__ __align__(16) bf16_t Al[3][128 * 32];
  __shared__ __align__(16) bf16_t Bl[3][128 * 32];
  int tid = threadIdx.x, w = tid >> 6, lane = tid & 63;
  int fr = lane & 15, hi = lane >> 4;
  int kc = (tid & 3) ^ ((tid >> 3) & 3);              // source k-chunk (inverse swizzle)
  const bf16_t* abase = A + (size_t)(h0 + (tid >> 2)) * Ln + kbase + kc * 8;
  const bf16_t* bbase = Bz + (size_t)(n0 + (tid >> 2)) * Ln + kbase + kc * 8;

  f32x4 acc[8][4];
#pragma unroll
  for (int i = 0; i < 8; ++i)
#pragma unroll
    for (int j = 0; j < 4; ++j) acc[i][j] = (f32x4){0.f, 0.f, 0.f, 0.f};

  auto STAGE = [&](int bufi, int kt) {
#pragma unroll
    for (int j = 0; j < 4; ++j) {
      gload16(abase + (size_t)(j * 32) * Ln + kt * 32, &Al[bufi][j * 1024 + tid * 8]);
      gload16(bbase + (size_t)(j * 32) * Ln + kt * 32, &Bl[bufi][j * 1024 + tid * 8]);
    }
  };

  int sw8 = (hi ^ ((fr >> 1) & 3)) * 8;               // swizzled chunk position (elements)
  auto COMPUTE = [&](int bufi) {
    bf16x8 afr[8], bfr[4];
#pragma unroll
    for (int i = 0; i < 8; ++i)
      afr[i] = *reinterpret_cast<const bf16x8*>(&Al[bufi][(i * 16 + fr) * 32 + sw8]);
#pragma unroll
    for (int j = 0; j < 4; ++j)
      bfr[j] = *reinterpret_cast<const bf16x8*>(&Bl[bufi][(w * 64 + j * 16 + fr) * 32 + sw8]);
    __builtin_amdgcn_s_setprio(1);
#pragma unroll
    for (int i = 0; i < 8; ++i)
#pragma unroll
      for (int j = 0; j < 4; ++j)
        acc[i][j] = __builtin_amdgcn_mfma_f32_16x16x32_bf16(afr[i], bfr[j], acc[i][j], 0, 0, 0);
    __builtin_amdgcn_s_setprio(0);
  };

  STAGE(0, 0);
  STAGE(1, 1);
  int cur = 0, nx = 2;
  for (int t = 0; t < NT; ++t) {
    __builtin_amdgcn_sched_barrier(0);
    if (t + 1 < NT) { asm volatile("s_waitcnt vmcnt(8)" ::: "memory"); }   // tile t landed; t+1 in flight
    else            { asm volatile("s_waitcnt vmcnt(0)" ::: "memory"); }
    __builtin_amdgcn_s_barrier();
    __builtin_amdgcn_sched_barrier(0);
    if (t + 2 < NT) STAGE(nx, t + 2);
    COMPUTE(cur);
    cur = (cur == 2) ? 0 : cur + 1;
    nx  = (nx == 2) ? 0 : nx + 1;
  }

#pragma unroll
  for (int i = 0; i < 8; ++i) {
#pragma unroll
    for (int j = 0; j < 4; ++j) {
#pragma unroll
      for (int r = 0; r < 4; ++r) {
        int h = h0 + i * 16 + hi * 4 + r;
        if (h < Hn) {
          int n = n0 + w * 64 + j * 16 + fr;
          int bidx = n >> 6, c = n & 63;
          Osr[(((size_t)z * Bn + bidx) * Hn + h) * Cn + c] = acc[i][j][r];
        }
      }
    }
  }
}

// ---------------- kernel 6: epilogue — sum K-slices, apply M, biases, inverse RevIN ----------------
template <int KS>
__global__ void __launch_bounds__(256) k_epi(const float* __restrict__ Osr, const float* __restrict__ M,
                                             const float* __restrict__ cvec, const float* __restrict__ S,
                                             const float* __restrict__ st_b, const float* __restrict__ tt_b,
                                             const float* __restrict__ rev_w, const float* __restrict__ rev_b,
                                             const float* __restrict__ mean, const float* __restrict__ stdv,
                                             float* __restrict__ out) {
  __shared__ float Msh[2][64][64];    // 32 KB
  __shared__ float rowS[4][64];
  __shared__ float rowT[4][64];
  int t = threadIdx.x;
  for (int i = t; i < 8192; i += 256) ((float*)Msh)[i] = M[i];
  int g = t >> 6, c = t & 63;
  float w = rev_w[c], rb = rev_b[c];
  float cs = cvec[c], ct = cvec[64 + c];
  int base = blockIdx.x * 16;
  for (int it = 0; it < 4; ++it) {
    int r = base + it * 4 + g;        // r = b*720 + h
    int b = r / 720, h = r % 720;
    __syncthreads();                  // also covers Msh load at it=0
    float vs = 0.f, vt = 0.f;
#pragma unroll
    for (int kq = 0; kq < KS; ++kq) {
      vs += Osr[(((size_t)kq * Bn + b) * Hn + h) * Cn + c];
      vt += Osr[(((size_t)(KS + kq) * Bn + b) * Hn + h) * Cn + c];
    }
    rowS[g][c] = vs;
    rowT[g][c] = vt;
    __syncthreads();
    float acc = cs * S[h] + ct * S[768 + h] + st_b[h] + tt_b[h];
    for (int cp = 0; cp < 64; ++cp)
      acc = fmaf(rowS[g][cp], Msh[0][cp][c], fmaf(rowT[g][cp], Msh[1][cp][c], acc));
    float o = (acc - rb) / (w + EPSf) * stdv[b * Cn + c] + mean[b * Cn + c];
    out[(size_t)r * 64 + c] = o;
  }
}

// ---------------- launch ----------------
extern "C" void kernel_launch(void* const* d_in, const int* in_sizes, int n_in,
                              void* d_out, int out_size, void* d_ws, size_t ws_size,
                              hipStream_t stream) {
  const float* x     = (const float*)d_in[0];
  const float* alpha = (const float*)d_in[1];
  const float* rev_w = (const float*)d_in[2];
  const float* rev_b = (const float*)d_in[3];
  const float* se_w  = (const float*)d_in[4];
  const float* se_b  = (const float*)d_in[5];
  const float* sp_w  = (const float*)d_in[6];
  const float* sp_b  = (const float*)d_in[7];
  const float* st_w  = (const float*)d_in[8];
  const float* st_b  = (const float*)d_in[9];
  const float* te_w  = (const float*)d_in[10];
  const float* te_b  = (const float*)d_in[11];
  const float* tp_w  = (const float*)d_in[12];
  const float* tp_b  = (const float*)d_in[13];
  const float* tt_w  = (const float*)d_in[14];
  const float* tt_b  = (const float*)d_in[15];
  float* out = (float*)d_out;

  const size_t SZ_WT  = (size_t)2 * HPn * Ln * 2;          // 12.58 MB
  const size_t SZ_ZT  = (size_t)2 * Bn * Cn * Ln * 2;      // 33.55 MB
  const size_t SZ_SEG = (size_t)Bn * 64 * 64 * 4;          // 0.5 MB seg-level scratch
  const size_t TAIL   = 2 * 64 * 64 * 4 + 2 * 64 * 4 + 2 * 768 * 4 + 3 * (size_t)Bn * Cn * 4;

  // KS=4 needs 8 Osr slices; KS=1 needs 2 (scan scratch: 2MB Psub + 4x0.5MB fits either way).
  const size_t NEED4 = SZ_WT + SZ_ZT + 8 * OSR_SLICE * 4 + TAIL;
  const int KS = (ws_size >= NEED4) ? 4 : 1;
  const size_t SZ_OSR = (size_t)(2 * KS) * OSR_SLICE * 4;

  char* ws = (char*)d_ws;
  bf16_t* Wt   = (bf16_t*)(ws);
  bf16_t* Zt   = (bf16_t*)(ws + SZ_WT);
  float*  Osr  = (float*)(ws + SZ_WT + SZ_ZT);
  // scan scratch aliases Osr (dead before k_gemm writes Osr)
  float*  Psub  = Osr;                                     // 2 MB
  float*  Pseg  = (float*)((char*)Psub + 4 * SZ_SEG);
  float*  Ssum  = (float*)((char*)Pseg + SZ_SEG);
  float*  Ssq   = (float*)((char*)Ssum + SZ_SEG);
  float*  Carry = (float*)((char*)Ssq + SZ_SEG);
  char* tail = ws + SZ_WT + SZ_ZT + SZ_OSR;
  float* Mbuf = (float*)tail;                 tail += 2 * 64 * 64 * 4;
  float* cvec = (float*)tail;                 tail += 2 * 64 * 4;
  float* S    = (float*)tail;                 tail += 2 * 768 * 4;
  float* mean = (float*)tail;                 tail += (size_t)Bn * Cn * 4;
  float* rstd = (float*)tail;                 tail += (size_t)Bn * Cn * 4;
  float* stdv = (float*)tail;

  hipMemsetAsync(S, 0, 2 * 768 * 4, stream);

  k_prep_small<<<32, 256, 0, stream>>>(se_w, sp_w, se_b, sp_b, te_w, tp_w, te_b, tp_b, Mbuf, cvec);
  k_wprep<<<dim3(64, 12, 2), 256, 0, stream>>>(st_w, tt_w, Wt, S);
  k_scanA<<<dim3(32, 64), 64, 0, stream>>>(x, alpha, Psub, Pseg, Ssum, Ssq);
  k_scanB<<<32, 64, 0, stream>>>(x, alpha, rev_w, rev_b, Pseg, Ssum, Ssq, mean, rstd, stdv, Carry);
  k_scanC<<<dim3(32, 64), 64, 0, stream>>>(x, alpha, rev_w, rev_b, mean, rstd, Carry, Psub, Zt);
  if (KS == 4) {
    k_gemm<4><<<dim3(16, 6, 8), 128, 0, stream>>>(Wt, Zt, Osr);
    k_epi<4><<<1440, 256, 0, stream>>>(Osr, Mbuf, cvec, S, st_b, tt_b, rev_w, rev_b, mean, stdv, out);
  } else {
    k_gemm<1><<<dim3(16, 6, 2), 128, 0, stream>>>(Wt, Zt, Osr);
    k_epi<1><<<1440, 256, 0, stream>>>(Osr, Mbuf, cvec, S, st_b, tt_b, rev_w, rev_b, mean, stdv, out);
  }
}

// Round 5
// 144.281 us; speedup vs baseline: 5.3675x; 1.0563x over previous
//
#include <hip/hip_runtime.h>
#include <hip/hip_bf16.h>
#include <string.h>
#include <stdint.h>

typedef __hip_bfloat16 bf16_t;
typedef float f32x4 __attribute__((ext_vector_type(4)));
typedef short bf16x8 __attribute__((ext_vector_type(8)));

#define AS_GLOBAL __attribute__((address_space(1)))
#define AS_LDS    __attribute__((address_space(3)))

static constexpr int Bn = 32, Ln = 4096, Cn = 64, Hn = 720, HPn = 768;
static constexpr float EPSf = 1e-5f;

static constexpr size_t OSR_SLICE = (size_t)Bn * Hn * Cn;   // f32 elements per K-slice per path

__device__ __forceinline__ short f2bf(float f) {
  bf16_t h = __float2bfloat16(f);
  unsigned short u; memcpy(&u, &h, 2);
  return (short)u;
}

__device__ __forceinline__ float sigm(float v) { return 1.f / (1.f + expf(-v)); }

// ---------------- kernel 1: fold the two 64->512->64 MLPs ----------------
__global__ void k_prep_small(const float* __restrict__ se_w, const float* __restrict__ sp_w,
                             const float* __restrict__ se_b, const float* __restrict__ sp_b,
                             const float* __restrict__ te_w, const float* __restrict__ tp_w,
                             const float* __restrict__ te_b, const float* __restrict__ tp_b,
                             float* __restrict__ M, float* __restrict__ cvec) {
  int p = blockIdx.x >> 4, sub = blockIdx.x & 15;
  const float* ew = p ? te_w : se_w;   // (64,512)
  const float* pw = p ? tp_w : sp_w;   // (512,64)
  const float* eb = p ? te_b : se_b;   // (512,)
  const float* pb = p ? tp_b : sp_b;   // (64,)
  int idx = sub * 256 + threadIdx.x;   // 0..4095
  int cp = idx >> 6, c = idx & 63;
  float s = 0.f;
  for (int d = 0; d < 512; ++d) s = fmaf(ew[cp * 512 + d], pw[d * 64 + c], s);
  M[p * 4096 + idx] = s;
  if (sub == 0 && threadIdx.x < 64) {
    int t = threadIdx.x;
    float sb = pb[t];
    for (int d = 0; d < 512; ++d) sb = fmaf(eb[d], pw[d * 64 + t], sb);
    cvec[p * 64 + t] = sb;
  }
}

// ---------------- kernel 2: transpose tw -> Wt[h][l] bf16 (+colsum) ----------------
__global__ void k_wprep(const float* __restrict__ st_w, const float* __restrict__ tt_w,
                        bf16_t* __restrict__ Wt, float* __restrict__ S) {
  int p = blockIdx.z;
  const float* W = p ? tt_w : st_w;          // (4096, 720)
  int l0 = blockIdx.x * 64, h0 = blockIdx.y * 64;
  __shared__ float tile[64][65];
  int row = threadIdx.x >> 6, col = threadIdx.x & 63;
  int h = h0 + col;
  float partial = 0.f;
  for (int r = row; r < 64; r += 4) {
    float v = (h < Hn) ? W[(size_t)(l0 + r) * Hn + h] : 0.f;
    tile[r][col] = v;
    partial += v;
  }
  if (h < Hn) atomicAdd(&S[p * 768 + h], partial);
  __syncthreads();
  for (int a = row; a < 64; a += 4) {
    float v = tile[col][a];                  // transposed read (pad 65 -> no conflict)
    Wt[(size_t)(p * HPn + h0 + a) * Ln + l0 + col] = __float2bfloat16(v);
  }
}

// ---------------- kernel 3a: (c-quad x l-sub16) raw-x partials + LDS seg reduce ----------------
__global__ void __launch_bounds__(64) k_scanA(const float* __restrict__ x, const float* __restrict__ alpha,
                                              float* __restrict__ Psub, float* __restrict__ Pseg,
                                              float* __restrict__ Ssum, float* __restrict__ Ssq) {
  int b = blockIdx.x, s = blockIdx.y, t = threadIdx.x;
  int c4 = (t & 15) * 4, sub = t >> 4;
  float a[4], k1[4];
#pragma unroll
  for (int i = 0; i < 4; ++i) { a[i] = sigm(alpha[c4 + i]); k1[i] = 1.f - a[i]; }
  const float* xb = x + ((size_t)b * Ln + s * 64 + sub * 16) * Cn + c4;
  float pr[4] = {0.f, 0.f, 0.f, 0.f}, sm[4] = {0.f, 0.f, 0.f, 0.f}, sq[4] = {0.f, 0.f, 0.f, 0.f};
#pragma unroll
  for (int j = 0; j < 16; ++j) {
    f32x4 v = *reinterpret_cast<const f32x4*>(xb + (size_t)j * Cn);
#pragma unroll
    for (int i = 0; i < 4; ++i) {
      sm[i] += v[i];
      sq[i] = fmaf(v[i], v[i], sq[i]);
      pr[i] = fmaf(a[i], pr[i], k1[i] * v[i]);
    }
  }
  *reinterpret_cast<f32x4*>(&Psub[(((size_t)b * 64 + s) * 4 + sub) * 64 + c4]) =
      (f32x4){pr[0], pr[1], pr[2], pr[3]};
  __shared__ float lp[4][64], ls[4][64], lq[4][64];
#pragma unroll
  for (int i = 0; i < 4; ++i) { lp[sub][c4 + i] = pr[i]; ls[sub][c4 + i] = sm[i]; lq[sub][c4 + i] = sq[i]; }
  __syncthreads();
  int c = t;
  float av = sigm(alpha[c]);
  float a16 = av * av; a16 *= a16; a16 *= a16; a16 *= a16;   // a^16
  float P = ((lp[0][c] * a16 + lp[1][c]) * a16 + lp[2][c]) * a16 + lp[3][c];
  int idx = (b * 64 + s) * 64 + c;
  Pseg[idx] = P;
  Ssum[idx] = ls[0][c] + ls[1][c] + ls[2][c] + ls[3][c];
  Ssq[idx]  = lq[0][c] + lq[1][c] + lq[2][c] + lq[3][c];
}

// ---------------- kernel 3b: stats finalize + 64-step carry scan ----------------
__global__ void __launch_bounds__(64) k_scanB(const float* __restrict__ x, const float* __restrict__ alpha,
                                              const float* __restrict__ rev_w, const float* __restrict__ rev_b,
                                              const float* __restrict__ Pseg, const float* __restrict__ Ssum,
                                              const float* __restrict__ Ssq,
                                              float* __restrict__ mean, float* __restrict__ rstd,
                                              float* __restrict__ stdv, float* __restrict__ CarryIn) {
  int b = blockIdx.x, c = threadIdx.x;
  float sm = 0.f, sq = 0.f;
#pragma unroll 8
  for (int s = 0; s < 64; ++s) {
    int idx = (b * 64 + s) * 64 + c;
    sm += Ssum[idx]; sq += Ssq[idx];
  }
  float mn = sm * (1.f / 4096.f);
  float var = sq * (1.f / 4096.f) - mn * mn;
  float sd = sqrtf(var + EPSf);
  float rs = 1.f / sd;
  mean[b * 64 + c] = mn; stdv[b * 64 + c] = sd; rstd[b * 64 + c] = rs;

  float w = rev_w[c], rb = rev_b[c];
  float g = rs * w, d = rb - mn * g;         // xn = g*x + d
  float a = sigm(alpha[c]);
  float a2 = a * a, a4 = a2 * a2, a8 = a4 * a4, a16 = a8 * a8, a32 = a16 * a16;
  float a64 = a32 * a32;
  float dk1s = d * (1.f - a64);               // d * sum of (1-a)*a^k
  float carry = fmaf(g, x[((size_t)b * Ln) * Cn + c], d);   // xn[0]
  for (int so = 0; so < 8; ++so) {
    float pv[8];
#pragma unroll
    for (int i = 0; i < 8; ++i)
      pv[i] = Pseg[((size_t)(b * 64 + so * 8 + i)) * 64 + c];   // batched, independent loads
#pragma unroll
    for (int i = 0; i < 8; ++i) {
      CarryIn[((size_t)(b * 64 + so * 8 + i)) * 64 + c] = carry;
      carry = fmaf(a64, carry, fmaf(g, pv[i], dk1s));
    }
  }
}

// ---------------- kernel 3c: (c-quad x l-sub16) apply scan, write transposed bf16 ----------------
__global__ void __launch_bounds__(64) k_scanC(const float* __restrict__ x, const float* __restrict__ alpha,
                                              const float* __restrict__ rev_w, const float* __restrict__ rev_b,
                                              const float* __restrict__ mean, const float* __restrict__ rstd,
                                              const float* __restrict__ CarryIn, const float* __restrict__ Psub,
                                              bf16_t* __restrict__ Zt) {
  int b = blockIdx.x, s = blockIdx.y, t = threadIdx.x;
  int c4 = (t & 15) * 4, sub = t >> 4;
  float g[4], d[4], a[4], k1[4], a16[4], dk[4], tr[4];
#pragma unroll
  for (int i = 0; i < 4; ++i) {
    int c = c4 + i;
    float rs = rstd[b * 64 + c];
    g[i] = rs * rev_w[c]; d[i] = rev_b[c] - mean[b * 64 + c] * g[i];
    a[i] = sigm(alpha[c]); k1[i] = 1.f - a[i];
    float v = a[i] * a[i]; v *= v; v *= v; v *= v;
    a16[i] = v;
    dk[i] = d[i] * (1.f - v);
  }
  f32x4 cs = *reinterpret_cast<const f32x4*>(&CarryIn[((size_t)b * 64 + s) * 64 + c4]);
#pragma unroll
  for (int i = 0; i < 4; ++i) tr[i] = cs[i];
  for (int k = 0; k < sub; ++k) {            // compose prior subs (<=3 iters, masked)
    f32x4 p = *reinterpret_cast<const f32x4*>(&Psub[(((size_t)b * 64 + s) * 4 + k) * 64 + c4]);
#pragma unroll
    for (int i = 0; i < 4; ++i) tr[i] = fmaf(a16[i], tr[i], fmaf(g[i], p[i], dk[i]));
  }
  const float* xb = x + ((size_t)b * Ln + s * 64 + sub * 16) * Cn + c4;
  bf16x8 vs[4][2], vt[4][2];
#pragma unroll
  for (int j = 0; j < 16; ++j) {
    f32x4 v = *reinterpret_cast<const f32x4*>(xb + (size_t)j * Cn);
#pragma unroll
    for (int i = 0; i < 4; ++i) {
      float xn = fmaf(g[i], v[i], d[i]);
      tr[i] = fmaf(a[i], tr[i], k1[i] * xn);
      vs[i][j >> 3][j & 7] = f2bf(xn - tr[i]);
      vt[i][j >> 3][j & 7] = f2bf(tr[i]);
    }
  }
#pragma unroll
  for (int i = 0; i < 4; ++i) {
    int c = c4 + i;
    bf16_t* zs = Zt + ((size_t)b * 64 + c) * Ln + s * 64 + sub * 16;
    bf16_t* zt = zs + (size_t)Bn * Cn * Ln;
    *reinterpret_cast<bf16x8*>(zs) = vs[i][0];
    *reinterpret_cast<bf16x8*>(zs + 8) = vs[i][1];
    *reinterpret_cast<bf16x8*>(zt) = vt[i][0];
    *reinterpret_cast<bf16x8*>(zt + 8) = vt[i][1];
  }
}

// ---------------- kernel 5: bf16 MFMA GEMM  Osr[z,b,h,c] = sum_{l in slice} Wt[p,h,l]*Zt[p,b,c,l] ----
// 128x128 tile, 256 thr / 4 waves (2x2, per-wave 64x64, 4x4 16x16x32 frags); BK=32;
// triple-buffered LDS (48KB -> 3 blocks/CU); single barrier + counted vmcnt(4) per K-step;
// conflict-free XOR swizzle (proven 0 conflicts in round 4):
//   LDS row m, slot u holds k-chunk u ^ ((m>>1)&3); read slot = hi ^ ((fr>>1)&3).
__device__ __forceinline__ void gload16(const bf16_t* g, bf16_t* l) {
  __builtin_amdgcn_global_load_lds((const AS_GLOBAL uint32_t*)g, (AS_LDS uint32_t*)l, 16, 0, 0);
}

template <int KS>
__global__ void __launch_bounds__(256, 3) k_gemm(const bf16_t* __restrict__ Wt, const bf16_t* __restrict__ Zt,
                                                 float* __restrict__ Osr) {
  int z = blockIdx.z;
  int p = z / KS, kq = z % KS;
  const bf16_t* A  = Wt + (size_t)p * HPn * Ln;       // [768][4096]
  const bf16_t* Bz = Zt + (size_t)p * (Bn * Cn) * Ln; // [2048][4096]
  int h0 = blockIdx.y * 128, n0 = blockIdx.x * 128;
  int kbase = kq * (Ln / KS);
  const int NT = (Ln / KS) / 32;                      // K-steps of 32
  __shared__ __align__(16) bf16_t Al[3][128 * 32];
  __shared__ __align__(16) bf16_t Bl[3][128 * 32];
  int tid = threadIdx.x, wid = tid >> 6, lane = tid & 63;
  int wr = wid >> 1, wc = wid & 1;
  int fr = lane & 15, hi = lane >> 4;
  // staging: thread t covers LDS rows (t>>2) and 64+(t>>2), slot t&3;
  // source k-chunk inverse-swizzled: kc = (t&3) ^ ((t>>3)&3)  (row>>1 &3 == (t>>3)&3)
  int kc = (tid & 3) ^ ((tid >> 3) & 3);
  const bf16_t* abase = A + (size_t)(h0 + (tid >> 2)) * Ln + kbase + kc * 8;
  const bf16_t* bbase = Bz + (size_t)(n0 + (tid >> 2)) * Ln + kbase + kc * 8;

  f32x4 acc[4][4];
#pragma unroll
  for (int i = 0; i < 4; ++i)
#pragma unroll
    for (int j = 0; j < 4; ++j) acc[i][j] = (f32x4){0.f, 0.f, 0.f, 0.f};

  auto STAGE = [&](int bufi, int kt) {
    gload16(abase + (size_t)kt * 32, &Al[bufi][tid * 8]);
    gload16(abase + (size_t)64 * Ln + kt * 32, &Al[bufi][2048 + tid * 8]);
    gload16(bbase + (size_t)kt * 32, &Bl[bufi][tid * 8]);
    gload16(bbase + (size_t)64 * Ln + kt * 32, &Bl[bufi][2048 + tid * 8]);
  };

  int sw8 = (hi ^ ((fr >> 1) & 3)) * 8;               // swizzled chunk position (elements)
  auto COMPUTE = [&](int bufi) {
    bf16x8 afr[4], bfr[4];
#pragma unroll
    for (int i = 0; i < 4; ++i)
      afr[i] = *reinterpret_cast<const bf16x8*>(&Al[bufi][(wr * 64 + i * 16 + fr) * 32 + sw8]);
#pragma unroll
    for (int j = 0; j < 4; ++j)
      bfr[j] = *reinterpret_cast<const bf16x8*>(&Bl[bufi][(wc * 64 + j * 16 + fr) * 32 + sw8]);
    __builtin_amdgcn_s_setprio(1);
#pragma unroll
    for (int i = 0; i < 4; ++i)
#pragma unroll
      for (int j = 0; j < 4; ++j)
        acc[i][j] = __builtin_amdgcn_mfma_f32_16x16x32_bf16(afr[i], bfr[j], acc[i][j], 0, 0, 0);
    __builtin_amdgcn_s_setprio(0);
  };

  STAGE(0, 0);
  STAGE(1, 1);
  int cur = 0, nx = 2;
  for (int t = 0; t < NT; ++t) {
    __builtin_amdgcn_sched_barrier(0);
    if (t + 1 < NT) { asm volatile("s_waitcnt vmcnt(4)" ::: "memory"); }   // tile t landed; t+1 in flight
    else            { asm volatile("s_waitcnt vmcnt(0)" ::: "memory"); }
    __builtin_amdgcn_s_barrier();
    __builtin_amdgcn_sched_barrier(0);
    if (t + 2 < NT) STAGE(nx, t + 2);
    COMPUTE(cur);
    cur = (cur == 2) ? 0 : cur + 1;
    nx  = (nx == 2) ? 0 : nx + 1;
  }

#pragma unroll
  for (int i = 0; i < 4; ++i) {
#pragma unroll
    for (int j = 0; j < 4; ++j) {
#pragma unroll
      for (int r = 0; r < 4; ++r) {
        int m = wr * 64 + i * 16 + hi * 4 + r;
        int h = h0 + m;
        if (h < Hn) {
          int n = n0 + wc * 64 + j * 16 + fr;
          int bidx = n >> 6, c = n & 63;
          Osr[(((size_t)z * Bn + bidx) * Hn + h) * Cn + c] = acc[i][j][r];
        }
      }
    }
  }
}

// ---------------- kernel 6: epilogue — sum K-slices, apply M, biases, inverse RevIN ----------------
template <int KS>
__global__ void __launch_bounds__(256) k_epi(const float* __restrict__ Osr, const float* __restrict__ M,
                                             const float* __restrict__ cvec, const float* __restrict__ S,
                                             const float* __restrict__ st_b, const float* __restrict__ tt_b,
                                             const float* __restrict__ rev_w, const float* __restrict__ rev_b,
                                             const float* __restrict__ mean, const float* __restrict__ stdv,
                                             float* __restrict__ out) {
  __shared__ float Msh[2][64][64];    // 32 KB
  __shared__ float rowS[4][64];
  __shared__ float rowT[4][64];
  int t = threadIdx.x;
  for (int i = t; i < 8192; i += 256) ((float*)Msh)[i] = M[i];
  int g = t >> 6, c = t & 63;
  float w = rev_w[c], rb = rev_b[c];
  float cs = cvec[c], ct = cvec[64 + c];
  int base = blockIdx.x * 16;
  for (int it = 0; it < 4; ++it) {
    int r = base + it * 4 + g;        // r = b*720 + h
    int b = r / 720, h = r % 720;
    __syncthreads();                  // also covers Msh load at it=0
    float vs = 0.f, vt = 0.f;
#pragma unroll
    for (int kq = 0; kq < KS; ++kq) {
      vs += Osr[(((size_t)kq * Bn + b) * Hn + h) * Cn + c];
      vt += Osr[(((size_t)(KS + kq) * Bn + b) * Hn + h) * Cn + c];
    }
    rowS[g][c] = vs;
    rowT[g][c] = vt;
    __syncthreads();
    float acc = cs * S[h] + ct * S[768 + h] + st_b[h] + tt_b[h];
    for (int cp = 0; cp < 64; ++cp)
      acc = fmaf(rowS[g][cp], Msh[0][cp][c], fmaf(rowT[g][cp], Msh[1][cp][c], acc));
    float o = (acc - rb) / (w + EPSf) * stdv[b * Cn + c] + mean[b * Cn + c];
    out[(size_t)r * 64 + c] = o;
  }
}

// ---------------- launch ----------------
extern "C" void kernel_launch(void* const* d_in, const int* in_sizes, int n_in,
                              void* d_out, int out_size, void* d_ws, size_t ws_size,
                              hipStream_t stream) {
  const float* x     = (const float*)d_in[0];
  const float* alpha = (const float*)d_in[1];
  const float* rev_w = (const float*)d_in[2];
  const float* rev_b = (const float*)d_in[3];
  const float* se_w  = (const float*)d_in[4];
  const float* se_b  = (const float*)d_in[5];
  const float* sp_w  = (const float*)d_in[6];
  const float* sp_b  = (const float*)d_in[7];
  const float* st_w  = (const float*)d_in[8];
  const float* st_b  = (const float*)d_in[9];
  const float* te_w  = (const float*)d_in[10];
  const float* te_b  = (const float*)d_in[11];
  const float* tp_w  = (const float*)d_in[12];
  const float* tp_b  = (const float*)d_in[13];
  const float* tt_w  = (const float*)d_in[14];
  const float* tt_b  = (const float*)d_in[15];
  float* out = (float*)d_out;

  const size_t SZ_WT  = (size_t)2 * HPn * Ln * 2;          // 12.58 MB
  const size_t SZ_ZT  = (size_t)2 * Bn * Cn * Ln * 2;      // 33.55 MB
  const size_t SZ_SEG = (size_t)Bn * 64 * 64 * 4;          // 0.5 MB seg-level scratch
  const size_t TAIL   = 2 * 64 * 64 * 4 + 2 * 64 * 4 + 2 * 768 * 4 + 3 * (size_t)Bn * Cn * 4;

  // KS=4 needs 8 Osr slices; KS=1 needs 2 (scan scratch: 2MB Psub + 4x0.5MB fits either way).
  const size_t NEED4 = SZ_WT + SZ_ZT + 8 * OSR_SLICE * 4 + TAIL;
  const int KS = (ws_size >= NEED4) ? 4 : 1;
  const size_t SZ_OSR = (size_t)(2 * KS) * OSR_SLICE * 4;

  char* ws = (char*)d_ws;
  bf16_t* Wt   = (bf16_t*)(ws);
  bf16_t* Zt   = (bf16_t*)(ws + SZ_WT);
  float*  Osr  = (float*)(ws + SZ_WT + SZ_ZT);
  // scan scratch aliases Osr (dead before k_gemm writes Osr)
  float*  Psub  = Osr;                                     // 2 MB
  float*  Pseg  = (float*)((char*)Psub + 4 * SZ_SEG);
  float*  Ssum  = (float*)((char*)Pseg + SZ_SEG);
  float*  Ssq   = (float*)((char*)Ssum + SZ_SEG);
  float*  Carry = (float*)((char*)Ssq + SZ_SEG);
  char* tail = ws + SZ_WT + SZ_ZT + SZ_OSR;
  float* Mbuf = (float*)tail;                 tail += 2 * 64 * 64 * 4;
  float* cvec = (float*)tail;                 tail += 2 * 64 * 4;
  float* S    = (float*)tail;                 tail += 2 * 768 * 4;
  float* mean = (float*)tail;                 tail += (size_t)Bn * Cn * 4;
  float* rstd = (float*)tail;                 tail += (size_t)Bn * Cn * 4;
  float* stdv = (float*)tail;

  hipMemsetAsync(S, 0, 2 * 768 * 4, stream);

  k_prep_small<<<32, 256, 0, stream>>>(se_w, sp_w, se_b, sp_b, te_w, tp_w, te_b, tp_b, Mbuf, cvec);
  k_wprep<<<dim3(64, 12, 2), 256, 0, stream>>>(st_w, tt_w, Wt, S);
  k_scanA<<<dim3(32, 64), 64, 0, stream>>>(x, alpha, Psub, Pseg, Ssum, Ssq);
  k_scanB<<<32, 64, 0, stream>>>(x, alpha, rev_w, rev_b, Pseg, Ssum, Ssq, mean, rstd, stdv, Carry);
  k_scanC<<<dim3(32, 64), 64, 0, stream>>>(x, alpha, rev_w, rev_b, mean, rstd, Carry, Psub, Zt);
  if (KS == 4) {
    k_gemm<4><<<dim3(16, 6, 8), 256, 0, stream>>>(Wt, Zt, Osr);
    k_epi<4><<<1440, 256, 0, stream>>>(Osr, Mbuf, cvec, S, st_b, tt_b, rev_w, rev_b, mean, stdv, out);
  } else {
    k_gemm<1><<<dim3(16, 6, 2), 256, 0, stream>>>(Wt, Zt, Osr);
    k_epi<1><<<1440, 256, 0, stream>>>(Osr, Mbuf, cvec, S, st_b, tt_b, rev_w, rev_b, mean, stdv, out);
  }
}

// Round 6
// 131.341 us; speedup vs baseline: 5.8963x; 1.0985x over previous
//
#include <hip/hip_runtime.h>
#include <hip/hip_bf16.h>
#include <string.h>
#include <stdint.h>

typedef __hip_bfloat16 bf16_t;
typedef float f32x4 __attribute__((ext_vector_type(4)));
typedef short bf16x8 __attribute__((ext_vector_type(8)));

#define AS_GLOBAL __attribute__((address_space(1)))
#define AS_LDS    __attribute__((address_space(3)))

static constexpr int Bn = 32, Ln = 4096, Cn = 64, Hn = 720, HPn = 768;
static constexpr float EPSf = 1e-5f;

static constexpr size_t OSR_SLICE = (size_t)Bn * Hn * Cn;   // f32 elements per K-slice per path

__device__ __forceinline__ short f2bf(float f) {
  bf16_t h = __float2bfloat16(f);
  unsigned short u; memcpy(&u, &h, 2);
  return (short)u;
}

__device__ __forceinline__ float sigm(float v) { return 1.f / (1.f + expf(-v)); }

// ---------------- kernel 1: fold the two 64->512->64 MLPs (d-chunked, LDS-tiled) ----------------
// grid (8 d-chunks, 2 paths) x 256 thr. Partial 64x64 outer-product chunk -> atomicAdd into M.
// M/cvec zeroed by the launch-side memset.
__global__ void __launch_bounds__(256) k_prep(const float* __restrict__ se_w, const float* __restrict__ sp_w,
                                              const float* __restrict__ se_b, const float* __restrict__ sp_b,
                                              const float* __restrict__ te_w, const float* __restrict__ tp_w,
                                              const float* __restrict__ te_b, const float* __restrict__ tp_b,
                                              float* __restrict__ M, float* __restrict__ cvec) {
  int p = blockIdx.y, dc = blockIdx.x, t = threadIdx.x;
  const float* ew = p ? te_w : se_w;   // (64,512)
  const float* pw = p ? tp_w : sp_w;   // (512,64)
  const float* eb = p ? te_b : se_b;   // (512,)
  const float* pb = p ? tp_b : sp_b;   // (64,)
  int d0 = dc * 64;
  __shared__ float ews[64][68];        // [row r][dd]
  __shared__ float pws[64][68];        // [dd][c]
  __shared__ float ebs[64];
#pragma unroll
  for (int q = 0; q < 4; ++q) {        // stage: 4 float4 per thread per array (coalesced)
    int fi = t * 4 + q;
    int r = fi >> 4, dd = (fi * 4) & 63;
    *reinterpret_cast<f32x4*>(&ews[r][dd]) = *reinterpret_cast<const f32x4*>(&ew[r * 512 + d0 + dd]);
    int pdd = fi >> 4, c = (fi * 4) & 63;
    *reinterpret_cast<f32x4*>(&pws[pdd][c]) = *reinterpret_cast<const f32x4*>(&pw[(d0 + pdd) * 64 + c]);
  }
  if (t < 64) ebs[t] = eb[d0 + t];
  __syncthreads();
  int r0 = (t >> 4) * 4, c0 = (t & 15) * 4;
  float acc[4][4];
#pragma unroll
  for (int i = 0; i < 4; ++i)
#pragma unroll
    for (int j = 0; j < 4; ++j) acc[i][j] = 0.f;
#pragma unroll 4
  for (int g = 0; g < 16; ++g) {
    int dd = g * 4;
    f32x4 av[4], bv[4];
#pragma unroll
    for (int i = 0; i < 4; ++i) av[i] = *reinterpret_cast<const f32x4*>(&ews[r0 + i][dd]);
#pragma unroll
    for (int d = 0; d < 4; ++d) bv[d] = *reinterpret_cast<const f32x4*>(&pws[dd + d][c0]);
#pragma unroll
    for (int d = 0; d < 4; ++d)
#pragma unroll
      for (int i = 0; i < 4; ++i)
#pragma unroll
        for (int j = 0; j < 4; ++j) acc[i][j] = fmaf(av[i][d], bv[d][j], acc[i][j]);
  }
#pragma unroll
  for (int i = 0; i < 4; ++i)
#pragma unroll
    for (int j = 0; j < 4; ++j)
      atomicAdd(&M[p * 4096 + (r0 + i) * 64 + c0 + j], acc[i][j]);
  if (t < 64) {
    float s = (dc == 0) ? pb[t] : 0.f;
#pragma unroll 8
    for (int dd = 0; dd < 64; ++dd) s = fmaf(ebs[dd], pws[dd][t], s);
    atomicAdd(&cvec[p * 64 + t], s);
  }
}

// ---------------- kernel 2: transpose tw -> Wt[h][l] bf16 (+colsum) ----------------
__global__ void k_wprep(const float* __restrict__ st_w, const float* __restrict__ tt_w,
                        bf16_t* __restrict__ Wt, float* __restrict__ S) {
  int p = blockIdx.z;
  const float* W = p ? tt_w : st_w;          // (4096, 720)
  int l0 = blockIdx.x * 64, h0 = blockIdx.y * 64;
  __shared__ float tile[64][65];
  int row = threadIdx.x >> 6, col = threadIdx.x & 63;
  int h = h0 + col;
  float partial = 0.f;
  for (int r = row; r < 64; r += 4) {
    float v = (h < Hn) ? W[(size_t)(l0 + r) * Hn + h] : 0.f;
    tile[r][col] = v;
    partial += v;
  }
  if (h < Hn) atomicAdd(&S[p * 768 + h], partial);
  __syncthreads();
  for (int a = row; a < 64; a += 4) {
    float v = tile[col][a];                  // transposed read (pad 65 -> no conflict)
    Wt[(size_t)(p * HPn + h0 + a) * Ln + l0 + col] = __float2bfloat16(v);
  }
}

// ---------------- kernel 3a: (c-quad x l-sub16) raw-x partials + LDS seg reduce ----------------
__global__ void __launch_bounds__(64) k_scanA(const float* __restrict__ x, const float* __restrict__ alpha,
                                              float* __restrict__ Psub, float* __restrict__ Pseg,
                                              float* __restrict__ Ssum, float* __restrict__ Ssq) {
  int b = blockIdx.x, s = blockIdx.y, t = threadIdx.x;
  int c4 = (t & 15) * 4, sub = t >> 4;
  float a[4], k1[4];
#pragma unroll
  for (int i = 0; i < 4; ++i) { a[i] = sigm(alpha[c4 + i]); k1[i] = 1.f - a[i]; }
  const float* xb = x + ((size_t)b * Ln + s * 64 + sub * 16) * Cn + c4;
  float pr[4] = {0.f, 0.f, 0.f, 0.f}, sm[4] = {0.f, 0.f, 0.f, 0.f}, sq[4] = {0.f, 0.f, 0.f, 0.f};
#pragma unroll
  for (int j = 0; j < 16; ++j) {
    f32x4 v = *reinterpret_cast<const f32x4*>(xb + (size_t)j * Cn);
#pragma unroll
    for (int i = 0; i < 4; ++i) {
      sm[i] += v[i];
      sq[i] = fmaf(v[i], v[i], sq[i]);
      pr[i] = fmaf(a[i], pr[i], k1[i] * v[i]);
    }
  }
  *reinterpret_cast<f32x4*>(&Psub[(((size_t)b * 64 + s) * 4 + sub) * 64 + c4]) =
      (f32x4){pr[0], pr[1], pr[2], pr[3]};
  __shared__ float lp[4][64], ls[4][64], lq[4][64];
#pragma unroll
  for (int i = 0; i < 4; ++i) { lp[sub][c4 + i] = pr[i]; ls[sub][c4 + i] = sm[i]; lq[sub][c4 + i] = sq[i]; }
  __syncthreads();
  int c = t;
  float av = sigm(alpha[c]);
  float a16 = av * av; a16 *= a16; a16 *= a16; a16 *= a16;   // a^16
  float P = ((lp[0][c] * a16 + lp[1][c]) * a16 + lp[2][c]) * a16 + lp[3][c];
  int idx = (b * 64 + s) * 64 + c;
  Pseg[idx] = P;
  Ssum[idx] = ls[0][c] + ls[1][c] + ls[2][c] + ls[3][c];
  Ssq[idx]  = lq[0][c] + lq[1][c] + lq[2][c] + lq[3][c];
}

// ---------------- kernel 3b: stats finalize + 64-step carry scan ----------------
__global__ void __launch_bounds__(64) k_scanB(const float* __restrict__ x, const float* __restrict__ alpha,
                                              const float* __restrict__ rev_w, const float* __restrict__ rev_b,
                                              const float* __restrict__ Pseg, const float* __restrict__ Ssum,
                                              const float* __restrict__ Ssq,
                                              float* __restrict__ mean, float* __restrict__ rstd,
                                              float* __restrict__ stdv, float* __restrict__ CarryIn) {
  int b = blockIdx.x, c = threadIdx.x;
  float sm = 0.f, sq = 0.f;
#pragma unroll 8
  for (int s = 0; s < 64; ++s) {
    int idx = (b * 64 + s) * 64 + c;
    sm += Ssum[idx]; sq += Ssq[idx];
  }
  float mn = sm * (1.f / 4096.f);
  float var = sq * (1.f / 4096.f) - mn * mn;
  float sd = sqrtf(var + EPSf);
  float rs = 1.f / sd;
  mean[b * 64 + c] = mn; stdv[b * 64 + c] = sd; rstd[b * 64 + c] = rs;

  float w = rev_w[c], rb = rev_b[c];
  float g = rs * w, d = rb - mn * g;         // xn = g*x + d
  float a = sigm(alpha[c]);
  float a2 = a * a, a4 = a2 * a2, a8 = a4 * a4, a16 = a8 * a8, a32 = a16 * a16;
  float a64 = a32 * a32;
  float dk1s = d * (1.f - a64);               // d * sum of (1-a)*a^k
  float carry = fmaf(g, x[((size_t)b * Ln) * Cn + c], d);   // xn[0]
  for (int so = 0; so < 8; ++so) {
    float pv[8];
#pragma unroll
    for (int i = 0; i < 8; ++i)
      pv[i] = Pseg[((size_t)(b * 64 + so * 8 + i)) * 64 + c];   // batched, independent loads
#pragma unroll
    for (int i = 0; i < 8; ++i) {
      CarryIn[((size_t)(b * 64 + so * 8 + i)) * 64 + c] = carry;
      carry = fmaf(a64, carry, fmaf(g, pv[i], dk1s));
    }
  }
}

// ---------------- kernel 3c: (c-quad x l-sub16) apply scan, write transposed bf16 ----------------
__global__ void __launch_bounds__(64) k_scanC(const float* __restrict__ x, const float* __restrict__ alpha,
                                              const float* __restrict__ rev_w, const float* __restrict__ rev_b,
                                              const float* __restrict__ mean, const float* __restrict__ rstd,
                                              const float* __restrict__ CarryIn, const float* __restrict__ Psub,
                                              bf16_t* __restrict__ Zt) {
  int b = blockIdx.x, s = blockIdx.y, t = threadIdx.x;
  int c4 = (t & 15) * 4, sub = t >> 4;
  float g[4], d[4], a[4], k1[4], a16[4], dk[4], tr[4];
#pragma unroll
  for (int i = 0; i < 4; ++i) {
    int c = c4 + i;
    float rs = rstd[b * 64 + c];
    g[i] = rs * rev_w[c]; d[i] = rev_b[c] - mean[b * 64 + c] * g[i];
    a[i] = sigm(alpha[c]); k1[i] = 1.f - a[i];
    float v = a[i] * a[i]; v *= v; v *= v; v *= v;
    a16[i] = v;
    dk[i] = d[i] * (1.f - v);
  }
  f32x4 cs = *reinterpret_cast<const f32x4*>(&CarryIn[((size_t)b * 64 + s) * 64 + c4]);
#pragma unroll
  for (int i = 0; i < 4; ++i) tr[i] = cs[i];
  for (int k = 0; k < sub; ++k) {            // compose prior subs (<=3 iters, masked)
    f32x4 p = *reinterpret_cast<const f32x4*>(&Psub[(((size_t)b * 64 + s) * 4 + k) * 64 + c4]);
#pragma unroll
    for (int i = 0; i < 4; ++i) tr[i] = fmaf(a16[i], tr[i], fmaf(g[i], p[i], dk[i]));
  }
  const float* xb = x + ((size_t)b * Ln + s * 64 + sub * 16) * Cn + c4;
  bf16x8 vs[4][2], vt[4][2];
#pragma unroll
  for (int j = 0; j < 16; ++j) {
    f32x4 v = *reinterpret_cast<const f32x4*>(xb + (size_t)j * Cn);
#pragma unroll
    for (int i = 0; i < 4; ++i) {
      float xn = fmaf(g[i], v[i], d[i]);
      tr[i] = fmaf(a[i], tr[i], k1[i] * xn);
      vs[i][j >> 3][j & 7] = f2bf(xn - tr[i]);
      vt[i][j >> 3][j & 7] = f2bf(tr[i]);
    }
  }
#pragma unroll
  for (int i = 0; i < 4; ++i) {
    int c = c4 + i;
    bf16_t* zs = Zt + ((size_t)b * 64 + c) * Ln + s * 64 + sub * 16;
    bf16_t* zt = zs + (size_t)Bn * Cn * Ln;
    *reinterpret_cast<bf16x8*>(zs) = vs[i][0];
    *reinterpret_cast<bf16x8*>(zs + 8) = vs[i][1];
    *reinterpret_cast<bf16x8*>(zt) = vt[i][0];
    *reinterpret_cast<bf16x8*>(zt + 8) = vt[i][1];
  }
}

// ---------------- kernel 5: bf16 MFMA GEMM  Osr[z,b,h,c] = sum_{l in slice} Wt[p,h,l]*Zt[p,b,c,l] ----
// 128x128 tile, 256 thr / 4 waves (2x2, per-wave 64x64); BK=32; FOUR LDS buffers (64KB, 2 blocks/CU);
// depth-3 prefetch with counted vmcnt(8) (vmcnt retires in issue order -> exact tail counts);
// conflict-free XOR swizzle (0 conflicts measured): row m slot u holds chunk u ^ ((m>>1)&3).
__device__ __forceinline__ void gload16(const bf16_t* g, bf16_t* l) {
  __builtin_amdgcn_global_load_lds((const AS_GLOBAL uint32_t*)g, (AS_LDS uint32_t*)l, 16, 0, 0);
}

template <int KS>
__global__ void __launch_bounds__(256, 2) k_gemm(const bf16_t* __restrict__ Wt, const bf16_t* __restrict__ Zt,
                                                 float* __restrict__ Osr) {
  int z = blockIdx.z;
  int p = z / KS, kq = z % KS;
  const bf16_t* A  = Wt + (size_t)p * HPn * Ln;       // [768][4096]
  const bf16_t* Bz = Zt + (size_t)p * (Bn * Cn) * Ln; // [2048][4096]
  int h0 = blockIdx.y * 128, n0 = blockIdx.x * 128;
  int kbase = kq * (Ln / KS);
  const int NT = (Ln / KS) / 32;                      // K-steps of 32
  __shared__ __align__(16) bf16_t Al[4][128 * 32];
  __shared__ __align__(16) bf16_t Bl[4][128 * 32];
  int tid = threadIdx.x, wid = tid >> 6, lane = tid & 63;
  int wr = wid >> 1, wc = wid & 1;
  int fr = lane & 15, hi = lane >> 4;
  int kc = (tid & 3) ^ ((tid >> 3) & 3);              // source k-chunk (inverse swizzle)
  const bf16_t* abase = A + (size_t)(h0 + (tid >> 2)) * Ln + kbase + kc * 8;
  const bf16_t* bbase = Bz + (size_t)(n0 + (tid >> 2)) * Ln + kbase + kc * 8;

  f32x4 acc[4][4];
#pragma unroll
  for (int i = 0; i < 4; ++i)
#pragma unroll
    for (int j = 0; j < 4; ++j) acc[i][j] = (f32x4){0.f, 0.f, 0.f, 0.f};

  auto STAGE = [&](int bufi, int kt) {
    gload16(abase + (size_t)kt * 32, &Al[bufi][tid * 8]);
    gload16(abase + (size_t)64 * Ln + kt * 32, &Al[bufi][2048 + tid * 8]);
    gload16(bbase + (size_t)kt * 32, &Bl[bufi][tid * 8]);
    gload16(bbase + (size_t)64 * Ln + kt * 32, &Bl[bufi][2048 + tid * 8]);
  };

  int sw8 = (hi ^ ((fr >> 1) & 3)) * 8;               // swizzled chunk position (elements)
  auto COMPUTE = [&](int bufi) {
    bf16x8 afr[4], bfr[4];
#pragma unroll
    for (int i = 0; i < 4; ++i)
      afr[i] = *reinterpret_cast<const bf16x8*>(&Al[bufi][(wr * 64 + i * 16 + fr) * 32 + sw8]);
#pragma unroll
    for (int j = 0; j < 4; ++j)
      bfr[j] = *reinterpret_cast<const bf16x8*>(&Bl[bufi][(wc * 64 + j * 16 + fr) * 32 + sw8]);
    __builtin_amdgcn_s_setprio(1);
#pragma unroll
    for (int i = 0; i < 4; ++i)
#pragma unroll
      for (int j = 0; j < 4; ++j)
        acc[i][j] = __builtin_amdgcn_mfma_f32_16x16x32_bf16(afr[i], bfr[j], acc[i][j], 0, 0, 0);
    __builtin_amdgcn_s_setprio(0);
  };

  STAGE(0, 0);
  STAGE(1, 1);
  STAGE(2, 2);
  for (int t = 0; t < NT; ++t) {
    __builtin_amdgcn_sched_barrier(0);
    // wait for tile t: outstanding after-t stages = {t+1,t+2} (8 loads) steady-state
    if (t + 2 < NT)      { asm volatile("s_waitcnt vmcnt(8)" ::: "memory"); }
    else if (t + 1 < NT) { asm volatile("s_waitcnt vmcnt(4)" ::: "memory"); }
    else                 { asm volatile("s_waitcnt vmcnt(0)" ::: "memory"); }
    __builtin_amdgcn_s_barrier();
    __builtin_amdgcn_sched_barrier(0);
    if (t + 3 < NT) STAGE((t + 3) & 3, t + 3);
    COMPUTE(t & 3);
  }

#pragma unroll
  for (int i = 0; i < 4; ++i) {
#pragma unroll
    for (int j = 0; j < 4; ++j) {
#pragma unroll
      for (int r = 0; r < 4; ++r) {
        int m = wr * 64 + i * 16 + hi * 4 + r;
        int h = h0 + m;
        if (h < Hn) {
          int n = n0 + wc * 64 + j * 16 + fr;
          int bidx = n >> 6, c = n & 63;
          Osr[(((size_t)z * Bn + bidx) * Hn + h) * Cn + c] = acc[i][j][r];
        }
      }
    }
  }
}

// ---------------- kernel 6: epilogue — sum K-slices, apply M, biases, inverse RevIN ----------------
template <int KS>
__global__ void __launch_bounds__(256) k_epi(const float* __restrict__ Osr, const float* __restrict__ M,
                                             const float* __restrict__ cvec, const float* __restrict__ S,
                                             const float* __restrict__ st_b, const float* __restrict__ tt_b,
                                             const float* __restrict__ rev_w, const float* __restrict__ rev_b,
                                             const float* __restrict__ mean, const float* __restrict__ stdv,
                                             float* __restrict__ out) {
  __shared__ float Msh[2][64][64];    // 32 KB
  __shared__ float rowS[4][64];
  __shared__ float rowT[4][64];
  int t = threadIdx.x;
  for (int i = t; i < 8192; i += 256) ((float*)Msh)[i] = M[i];
  int g = t >> 6, c = t & 63;
  float w = rev_w[c], rb = rev_b[c];
  float cs = cvec[c], ct = cvec[64 + c];
  int base = blockIdx.x * 16;
  for (int it = 0; it < 4; ++it) {
    int r = base + it * 4 + g;        // r = b*720 + h
    int b = r / 720, h = r % 720;
    __syncthreads();                  // also covers Msh load at it=0
    float vs = 0.f, vt = 0.f;
#pragma unroll
    for (int kq = 0; kq < KS; ++kq) {
      vs += Osr[(((size_t)kq * Bn + b) * Hn + h) * Cn + c];
      vt += Osr[(((size_t)(KS + kq) * Bn + b) * Hn + h) * Cn + c];
    }
    rowS[g][c] = vs;
    rowT[g][c] = vt;
    __syncthreads();
    float acc = cs * S[h] + ct * S[768 + h] + st_b[h] + tt_b[h];
    for (int cp = 0; cp < 64; ++cp)
      acc = fmaf(rowS[g][cp], Msh[0][cp][c], fmaf(rowT[g][cp], Msh[1][cp][c], acc));
    float o = (acc - rb) / (w + EPSf) * stdv[b * Cn + c] + mean[b * Cn + c];
    out[(size_t)r * 64 + c] = o;
  }
}

// ---------------- launch ----------------
extern "C" void kernel_launch(void* const* d_in, const int* in_sizes, int n_in,
                              void* d_out, int out_size, void* d_ws, size_t ws_size,
                              hipStream_t stream) {
  const float* x     = (const float*)d_in[0];
  const float* alpha = (const float*)d_in[1];
  const float* rev_w = (const float*)d_in[2];
  const float* rev_b = (const float*)d_in[3];
  const float* se_w  = (const float*)d_in[4];
  const float* se_b  = (const float*)d_in[5];
  const float* sp_w  = (const float*)d_in[6];
  const float* sp_b  = (const float*)d_in[7];
  const float* st_w  = (const float*)d_in[8];
  const float* st_b  = (const float*)d_in[9];
  const float* te_w  = (const float*)d_in[10];
  const float* te_b  = (const float*)d_in[11];
  const float* tp_w  = (const float*)d_in[12];
  const float* tp_b  = (const float*)d_in[13];
  const float* tt_w  = (const float*)d_in[14];
  const float* tt_b  = (const float*)d_in[15];
  float* out = (float*)d_out;

  const size_t SZ_WT  = (size_t)2 * HPn * Ln * 2;          // 12.58 MB
  const size_t SZ_ZT  = (size_t)2 * Bn * Cn * Ln * 2;      // 33.55 MB
  const size_t SZ_SEG = (size_t)Bn * 64 * 64 * 4;          // 0.5 MB seg-level scratch
  const size_t SZ_M   = 2 * 64 * 64 * 4;                   // 32 KB
  const size_t SZ_CV  = 2 * 64 * 4;
  const size_t SZ_S   = 2 * 768 * 4;
  const size_t TAIL   = SZ_M + SZ_CV + SZ_S + 3 * (size_t)Bn * Cn * 4;

  // KS=4 needs 8 Osr slices; KS=1 needs 2 (scan scratch: 2MB Psub + 4x0.5MB fits either way).
  const size_t NEED4 = SZ_WT + SZ_ZT + 8 * OSR_SLICE * 4 + TAIL;
  const int KS = (ws_size >= NEED4) ? 4 : 1;
  const size_t SZ_OSR = (size_t)(2 * KS) * OSR_SLICE * 4;

  char* ws = (char*)d_ws;
  bf16_t* Wt   = (bf16_t*)(ws);
  bf16_t* Zt   = (bf16_t*)(ws + SZ_WT);
  float*  Osr  = (float*)(ws + SZ_WT + SZ_ZT);
  // scan scratch aliases Osr (dead before k_gemm writes Osr)
  float*  Psub  = Osr;                                     // 2 MB
  float*  Pseg  = (float*)((char*)Psub + 4 * SZ_SEG);
  float*  Ssum  = (float*)((char*)Pseg + SZ_SEG);
  float*  Ssq   = (float*)((char*)Ssum + SZ_SEG);
  float*  Carry = (float*)((char*)Ssq + SZ_SEG);
  char* tail = ws + SZ_WT + SZ_ZT + SZ_OSR;
  float* Mbuf = (float*)tail;                 tail += SZ_M;
  float* cvec = (float*)tail;                 tail += SZ_CV;
  float* S    = (float*)tail;                 tail += SZ_S;
  float* mean = (float*)tail;                 tail += (size_t)Bn * Cn * 4;
  float* rstd = (float*)tail;                 tail += (size_t)Bn * Cn * 4;
  float* stdv = (float*)tail;

  // zero M | cvec | S (contiguous) for the atomicAdd accumulations
  hipMemsetAsync(Mbuf, 0, SZ_M + SZ_CV + SZ_S, stream);

  k_prep<<<dim3(8, 2), 256, 0, stream>>>(se_w, sp_w, se_b, sp_b, te_w, tp_w, te_b, tp_b, Mbuf, cvec);
  k_wprep<<<dim3(64, 12, 2), 256, 0, stream>>>(st_w, tt_w, Wt, S);
  k_scanA<<<dim3(32, 64), 64, 0, stream>>>(x, alpha, Psub, Pseg, Ssum, Ssq);
  k_scanB<<<32, 64, 0, stream>>>(x, alpha, rev_w, rev_b, Pseg, Ssum, Ssq, mean, rstd, stdv, Carry);
  k_scanC<<<dim3(32, 64), 64, 0, stream>>>(x, alpha, rev_w, rev_b, mean, rstd, Carry, Psub, Zt);
  if (KS == 4) {
    k_gemm<4><<<dim3(16, 6, 8), 256, 0, stream>>>(Wt, Zt, Osr);
    k_epi<4><<<1440, 256, 0, stream>>>(Osr, Mbuf, cvec, S, st_b, tt_b, rev_w, rev_b, mean, stdv, out);
  } else {
    k_gemm<1><<<dim3(16, 6, 2), 256, 0, stream>>>(Wt, Zt, Osr);
    k_epi<1><<<1440, 256, 0, stream>>>(Osr, Mbuf, cvec, S, st_b, tt_b, rev_w, rev_b, mean, stdv, out);
  }
}

// Round 7
// 117.852 us; speedup vs baseline: 6.5712x; 1.1145x over previous
//
#include <hip/hip_runtime.h>
#include <hip/hip_bf16.h>
#include <string.h>
#include <stdint.h>

typedef __hip_bfloat16 bf16_t;
typedef float f32x4 __attribute__((ext_vector_type(4)));
typedef short bf16x8 __attribute__((ext_vector_type(8)));

#define AS_GLOBAL __attribute__((address_space(1)))
#define AS_LDS    __attribute__((address_space(3)))

static constexpr int Bn = 32, Ln = 4096, Cn = 64, Hn = 720, HPn = 768;
static constexpr float EPSf = 1e-5f;

static constexpr size_t OSR_SLICE = (size_t)Bn * Hn * Cn;   // f32 elements per K-slice per path

__device__ __forceinline__ short f2bf(float f) {
  bf16_t h = __float2bfloat16(f);
  unsigned short u; memcpy(&u, &h, 2);
  return (short)u;
}

__device__ __forceinline__ float sigm(float v) { return 1.f / (1.f + expf(-v)); }

// ---------------- kernel 1: fold the two 64->512->64 MLPs (d-chunked, LDS-tiled) ----------------
__global__ void __launch_bounds__(256) k_prep(const float* __restrict__ se_w, const float* __restrict__ sp_w,
                                              const float* __restrict__ se_b, const float* __restrict__ sp_b,
                                              const float* __restrict__ te_w, const float* __restrict__ tp_w,
                                              const float* __restrict__ te_b, const float* __restrict__ tp_b,
                                              float* __restrict__ M, float* __restrict__ cvec) {
  int p = blockIdx.y, dc = blockIdx.x, t = threadIdx.x;
  const float* ew = p ? te_w : se_w;   // (64,512)
  const float* pw = p ? tp_w : sp_w;   // (512,64)
  const float* eb = p ? te_b : se_b;   // (512,)
  const float* pb = p ? tp_b : sp_b;   // (64,)
  int d0 = dc * 64;
  __shared__ float ews[64][68];        // [row r][dd]
  __shared__ float pws[64][68];        // [dd][c]
  __shared__ float ebs[64];
#pragma unroll
  for (int q = 0; q < 4; ++q) {        // stage: 4 float4 per thread per array (coalesced)
    int fi = t * 4 + q;
    int r = fi >> 4, dd = (fi * 4) & 63;
    *reinterpret_cast<f32x4*>(&ews[r][dd]) = *reinterpret_cast<const f32x4*>(&ew[r * 512 + d0 + dd]);
    int pdd = fi >> 4, c = (fi * 4) & 63;
    *reinterpret_cast<f32x4*>(&pws[pdd][c]) = *reinterpret_cast<const f32x4*>(&pw[(d0 + pdd) * 64 + c]);
  }
  if (t < 64) ebs[t] = eb[d0 + t];
  __syncthreads();
  int r0 = (t >> 4) * 4, c0 = (t & 15) * 4;
  float acc[4][4];
#pragma unroll
  for (int i = 0; i < 4; ++i)
#pragma unroll
    for (int j = 0; j < 4; ++j) acc[i][j] = 0.f;
#pragma unroll 4
  for (int g = 0; g < 16; ++g) {
    int dd = g * 4;
    f32x4 av[4], bv[4];
#pragma unroll
    for (int i = 0; i < 4; ++i) av[i] = *reinterpret_cast<const f32x4*>(&ews[r0 + i][dd]);
#pragma unroll
    for (int d = 0; d < 4; ++d) bv[d] = *reinterpret_cast<const f32x4*>(&pws[dd + d][c0]);
#pragma unroll
    for (int d = 0; d < 4; ++d)
#pragma unroll
      for (int i = 0; i < 4; ++i)
#pragma unroll
        for (int j = 0; j < 4; ++j) acc[i][j] = fmaf(av[i][d], bv[d][j], acc[i][j]);
  }
#pragma unroll
  for (int i = 0; i < 4; ++i)
#pragma unroll
    for (int j = 0; j < 4; ++j)
      atomicAdd(&M[p * 4096 + (r0 + i) * 64 + c0 + j], acc[i][j]);
  if (t < 64) {
    float s = (dc == 0) ? pb[t] : 0.f;
#pragma unroll 8
    for (int dd = 0; dd < 64; ++dd) s = fmaf(ebs[dd], pws[dd][t], s);
    atomicAdd(&cvec[p * 64 + t], s);
  }
}

// ---------------- kernel 2: transpose tw -> Wt[h][l] bf16 (+colsum) ----------------
__global__ void k_wprep(const float* __restrict__ st_w, const float* __restrict__ tt_w,
                        bf16_t* __restrict__ Wt, float* __restrict__ S) {
  int p = blockIdx.z;
  const float* W = p ? tt_w : st_w;          // (4096, 720)
  int l0 = blockIdx.x * 64, h0 = blockIdx.y * 64;
  __shared__ float tile[64][65];
  int row = threadIdx.x >> 6, col = threadIdx.x & 63;
  int h = h0 + col;
  float partial = 0.f;
  for (int r = row; r < 64; r += 4) {
    float v = (h < Hn) ? W[(size_t)(l0 + r) * Hn + h] : 0.f;
    tile[r][col] = v;
    partial += v;
  }
  if (h < Hn) atomicAdd(&S[p * 768 + h], partial);
  __syncthreads();
  for (int a = row; a < 64; a += 4) {
    float v = tile[col][a];                  // transposed read (pad 65 -> no conflict)
    Wt[(size_t)(p * HPn + h0 + a) * Ln + l0 + col] = __float2bfloat16(v);
  }
}

// ---------------- kernel 3a: 4-wave blocks, (c-quad x l-sub16) raw-x partials + seg reduce ------
__global__ void __launch_bounds__(256) k_scanA(const float* __restrict__ x, const float* __restrict__ alpha,
                                               float* __restrict__ Psub, float* __restrict__ Pseg,
                                               float* __restrict__ Ssum, float* __restrict__ Ssq) {
  int b = blockIdx.x, q = threadIdx.y, s = blockIdx.y * 4 + q, t = threadIdx.x;
  int c4 = (t & 15) * 4, sub = t >> 4;
  float a[4], k1[4];
#pragma unroll
  for (int i = 0; i < 4; ++i) { a[i] = sigm(alpha[c4 + i]); k1[i] = 1.f - a[i]; }
  const float* xb = x + ((size_t)b * Ln + s * 64 + sub * 16) * Cn + c4;
  float pr[4] = {0.f, 0.f, 0.f, 0.f}, sm[4] = {0.f, 0.f, 0.f, 0.f}, sq[4] = {0.f, 0.f, 0.f, 0.f};
#pragma unroll
  for (int j = 0; j < 16; ++j) {
    f32x4 v = *reinterpret_cast<const f32x4*>(xb + (size_t)j * Cn);
#pragma unroll
    for (int i = 0; i < 4; ++i) {
      sm[i] += v[i];
      sq[i] = fmaf(v[i], v[i], sq[i]);
      pr[i] = fmaf(a[i], pr[i], k1[i] * v[i]);
    }
  }
  *reinterpret_cast<f32x4*>(&Psub[(((size_t)b * 64 + s) * 4 + sub) * 64 + c4]) =
      (f32x4){pr[0], pr[1], pr[2], pr[3]};
  __shared__ float lp[4][4][64], ls[4][4][64], lq[4][4][64];   // [wave q][sub][c]
#pragma unroll
  for (int i = 0; i < 4; ++i) { lp[q][sub][c4 + i] = pr[i]; ls[q][sub][c4 + i] = sm[i]; lq[q][sub][c4 + i] = sq[i]; }
  __syncthreads();
  int c = t;
  float av = sigm(alpha[c]);
  float a16 = av * av; a16 *= a16; a16 *= a16; a16 *= a16;   // a^16
  float P = ((lp[q][0][c] * a16 + lp[q][1][c]) * a16 + lp[q][2][c]) * a16 + lp[q][3][c];
  int idx = (b * 64 + s) * 64 + c;
  Pseg[idx] = P;
  Ssum[idx] = ls[q][0][c] + ls[q][1][c] + ls[q][2][c] + ls[q][3][c];
  Ssq[idx]  = lq[q][0][c] + lq[q][1][c] + lq[q][2][c] + lq[q][3][c];
}

// ---------------- kernel 3b: stats finalize + 64-step carry scan ----------------
__global__ void __launch_bounds__(64) k_scanB(const float* __restrict__ x, const float* __restrict__ alpha,
                                              const float* __restrict__ rev_w, const float* __restrict__ rev_b,
                                              const float* __restrict__ Pseg, const float* __restrict__ Ssum,
                                              const float* __restrict__ Ssq,
                                              float* __restrict__ mean, float* __restrict__ rstd,
                                              float* __restrict__ stdv, float* __restrict__ CarryIn) {
  int b = blockIdx.x, c = threadIdx.x;
  float sm = 0.f, sq = 0.f;
#pragma unroll 8
  for (int s = 0; s < 64; ++s) {
    int idx = (b * 64 + s) * 64 + c;
    sm += Ssum[idx]; sq += Ssq[idx];
  }
  float mn = sm * (1.f / 4096.f);
  float var = sq * (1.f / 4096.f) - mn * mn;
  float sd = sqrtf(var + EPSf);
  float rs = 1.f / sd;
  mean[b * 64 + c] = mn; stdv[b * 64 + c] = sd; rstd[b * 64 + c] = rs;

  float w = rev_w[c], rb = rev_b[c];
  float g = rs * w, d = rb - mn * g;         // xn = g*x + d
  float a = sigm(alpha[c]);
  float a2 = a * a, a4 = a2 * a2, a8 = a4 * a4, a16 = a8 * a8, a32 = a16 * a16;
  float a64 = a32 * a32;
  float dk1s = d * (1.f - a64);               // d * sum of (1-a)*a^k
  float carry = fmaf(g, x[((size_t)b * Ln) * Cn + c], d);   // xn[0]
  for (int so = 0; so < 8; ++so) {
    float pv[8];
#pragma unroll
    for (int i = 0; i < 8; ++i)
      pv[i] = Pseg[((size_t)(b * 64 + so * 8 + i)) * 64 + c];   // batched, independent loads
#pragma unroll
    for (int i = 0; i < 8; ++i) {
      CarryIn[((size_t)(b * 64 + so * 8 + i)) * 64 + c] = carry;
      carry = fmaf(a64, carry, fmaf(g, pv[i], dk1s));
    }
  }
}

// ---------------- kernel 3c: 4-wave blocks, apply scan, write transposed bf16 ----------------
__global__ void __launch_bounds__(256) k_scanC(const float* __restrict__ x, const float* __restrict__ alpha,
                                               const float* __restrict__ rev_w, const float* __restrict__ rev_b,
                                               const float* __restrict__ mean, const float* __restrict__ rstd,
                                               const float* __restrict__ CarryIn, const float* __restrict__ Psub,
                                               bf16_t* __restrict__ Zt) {
  int b = blockIdx.x, s = blockIdx.y * 4 + threadIdx.y, t = threadIdx.x;
  int c4 = (t & 15) * 4, sub = t >> 4;
  float g[4], d[4], a[4], k1[4], a16[4], dk[4], tr[4];
#pragma unroll
  for (int i = 0; i < 4; ++i) {
    int c = c4 + i;
    float rs = rstd[b * 64 + c];
    g[i] = rs * rev_w[c]; d[i] = rev_b[c] - mean[b * 64 + c] * g[i];
    a[i] = sigm(alpha[c]); k1[i] = 1.f - a[i];
    float v = a[i] * a[i]; v *= v; v *= v; v *= v;
    a16[i] = v;
    dk[i] = d[i] * (1.f - v);
  }
  f32x4 cs = *reinterpret_cast<const f32x4*>(&CarryIn[((size_t)b * 64 + s) * 64 + c4]);
#pragma unroll
  for (int i = 0; i < 4; ++i) tr[i] = cs[i];
  for (int k = 0; k < sub; ++k) {            // compose prior subs (<=3 iters, masked)
    f32x4 p = *reinterpret_cast<const f32x4*>(&Psub[(((size_t)b * 64 + s) * 4 + k) * 64 + c4]);
#pragma unroll
    for (int i = 0; i < 4; ++i) tr[i] = fmaf(a16[i], tr[i], fmaf(g[i], p[i], dk[i]));
  }
  const float* xb = x + ((size_t)b * Ln + s * 64 + sub * 16) * Cn + c4;
  bf16x8 vs[4][2], vt[4][2];
#pragma unroll
  for (int j = 0; j < 16; ++j) {
    f32x4 v = *reinterpret_cast<const f32x4*>(xb + (size_t)j * Cn);
#pragma unroll
    for (int i = 0; i < 4; ++i) {
      float xn = fmaf(g[i], v[i], d[i]);
      tr[i] = fmaf(a[i], tr[i], k1[i] * xn);
      vs[i][j >> 3][j & 7] = f2bf(xn - tr[i]);
      vt[i][j >> 3][j & 7] = f2bf(tr[i]);
    }
  }
#pragma unroll
  for (int i = 0; i < 4; ++i) {
    int c = c4 + i;
    bf16_t* zs = Zt + ((size_t)b * 64 + c) * Ln + s * 64 + sub * 16;
    bf16_t* zt = zs + (size_t)Bn * Cn * Ln;
    *reinterpret_cast<bf16x8*>(zs) = vs[i][0];
    *reinterpret_cast<bf16x8*>(zs + 8) = vs[i][1];
    *reinterpret_cast<bf16x8*>(zt) = vt[i][0];
    *reinterpret_cast<bf16x8*>(zt + 8) = vt[i][1];
  }
}

// ---------------- kernel 5: bf16 MFMA GEMM (round-5 proven config: 46 µs) ----------------
// 128x128 tile, 256 thr / 4 waves (2x2, per-wave 64x64); BK=32; triple-buffered LDS (48KB,
// 3 blocks/CU); single barrier + counted vmcnt(4) per K-step; conflict-free XOR swizzle.
__device__ __forceinline__ void gload16(const bf16_t* g, bf16_t* l) {
  __builtin_amdgcn_global_load_lds((const AS_GLOBAL uint32_t*)g, (AS_LDS uint32_t*)l, 16, 0, 0);
}

template <int KS>
__global__ void __launch_bounds__(256, 3) k_gemm(const bf16_t* __restrict__ Wt, const bf16_t* __restrict__ Zt,
                                                 float* __restrict__ Osr) {
  int z = blockIdx.z;
  int p = z / KS, kq = z % KS;
  const bf16_t* A  = Wt + (size_t)p * HPn * Ln;       // [768][4096]
  const bf16_t* Bz = Zt + (size_t)p * (Bn * Cn) * Ln; // [2048][4096]
  int h0 = blockIdx.y * 128, n0 = blockIdx.x * 128;
  int kbase = kq * (Ln / KS);
  const int NT = (Ln / KS) / 32;                      // K-steps of 32
  __shared__ __align__(16) bf16_t Al[3][128 * 32];
  __shared__ __align__(16) bf16_t Bl[3][128 * 32];
  int tid = threadIdx.x, wid = tid >> 6, lane = tid & 63;
  int wr = wid >> 1, wc = wid & 1;
  int fr = lane & 15, hi = lane >> 4;
  int kc = (tid & 3) ^ ((tid >> 3) & 3);              // source k-chunk (inverse swizzle)
  const bf16_t* abase = A + (size_t)(h0 + (tid >> 2)) * Ln + kbase + kc * 8;
  const bf16_t* bbase = Bz + (size_t)(n0 + (tid >> 2)) * Ln + kbase + kc * 8;

  f32x4 acc[4][4];
#pragma unroll
  for (int i = 0; i < 4; ++i)
#pragma unroll
    for (int j = 0; j < 4; ++j) acc[i][j] = (f32x4){0.f, 0.f, 0.f, 0.f};

  auto STAGE = [&](int bufi, int kt) {
    gload16(abase + (size_t)kt * 32, &Al[bufi][tid * 8]);
    gload16(abase + (size_t)64 * Ln + kt * 32, &Al[bufi][2048 + tid * 8]);
    gload16(bbase + (size_t)kt * 32, &Bl[bufi][tid * 8]);
    gload16(bbase + (size_t)64 * Ln + kt * 32, &Bl[bufi][2048 + tid * 8]);
  };

  int sw8 = (hi ^ ((fr >> 1) & 3)) * 8;               // swizzled chunk position (elements)
  auto COMPUTE = [&](int bufi) {
    bf16x8 afr[4], bfr[4];
#pragma unroll
    for (int i = 0; i < 4; ++i)
      afr[i] = *reinterpret_cast<const bf16x8*>(&Al[bufi][(wr * 64 + i * 16 + fr) * 32 + sw8]);
#pragma unroll
    for (int j = 0; j < 4; ++j)
      bfr[j] = *reinterpret_cast<const bf16x8*>(&Bl[bufi][(wc * 64 + j * 16 + fr) * 32 + sw8]);
    __builtin_amdgcn_s_setprio(1);
#pragma unroll
    for (int i = 0; i < 4; ++i)
#pragma unroll
      for (int j = 0; j < 4; ++j)
        acc[i][j] = __builtin_amdgcn_mfma_f32_16x16x32_bf16(afr[i], bfr[j], acc[i][j], 0, 0, 0);
    __builtin_amdgcn_s_setprio(0);
  };

  STAGE(0, 0);
  STAGE(1, 1);
  int cur = 0, nx = 2;
  for (int t = 0; t < NT; ++t) {
    __builtin_amdgcn_sched_barrier(0);
    if (t + 1 < NT) { asm volatile("s_waitcnt vmcnt(4)" ::: "memory"); }   // tile t landed; t+1 in flight
    else            { asm volatile("s_waitcnt vmcnt(0)" ::: "memory"); }
    __builtin_amdgcn_s_barrier();
    __builtin_amdgcn_sched_barrier(0);
    if (t + 2 < NT) STAGE(nx, t + 2);
    COMPUTE(cur);
    cur = (cur == 2) ? 0 : cur + 1;
    nx  = (nx == 2) ? 0 : nx + 1;
  }

#pragma unroll
  for (int i = 0; i < 4; ++i) {
#pragma unroll
    for (int j = 0; j < 4; ++j) {
#pragma unroll
      for (int r = 0; r < 4; ++r) {
        int m = wr * 64 + i * 16 + hi * 4 + r;
        int h = h0 + m;
        if (h < Hn) {
          int n = n0 + wc * 64 + j * 16 + fr;
          int bidx = n >> 6, c = n & 63;
          Osr[(((size_t)z * Bn + bidx) * Hn + h) * Cn + c] = acc[i][j][r];
        }
      }
    }
  }
}

// ---------------- kernel 6: epilogue — sum K-slices, apply M, biases, inverse RevIN ----------------
template <int KS>
__global__ void __launch_bounds__(256) k_epi(const float* __restrict__ Osr, const float* __restrict__ M,
                                             const float* __restrict__ cvec, const float* __restrict__ S,
                                             const float* __restrict__ st_b, const float* __restrict__ tt_b,
                                             const float* __restrict__ rev_w, const float* __restrict__ rev_b,
                                             const float* __restrict__ mean, const float* __restrict__ stdv,
                                             float* __restrict__ out) {
  __shared__ float Msh[2][64][64];    // 32 KB
  __shared__ float rowS[4][64];
  __shared__ float rowT[4][64];
  int t = threadIdx.x;
  for (int i = t; i < 8192; i += 256) ((float*)Msh)[i] = M[i];
  int g = t >> 6, c = t & 63;
  float w = rev_w[c], rb = rev_b[c];
  float cs = cvec[c], ct = cvec[64 + c];
  int base = blockIdx.x * 16;
  for (int it = 0; it < 4; ++it) {
    int r = base + it * 4 + g;        // r = b*720 + h
    int b = r / 720, h = r % 720;
    __syncthreads();                  // also covers Msh load at it=0
    float vs = 0.f, vt = 0.f;
#pragma unroll
    for (int kq = 0; kq < KS; ++kq) {
      vs += Osr[(((size_t)kq * Bn + b) * Hn + h) * Cn + c];
      vt += Osr[(((size_t)(KS + kq) * Bn + b) * Hn + h) * Cn + c];
    }
    rowS[g][c] = vs;
    rowT[g][c] = vt;
    __syncthreads();
    float acc = cs * S[h] + ct * S[768 + h] + st_b[h] + tt_b[h];
    for (int cp = 0; cp < 64; ++cp)
      acc = fmaf(rowS[g][cp], Msh[0][cp][c], fmaf(rowT[g][cp], Msh[1][cp][c], acc));
    float o = (acc - rb) / (w + EPSf) * stdv[b * Cn + c] + mean[b * Cn + c];
    out[(size_t)r * 64 + c] = o;
  }
}

// ---------------- launch ----------------
extern "C" void kernel_launch(void* const* d_in, const int* in_sizes, int n_in,
                              void* d_out, int out_size, void* d_ws, size_t ws_size,
                              hipStream_t stream) {
  const float* x     = (const float*)d_in[0];
  const float* alpha = (const float*)d_in[1];
  const float* rev_w = (const float*)d_in[2];
  const float* rev_b = (const float*)d_in[3];
  const float* se_w  = (const float*)d_in[4];
  const float* se_b  = (const float*)d_in[5];
  const float* sp_w  = (const float*)d_in[6];
  const float* sp_b  = (const float*)d_in[7];
  const float* st_w  = (const float*)d_in[8];
  const float* st_b  = (const float*)d_in[9];
  const float* te_w  = (const float*)d_in[10];
  const float* te_b  = (const float*)d_in[11];
  const float* tp_w  = (const float*)d_in[12];
  const float* tp_b  = (const float*)d_in[13];
  const float* tt_w  = (const float*)d_in[14];
  const float* tt_b  = (const float*)d_in[15];
  float* out = (float*)d_out;

  const size_t SZ_WT  = (size_t)2 * HPn * Ln * 2;          // 12.58 MB
  const size_t SZ_ZT  = (size_t)2 * Bn * Cn * Ln * 2;      // 33.55 MB
  const size_t SZ_SEG = (size_t)Bn * 64 * 64 * 4;          // 0.5 MB seg-level scratch
  const size_t SZ_M   = 2 * 64 * 64 * 4;                   // 32 KB
  const size_t SZ_CV  = 2 * 64 * 4;
  const size_t SZ_S   = 2 * 768 * 4;
  const size_t TAIL   = SZ_M + SZ_CV + SZ_S + 3 * (size_t)Bn * Cn * 4;

  // KS=4 needs 8 Osr slices; KS=1 needs 2 (scan scratch: 2MB Psub + 4x0.5MB fits either way).
  const size_t NEED4 = SZ_WT + SZ_ZT + 8 * OSR_SLICE * 4 + TAIL;
  const int KS = (ws_size >= NEED4) ? 4 : 1;
  const size_t SZ_OSR = (size_t)(2 * KS) * OSR_SLICE * 4;

  char* ws = (char*)d_ws;
  bf16_t* Wt   = (bf16_t*)(ws);
  bf16_t* Zt   = (bf16_t*)(ws + SZ_WT);
  float*  Osr  = (float*)(ws + SZ_WT + SZ_ZT);
  // scan scratch aliases Osr (dead before k_gemm writes Osr)
  float*  Psub  = Osr;                                     // 2 MB
  float*  Pseg  = (float*)((char*)Psub + 4 * SZ_SEG);
  float*  Ssum  = (float*)((char*)Pseg + SZ_SEG);
  float*  Ssq   = (float*)((char*)Ssum + SZ_SEG);
  float*  Carry = (float*)((char*)Ssq + SZ_SEG);
  char* tail = ws + SZ_WT + SZ_ZT + SZ_OSR;
  float* Mbuf = (float*)tail;                 tail += SZ_M;
  float* cvec = (float*)tail;                 tail += SZ_CV;
  float* S    = (float*)tail;                 tail += SZ_S;
  float* mean = (float*)tail;                 tail += (size_t)Bn * Cn * 4;
  float* rstd = (float*)tail;                 tail += (size_t)Bn * Cn * 4;
  float* stdv = (float*)tail;

  // zero M | cvec | S (contiguous) for the atomicAdd accumulations
  hipMemsetAsync(Mbuf, 0, SZ_M + SZ_CV + SZ_S, stream);

  k_prep<<<dim3(8, 2), 256, 0, stream>>>(se_w, sp_w, se_b, sp_b, te_w, tp_w, te_b, tp_b, Mbuf, cvec);
  k_wprep<<<dim3(64, 12, 2), 256, 0, stream>>>(st_w, tt_w, Wt, S);
  k_scanA<<<dim3(32, 16), dim3(64, 4), 0, stream>>>(x, alpha, Psub, Pseg, Ssum, Ssq);
  k_scanB<<<32, 64, 0, stream>>>(x, alpha, rev_w, rev_b, Pseg, Ssum, Ssq, mean, rstd, stdv, Carry);
  k_scanC<<<dim3(32, 16), dim3(64, 4), 0, stream>>>(x, alpha, rev_w, rev_b, mean, rstd, Carry, Psub, Zt);
  if (KS == 4) {
    k_gemm<4><<<dim3(16, 6, 8), 256, 0, stream>>>(Wt, Zt, Osr);
    k_epi<4><<<1440, 256, 0, stream>>>(Osr, Mbuf, cvec, S, st_b, tt_b, rev_w, rev_b, mean, stdv, out);
  } else {
    k_gemm<1><<<dim3(16, 6, 2), 256, 0, stream>>>(Wt, Zt, Osr);
    k_epi<1><<<1440, 256, 0, stream>>>(Osr, Mbuf, cvec, S, st_b, tt_b, rev_w, rev_b, mean, stdv, out);
  }
}

// Round 8
// 115.565 us; speedup vs baseline: 6.7012x; 1.0198x over previous
//
#include <hip/hip_runtime.h>
#include <hip/hip_bf16.h>
#include <string.h>
#include <stdint.h>

typedef __hip_bfloat16 bf16_t;
typedef float f32x4 __attribute__((ext_vector_type(4)));
typedef short bf16x8 __attribute__((ext_vector_type(8)));

#define AS_GLOBAL __attribute__((address_space(1)))
#define AS_LDS    __attribute__((address_space(3)))

static constexpr int Bn = 32, Ln = 4096, Cn = 64, Hn = 720, HPn = 768;
static constexpr float EPSf = 1e-5f;

static constexpr size_t OSR_SLICE = (size_t)Bn * Hn * Cn;   // f32 elements per K-slice per path

__device__ __forceinline__ short f2bf(float f) {
  bf16_t h = __float2bfloat16(f);
  unsigned short u; memcpy(&u, &h, 2);
  return (short)u;
}

__device__ __forceinline__ float sigm(float v) { return 1.f / (1.f + expf(-v)); }

// ---------------- kernel 1: fold the two 64->512->64 MLPs (d-chunked, LDS-tiled) ----------------
__global__ void __launch_bounds__(256) k_prep(const float* __restrict__ se_w, const float* __restrict__ sp_w,
                                              const float* __restrict__ se_b, const float* __restrict__ sp_b,
                                              const float* __restrict__ te_w, const float* __restrict__ tp_w,
                                              const float* __restrict__ te_b, const float* __restrict__ tp_b,
                                              float* __restrict__ M, float* __restrict__ cvec) {
  int p = blockIdx.y, dc = blockIdx.x, t = threadIdx.x;
  const float* ew = p ? te_w : se_w;   // (64,512)
  const float* pw = p ? tp_w : sp_w;   // (512,64)
  const float* eb = p ? te_b : se_b;   // (512,)
  const float* pb = p ? tp_b : sp_b;   // (64,)
  int d0 = dc * 64;
  __shared__ float ews[64][68];        // [row r][dd]
  __shared__ float pws[64][68];        // [dd][c]
  __shared__ float ebs[64];
#pragma unroll
  for (int q = 0; q < 4; ++q) {        // stage: 4 float4 per thread per array (coalesced)
    int fi = t * 4 + q;
    int r = fi >> 4, dd = (fi * 4) & 63;
    *reinterpret_cast<f32x4*>(&ews[r][dd]) = *reinterpret_cast<const f32x4*>(&ew[r * 512 + d0 + dd]);
    int pdd = fi >> 4, c = (fi * 4) & 63;
    *reinterpret_cast<f32x4*>(&pws[pdd][c]) = *reinterpret_cast<const f32x4*>(&pw[(d0 + pdd) * 64 + c]);
  }
  if (t < 64) ebs[t] = eb[d0 + t];
  __syncthreads();
  int r0 = (t >> 4) * 4, c0 = (t & 15) * 4;
  float acc[4][4];
#pragma unroll
  for (int i = 0; i < 4; ++i)
#pragma unroll
    for (int j = 0; j < 4; ++j) acc[i][j] = 0.f;
#pragma unroll 4
  for (int g = 0; g < 16; ++g) {
    int dd = g * 4;
    f32x4 av[4], bv[4];
#pragma unroll
    for (int i = 0; i < 4; ++i) av[i] = *reinterpret_cast<const f32x4*>(&ews[r0 + i][dd]);
#pragma unroll
    for (int d = 0; d < 4; ++d) bv[d] = *reinterpret_cast<const f32x4*>(&pws[dd + d][c0]);
#pragma unroll
    for (int d = 0; d < 4; ++d)
#pragma unroll
      for (int i = 0; i < 4; ++i)
#pragma unroll
        for (int j = 0; j < 4; ++j) acc[i][j] = fmaf(av[i][d], bv[d][j], acc[i][j]);
  }
#pragma unroll
  for (int i = 0; i < 4; ++i)
#pragma unroll
    for (int j = 0; j < 4; ++j)
      atomicAdd(&M[p * 4096 + (r0 + i) * 64 + c0 + j], acc[i][j]);
  if (t < 64) {
    float s = (dc == 0) ? pb[t] : 0.f;
#pragma unroll 8
    for (int dd = 0; dd < 64; ++dd) s = fmaf(ebs[dd], pws[dd][t], s);
    atomicAdd(&cvec[p * 64 + t], s);
  }
}

// ---------------- kernel 2: tw -> FRAGMENT-MAJOR AF[p][ht][kt][lane]x8 bf16 (+colsum) ----------
// AF unit (ht,kt,lane): elems A[ht*16 + (lane&15)][kt*32 + (lane>>4)*8 + e], A = tw^T (h,l).
// k_gemm reads one whole unit per lane: base + lane*16B -> perfectly coalesced, no LDS for A.
__global__ void k_wprep(const float* __restrict__ st_w, const float* __restrict__ tt_w,
                        bf16_t* __restrict__ Wt, float* __restrict__ S) {
  int p = blockIdx.z;
  const float* W = p ? tt_w : st_w;          // (4096, 720)
  int l0 = blockIdx.x * 64, h0 = blockIdx.y * 64;
  __shared__ float tile[64][65];             // [l-local][h-local]
  int row = threadIdx.x >> 6, col = threadIdx.x & 63;
  int h = h0 + col;
  float partial = 0.f;
  for (int r = row; r < 64; r += 4) {
    float v = (h < Hn) ? W[(size_t)(l0 + r) * Hn + h] : 0.f;
    tile[r][col] = v;
    partial += v;
  }
  if (h < Hn) atomicAdd(&S[p * 768 + h], partial);
  __syncthreads();
  short* AF = (short*)Wt + (size_t)p * HPn * Ln;   // 48*128*64*8 shorts per path
#pragma unroll
  for (int u = 0; u < 2; ++u) {
    int uid = u * 256 + threadIdx.x;         // 0..511
    int ln = uid & 63, ktl = (uid >> 6) & 1, htl = uid >> 7;
    int fr = ln & 15, hi = ln >> 4;
    int ll = ktl * 32 + hi * 8;              // l-local base
    int hh = htl * 16 + fr;                  // h-local
    bf16x8 v;
#pragma unroll
    for (int e = 0; e < 8; ++e) v[e] = f2bf(tile[ll + e][hh]);
    size_t ht = (size_t)(h0 >> 4) + htl, ktg = (size_t)(l0 >> 5) + ktl;
    *reinterpret_cast<bf16x8*>(&AF[((ht * 128 + ktg) << 9) + ((size_t)ln << 3)]) = v;
  }
}

// ---------------- kernel 3a: 4-wave blocks, (c-quad x l-sub16) raw-x partials + seg reduce ------
__global__ void __launch_bounds__(256) k_scanA(const float* __restrict__ x, const float* __restrict__ alpha,
                                               float* __restrict__ Psub, float* __restrict__ Pseg,
                                               float* __restrict__ Ssum, float* __restrict__ Ssq) {
  int b = blockIdx.x, q = threadIdx.y, s = blockIdx.y * 4 + q, t = threadIdx.x;
  int c4 = (t & 15) * 4, sub = t >> 4;
  float a[4], k1[4];
#pragma unroll
  for (int i = 0; i < 4; ++i) { a[i] = sigm(alpha[c4 + i]); k1[i] = 1.f - a[i]; }
  const float* xb = x + ((size_t)b * Ln + s * 64 + sub * 16) * Cn + c4;
  float pr[4] = {0.f, 0.f, 0.f, 0.f}, sm[4] = {0.f, 0.f, 0.f, 0.f}, sq[4] = {0.f, 0.f, 0.f, 0.f};
#pragma unroll
  for (int j = 0; j < 16; ++j) {
    f32x4 v = *reinterpret_cast<const f32x4*>(xb + (size_t)j * Cn);
#pragma unroll
    for (int i = 0; i < 4; ++i) {
      sm[i] += v[i];
      sq[i] = fmaf(v[i], v[i], sq[i]);
      pr[i] = fmaf(a[i], pr[i], k1[i] * v[i]);
    }
  }
  *reinterpret_cast<f32x4*>(&Psub[(((size_t)b * 64 + s) * 4 + sub) * 64 + c4]) =
      (f32x4){pr[0], pr[1], pr[2], pr[3]};
  __shared__ float lp[4][4][64], ls[4][4][64], lq[4][4][64];   // [wave q][sub][c]
#pragma unroll
  for (int i = 0; i < 4; ++i) { lp[q][sub][c4 + i] = pr[i]; ls[q][sub][c4 + i] = sm[i]; lq[q][sub][c4 + i] = sq[i]; }
  __syncthreads();
  int c = t;
  float av = sigm(alpha[c]);
  float a16 = av * av; a16 *= a16; a16 *= a16; a16 *= a16;   // a^16
  float P = ((lp[q][0][c] * a16 + lp[q][1][c]) * a16 + lp[q][2][c]) * a16 + lp[q][3][c];
  int idx = (b * 64 + s) * 64 + c;
  Pseg[idx] = P;
  Ssum[idx] = ls[q][0][c] + ls[q][1][c] + ls[q][2][c] + ls[q][3][c];
  Ssq[idx]  = lq[q][0][c] + lq[q][1][c] + lq[q][2][c] + lq[q][3][c];
}

// ---------------- kernel 3b: stats finalize + 64-step carry scan ----------------
__global__ void __launch_bounds__(64) k_scanB(const float* __restrict__ x, const float* __restrict__ alpha,
                                              const float* __restrict__ rev_w, const float* __restrict__ rev_b,
                                              const float* __restrict__ Pseg, const float* __restrict__ Ssum,
                                              const float* __restrict__ Ssq,
                                              float* __restrict__ mean, float* __restrict__ rstd,
                                              float* __restrict__ stdv, float* __restrict__ CarryIn) {
  int b = blockIdx.x, c = threadIdx.x;
  float sm = 0.f, sq = 0.f;
#pragma unroll 8
  for (int s = 0; s < 64; ++s) {
    int idx = (b * 64 + s) * 64 + c;
    sm += Ssum[idx]; sq += Ssq[idx];
  }
  float mn = sm * (1.f / 4096.f);
  float var = sq * (1.f / 4096.f) - mn * mn;
  float sd = sqrtf(var + EPSf);
  float rs = 1.f / sd;
  mean[b * 64 + c] = mn; stdv[b * 64 + c] = sd; rstd[b * 64 + c] = rs;

  float w = rev_w[c], rb = rev_b[c];
  float g = rs * w, d = rb - mn * g;         // xn = g*x + d
  float a = sigm(alpha[c]);
  float a2 = a * a, a4 = a2 * a2, a8 = a4 * a4, a16 = a8 * a8, a32 = a16 * a16;
  float a64 = a32 * a32;
  float dk1s = d * (1.f - a64);               // d * sum of (1-a)*a^k
  float carry = fmaf(g, x[((size_t)b * Ln) * Cn + c], d);   // xn[0]
  for (int so = 0; so < 8; ++so) {
    float pv[8];
#pragma unroll
    for (int i = 0; i < 8; ++i)
      pv[i] = Pseg[((size_t)(b * 64 + so * 8 + i)) * 64 + c];   // batched, independent loads
#pragma unroll
    for (int i = 0; i < 8; ++i) {
      CarryIn[((size_t)(b * 64 + so * 8 + i)) * 64 + c] = carry;
      carry = fmaf(a64, carry, fmaf(g, pv[i], dk1s));
    }
  }
}

// ---------------- kernel 3c: 4-wave blocks, apply scan, write transposed bf16 ----------------
__global__ void __launch_bounds__(256) k_scanC(const float* __restrict__ x, const float* __restrict__ alpha,
                                               const float* __restrict__ rev_w, const float* __restrict__ rev_b,
                                               const float* __restrict__ mean, const float* __restrict__ rstd,
                                               const float* __restrict__ CarryIn, const float* __restrict__ Psub,
                                               bf16_t* __restrict__ Zt) {
  int b = blockIdx.x, s = blockIdx.y * 4 + threadIdx.y, t = threadIdx.x;
  int c4 = (t & 15) * 4, sub = t >> 4;
  float g[4], d[4], a[4], k1[4], a16[4], dk[4], tr[4];
#pragma unroll
  for (int i = 0; i < 4; ++i) {
    int c = c4 + i;
    float rs = rstd[b * 64 + c];
    g[i] = rs * rev_w[c]; d[i] = rev_b[c] - mean[b * 64 + c] * g[i];
    a[i] = sigm(alpha[c]); k1[i] = 1.f - a[i];
    float v = a[i] * a[i]; v *= v; v *= v; v *= v;
    a16[i] = v;
    dk[i] = d[i] * (1.f - v);
  }
  f32x4 cs = *reinterpret_cast<const f32x4*>(&CarryIn[((size_t)b * 64 + s) * 64 + c4]);
#pragma unroll
  for (int i = 0; i < 4; ++i) tr[i] = cs[i];
  for (int k = 0; k < sub; ++k) {            // compose prior subs (<=3 iters, masked)
    f32x4 p = *reinterpret_cast<const f32x4*>(&Psub[(((size_t)b * 64 + s) * 4 + k) * 64 + c4]);
#pragma unroll
    for (int i = 0; i < 4; ++i) tr[i] = fmaf(a16[i], tr[i], fmaf(g[i], p[i], dk[i]));
  }
  const float* xb = x + ((size_t)b * Ln + s * 64 + sub * 16) * Cn + c4;
  bf16x8 vs[4][2], vt[4][2];
#pragma unroll
  for (int j = 0; j < 16; ++j) {
    f32x4 v = *reinterpret_cast<const f32x4*>(xb + (size_t)j * Cn);
#pragma unroll
    for (int i = 0; i < 4; ++i) {
      float xn = fmaf(g[i], v[i], d[i]);
      tr[i] = fmaf(a[i], tr[i], k1[i] * xn);
      vs[i][j >> 3][j & 7] = f2bf(xn - tr[i]);
      vt[i][j >> 3][j & 7] = f2bf(tr[i]);
    }
  }
#pragma unroll
  for (int i = 0; i < 4; ++i) {
    int c = c4 + i;
    bf16_t* zs = Zt + ((size_t)b * 64 + c) * Ln + s * 64 + sub * 16;
    bf16_t* zt = zs + (size_t)Bn * Cn * Ln;
    *reinterpret_cast<bf16x8*>(zs) = vs[i][0];
    *reinterpret_cast<bf16x8*>(zs + 8) = vs[i][1];
    *reinterpret_cast<bf16x8*>(zt) = vt[i][0];
    *reinterpret_cast<bf16x8*>(zt + 8) = vt[i][1];
  }
}

// ---------------- kernel 5: bf16 MFMA GEMM ----------------
// 128x128 tile, 4 waves (2x2). A-operand: fragment-major from GLOBAL (coalesced lane*16B,
// L1/L2-served, register double-buffered) -- no LDS for A. B-operand: swizzled triple-buffered
// LDS (24KB), counted vmcnt (B(t+1)=2 + aload(t)=4 -> vmcnt(6) steady, 4 at tail).
__device__ __forceinline__ void gload16(const bf16_t* g, bf16_t* l) {
  __builtin_amdgcn_global_load_lds((const AS_GLOBAL uint32_t*)g, (AS_LDS uint32_t*)l, 16, 0, 0);
}

template <int KS>
__global__ void __launch_bounds__(256, 3) k_gemm(const bf16_t* __restrict__ Wt, const bf16_t* __restrict__ Zt,
                                                 float* __restrict__ Osr) {
  int z = blockIdx.z;
  int p = z / KS, kq = z % KS;
  const short* AF = (const short*)Wt + (size_t)p * HPn * Ln;  // fragment-major A
  const bf16_t* Bz = Zt + (size_t)p * (Bn * Cn) * Ln;         // [2048][4096]
  int h0 = blockIdx.y * 128, n0 = blockIdx.x * 128;
  int kbase = kq * (Ln / KS);
  const int NT = (Ln / KS) / 32;                      // K-steps of 32
  __shared__ __align__(16) bf16_t Bl[3][128 * 32];
  int tid = threadIdx.x, wid = tid >> 6, lane = tid & 63;
  int wr = wid >> 1, wc = wid & 1;
  int fr = lane & 15, hi = lane >> 4;
  int kc = (tid & 3) ^ ((tid >> 3) & 3);              // source k-chunk (inverse swizzle)
  const bf16_t* bbase = Bz + (size_t)(n0 + (tid >> 2)) * Ln + kbase + kc * 8;
  // A fragment base: unit (ht, ktg, lane); ht = h0/16 + wr*4 + i
  const short* abase = AF + ((((size_t)(h0 >> 4) + wr * 4) * 128 + (kbase >> 5)) << 9) + ((size_t)lane << 3);

  f32x4 acc[4][4];
#pragma unroll
  for (int i = 0; i < 4; ++i)
#pragma unroll
    for (int j = 0; j < 4; ++j) acc[i][j] = (f32x4){0.f, 0.f, 0.f, 0.f};

  auto STAGE_B = [&](int bufi, int kt) {
    gload16(bbase + (size_t)kt * 32, &Bl[bufi][tid * 8]);
    gload16(bbase + (size_t)64 * Ln + kt * 32, &Bl[bufi][2048 + tid * 8]);
  };
  auto ALOAD = [&](bf16x8 (&dst)[4], int kt) {
#pragma unroll
    for (int i = 0; i < 4; ++i)
      dst[i] = *reinterpret_cast<const bf16x8*>(abase + (((size_t)i * 128 + kt) << 9));
  };

  int sw8 = (hi ^ ((fr >> 1) & 3)) * 8;               // swizzled chunk position (elements)
  auto COMPUTE = [&](int bufi, const bf16x8 (&af)[4]) {
    bf16x8 bfr[4];
#pragma unroll
    for (int j = 0; j < 4; ++j)
      bfr[j] = *reinterpret_cast<const bf16x8*>(&Bl[bufi][(wc * 64 + j * 16 + fr) * 32 + sw8]);
    __builtin_amdgcn_s_setprio(1);
#pragma unroll
    for (int i = 0; i < 4; ++i)
#pragma unroll
      for (int j = 0; j < 4; ++j)
        acc[i][j] = __builtin_amdgcn_mfma_f32_16x16x32_bf16(af[i], bfr[j], acc[i][j], 0, 0, 0);
    __builtin_amdgcn_s_setprio(0);
  };

  bf16x8 aA[4], aB[4];
  STAGE_B(0, 0);
  STAGE_B(1, 1);
  ALOAD(aA, 0);

  auto ITER = [&](int t, int cur, int nx, const bf16x8 (&acur)[4], bf16x8 (&anxt)[4]) {
    __builtin_amdgcn_sched_barrier(0);
    if (t + 1 < NT) { asm volatile("s_waitcnt vmcnt(6)" ::: "memory"); }   // B(t) landed
    else            { asm volatile("s_waitcnt vmcnt(4)" ::: "memory"); }
    __builtin_amdgcn_s_barrier();
    __builtin_amdgcn_sched_barrier(0);
    if (t + 2 < NT) STAGE_B(nx, t + 2);
    if (t + 1 < NT) ALOAD(anxt, t + 1);
    COMPUTE(cur, acur);
  };

  int cur = 0;
  for (int t = 0; t < NT; t += 2) {
    int c1 = (cur == 2) ? 0 : cur + 1;
    int nx0 = (c1 == 2) ? 0 : c1 + 1;        // (t+2)%3
    int nx1 = cur;                           // (t+3)%3
    ITER(t,     cur, nx0, aA, aB);
    ITER(t + 1, c1,  nx1, aB, aA);
    cur = nx0;
  }

#pragma unroll
  for (int i = 0; i < 4; ++i) {
#pragma unroll
    for (int j = 0; j < 4; ++j) {
#pragma unroll
      for (int r = 0; r < 4; ++r) {
        int m = wr * 64 + i * 16 + hi * 4 + r;
        int h = h0 + m;
        if (h < Hn) {
          int n = n0 + wc * 64 + j * 16 + fr;
          int bidx = n >> 6, c = n & 63;
          Osr[(((size_t)z * Bn + bidx) * Hn + h) * Cn + c] = acc[i][j][r];
        }
      }
    }
  }
}

// ---------------- kernel 6: epilogue — sum K-slices, apply M, biases, inverse RevIN ----------------
template <int KS>
__global__ void __launch_bounds__(256) k_epi(const float* __restrict__ Osr, const float* __restrict__ M,
                                             const float* __restrict__ cvec, const float* __restrict__ S,
                                             const float* __restrict__ st_b, const float* __restrict__ tt_b,
                                             const float* __restrict__ rev_w, const float* __restrict__ rev_b,
                                             const float* __restrict__ mean, const float* __restrict__ stdv,
                                             float* __restrict__ out) {
  __shared__ float Msh[2][64][64];    // 32 KB
  __shared__ float rowS[4][64];
  __shared__ float rowT[4][64];
  int t = threadIdx.x;
  for (int i = t; i < 8192; i += 256) ((float*)Msh)[i] = M[i];
  int g = t >> 6, c = t & 63;
  float w = rev_w[c], rb = rev_b[c];
  float cs = cvec[c], ct = cvec[64 + c];
  int base = blockIdx.x * 16;
  for (int it = 0; it < 4; ++it) {
    int r = base + it * 4 + g;        // r = b*720 + h
    int b = r / 720, h = r % 720;
    __syncthreads();                  // also covers Msh load at it=0
    float vs = 0.f, vt = 0.f;
#pragma unroll
    for (int kq = 0; kq < KS; ++kq) {
      vs += Osr[(((size_t)kq * Bn + b) * Hn + h) * Cn + c];
      vt += Osr[(((size_t)(KS + kq) * Bn + b) * Hn + h) * Cn + c];
    }
    rowS[g][c] = vs;
    rowT[g][c] = vt;
    __syncthreads();
    float acc = cs * S[h] + ct * S[768 + h] + st_b[h] + tt_b[h];
    for (int cp = 0; cp < 64; ++cp)
      acc = fmaf(rowS[g][cp], Msh[0][cp][c], fmaf(rowT[g][cp], Msh[1][cp][c], acc));
    float o = (acc - rb) / (w + EPSf) * stdv[b * Cn + c] + mean[b * Cn + c];
    out[(size_t)r * 64 + c] = o;
  }
}

// ---------------- launch ----------------
extern "C" void kernel_launch(void* const* d_in, const int* in_sizes, int n_in,
                              void* d_out, int out_size, void* d_ws, size_t ws_size,
                              hipStream_t stream) {
  const float* x     = (const float*)d_in[0];
  const float* alpha = (const float*)d_in[1];
  const float* rev_w = (const float*)d_in[2];
  const float* rev_b = (const float*)d_in[3];
  const float* se_w  = (const float*)d_in[4];
  const float* se_b  = (const float*)d_in[5];
  const float* sp_w  = (const float*)d_in[6];
  const float* sp_b  = (const float*)d_in[7];
  const float* st_w  = (const float*)d_in[8];
  const float* st_b  = (const float*)d_in[9];
  const float* te_w  = (const float*)d_in[10];
  const float* te_b  = (const float*)d_in[11];
  const float* tp_w  = (const float*)d_in[12];
  const float* tp_b  = (const float*)d_in[13];
  const float* tt_w  = (const float*)d_in[14];
  const float* tt_b  = (const float*)d_in[15];
  float* out = (float*)d_out;

  const size_t SZ_WT  = (size_t)2 * HPn * Ln * 2;          // 12.58 MB (fragment-major AF)
  const size_t SZ_ZT  = (size_t)2 * Bn * Cn * Ln * 2;      // 33.55 MB
  const size_t SZ_SEG = (size_t)Bn * 64 * 64 * 4;          // 0.5 MB seg-level scratch
  const size_t SZ_M   = 2 * 64 * 64 * 4;                   // 32 KB
  const size_t SZ_CV  = 2 * 64 * 4;
  const size_t SZ_S   = 2 * 768 * 4;
  const size_t TAIL   = SZ_M + SZ_CV + SZ_S + 3 * (size_t)Bn * Cn * 4;

  // KS=4 needs 8 Osr slices; KS=1 needs 2 (scan scratch: 2MB Psub + 4x0.5MB fits either way).
  const size_t NEED4 = SZ_WT + SZ_ZT + 8 * OSR_SLICE * 4 + TAIL;
  const int KS = (ws_size >= NEED4) ? 4 : 1;
  const size_t SZ_OSR = (size_t)(2 * KS) * OSR_SLICE * 4;

  char* ws = (char*)d_ws;
  bf16_t* Wt   = (bf16_t*)(ws);
  bf16_t* Zt   = (bf16_t*)(ws + SZ_WT);
  float*  Osr  = (float*)(ws + SZ_WT + SZ_ZT);
  // scan scratch aliases Osr (dead before k_gemm writes Osr)
  float*  Psub  = Osr;                                     // 2 MB
  float*  Pseg  = (float*)((char*)Psub + 4 * SZ_SEG);
  float*  Ssum  = (float*)((char*)Pseg + SZ_SEG);
  float*  Ssq   = (float*)((char*)Ssum + SZ_SEG);
  float*  Carry = (float*)((char*)Ssq + SZ_SEG);
  char* tail = ws + SZ_WT + SZ_ZT + SZ_OSR;
  float* Mbuf = (float*)tail;                 tail += SZ_M;
  float* cvec = (float*)tail;                 tail += SZ_CV;
  float* S    = (float*)tail;                 tail += SZ_S;
  float* mean = (float*)tail;                 tail += (size_t)Bn * Cn * 4;
  float* rstd = (float*)tail;                 tail += (size_t)Bn * Cn * 4;
  float* stdv = (float*)tail;

  // zero M | cvec | S (contiguous) for the atomicAdd accumulations
  hipMemsetAsync(Mbuf, 0, SZ_M + SZ_CV + SZ_S, stream);

  k_prep<<<dim3(8, 2), 256, 0, stream>>>(se_w, sp_w, se_b, sp_b, te_w, tp_w, te_b, tp_b, Mbuf, cvec);
  k_wprep<<<dim3(64, 12, 2), 256, 0, stream>>>(st_w, tt_w, Wt, S);
  k_scanA<<<dim3(32, 16), dim3(64, 4), 0, stream>>>(x, alpha, Psub, Pseg, Ssum, Ssq);
  k_scanB<<<32, 64, 0, stream>>>(x, alpha, rev_w, rev_b, Pseg, Ssum, Ssq, mean, rstd, stdv, Carry);
  k_scanC<<<dim3(32, 16), dim3(64, 4), 0, stream>>>(x, alpha, rev_w, rev_b, mean, rstd, Carry, Psub, Zt);
  if (KS == 4) {
    k_gemm<4><<<dim3(16, 6, 8), 256, 0, stream>>>(Wt, Zt, Osr);
    k_epi<4><<<1440, 256, 0, stream>>>(Osr, Mbuf, cvec, S, st_b, tt_b, rev_w, rev_b, mean, stdv, out);
  } else {
    k_gemm<1><<<dim3(16, 6, 2), 256, 0, stream>>>(Wt, Zt, Osr);
    k_epi<1><<<1440, 256, 0, stream>>>(Osr, Mbuf, cvec, S, st_b, tt_b, rev_w, rev_b, mean, stdv, out);
  }
}

// Round 9
// 108.084 us; speedup vs baseline: 7.1651x; 1.0692x over previous
//
#include <hip/hip_runtime.h>
#include <hip/hip_bf16.h>
#include <string.h>
#include <stdint.h>

typedef __hip_bfloat16 bf16_t;
typedef float f32x4 __attribute__((ext_vector_type(4)));
typedef short bf16x8 __attribute__((ext_vector_type(8)));

#define AS_GLOBAL __attribute__((address_space(1)))
#define AS_LDS    __attribute__((address_space(3)))

static constexpr int Bn = 32, Ln = 4096, Cn = 64, Hn = 720, HPn = 768;
static constexpr float EPSf = 1e-5f;

static constexpr size_t OSR_SLICE = (size_t)Bn * Hn * Cn;   // f32 elements per K-slice per path

__device__ __forceinline__ short f2bf(float f) {
  bf16_t h = __float2bfloat16(f);
  unsigned short u; memcpy(&u, &h, 2);
  return (short)u;
}

__device__ __forceinline__ float sigm(float v) { return 1.f / (1.f + expf(-v)); }

// ---------------- kernel 1: fold the two 64->512->64 MLPs (d-chunked, LDS-tiled) ----------------
__global__ void __launch_bounds__(256) k_prep(const float* __restrict__ se_w, const float* __restrict__ sp_w,
                                              const float* __restrict__ se_b, const float* __restrict__ sp_b,
                                              const float* __restrict__ te_w, const float* __restrict__ tp_w,
                                              const float* __restrict__ te_b, const float* __restrict__ tp_b,
                                              float* __restrict__ M, float* __restrict__ cvec) {
  int p = blockIdx.y, dc = blockIdx.x, t = threadIdx.x;
  const float* ew = p ? te_w : se_w;   // (64,512)
  const float* pw = p ? tp_w : sp_w;   // (512,64)
  const float* eb = p ? te_b : se_b;   // (512,)
  const float* pb = p ? tp_b : sp_b;   // (64,)
  int d0 = dc * 64;
  __shared__ float ews[64][68];        // [row r][dd]
  __shared__ float pws[64][68];        // [dd][c]
  __shared__ float ebs[64];
#pragma unroll
  for (int q = 0; q < 4; ++q) {        // stage: 4 float4 per thread per array (coalesced)
    int fi = t * 4 + q;
    int r = fi >> 4, dd = (fi * 4) & 63;
    *reinterpret_cast<f32x4*>(&ews[r][dd]) = *reinterpret_cast<const f32x4*>(&ew[r * 512 + d0 + dd]);
    int pdd = fi >> 4, c = (fi * 4) & 63;
    *reinterpret_cast<f32x4*>(&pws[pdd][c]) = *reinterpret_cast<const f32x4*>(&pw[(d0 + pdd) * 64 + c]);
  }
  if (t < 64) ebs[t] = eb[d0 + t];
  __syncthreads();
  int r0 = (t >> 4) * 4, c0 = (t & 15) * 4;
  float acc[4][4];
#pragma unroll
  for (int i = 0; i < 4; ++i)
#pragma unroll
    for (int j = 0; j < 4; ++j) acc[i][j] = 0.f;
#pragma unroll 4
  for (int g = 0; g < 16; ++g) {
    int dd = g * 4;
    f32x4 av[4], bv[4];
#pragma unroll
    for (int i = 0; i < 4; ++i) av[i] = *reinterpret_cast<const f32x4*>(&ews[r0 + i][dd]);
#pragma unroll
    for (int d = 0; d < 4; ++d) bv[d] = *reinterpret_cast<const f32x4*>(&pws[dd + d][c0]);
#pragma unroll
    for (int d = 0; d < 4; ++d)
#pragma unroll
      for (int i = 0; i < 4; ++i)
#pragma unroll
        for (int j = 0; j < 4; ++j) acc[i][j] = fmaf(av[i][d], bv[d][j], acc[i][j]);
  }
#pragma unroll
  for (int i = 0; i < 4; ++i)
#pragma unroll
    for (int j = 0; j < 4; ++j)
      atomicAdd(&M[p * 4096 + (r0 + i) * 64 + c0 + j], acc[i][j]);
  if (t < 64) {
    float s = (dc == 0) ? pb[t] : 0.f;
#pragma unroll 8
    for (int dd = 0; dd < 64; ++dd) s = fmaf(ebs[dd], pws[dd][t], s);
    atomicAdd(&cvec[p * 64 + t], s);
  }
}

// ---------------- kernel 2: tw -> FRAGMENT-MAJOR AF[p][ht][kt][lane]x8 bf16 (+colsum) ----------
__global__ void k_wprep(const float* __restrict__ st_w, const float* __restrict__ tt_w,
                        bf16_t* __restrict__ Wt, float* __restrict__ S) {
  int p = blockIdx.z;
  const float* W = p ? tt_w : st_w;          // (4096, 720)
  int l0 = blockIdx.x * 64, h0 = blockIdx.y * 64;
  __shared__ float tile[64][65];             // [l-local][h-local]
  int row = threadIdx.x >> 6, col = threadIdx.x & 63;
  int h = h0 + col;
  float partial = 0.f;
  for (int r = row; r < 64; r += 4) {
    float v = (h < Hn) ? W[(size_t)(l0 + r) * Hn + h] : 0.f;
    tile[r][col] = v;
    partial += v;
  }
  if (h < Hn) atomicAdd(&S[p * 768 + h], partial);
  __syncthreads();
  short* AF = (short*)Wt + (size_t)p * HPn * Ln;   // 48*128*64*8 shorts per path
#pragma unroll
  for (int u = 0; u < 2; ++u) {
    int uid = u * 256 + threadIdx.x;         // 0..511
    int ln = uid & 63, ktl = (uid >> 6) & 1, htl = uid >> 7;
    int fr = ln & 15, hi = ln >> 4;
    int ll = ktl * 32 + hi * 8;              // l-local base
    int hh = htl * 16 + fr;                  // h-local
    bf16x8 v;
#pragma unroll
    for (int e = 0; e < 8; ++e) v[e] = f2bf(tile[ll + e][hh]);
    size_t ht = (size_t)(h0 >> 4) + htl, ktg = (size_t)(l0 >> 5) + ktl;
    *reinterpret_cast<bf16x8*>(&AF[((ht * 128 + ktg) << 9) + ((size_t)ln << 3)]) = v;
  }
}

// ---------------- kernel 3a: 4-wave blocks, (c-quad x l-sub16) raw-x partials + seg reduce ------
__global__ void __launch_bounds__(256) k_scanA(const float* __restrict__ x, const float* __restrict__ alpha,
                                               float* __restrict__ Psub, float* __restrict__ Pseg,
                                               float* __restrict__ Ssum, float* __restrict__ Ssq) {
  int b = blockIdx.x, q = threadIdx.y, s = blockIdx.y * 4 + q, t = threadIdx.x;
  int c4 = (t & 15) * 4, sub = t >> 4;
  float a[4], k1[4];
#pragma unroll
  for (int i = 0; i < 4; ++i) { a[i] = sigm(alpha[c4 + i]); k1[i] = 1.f - a[i]; }
  const float* xb = x + ((size_t)b * Ln + s * 64 + sub * 16) * Cn + c4;
  float pr[4] = {0.f, 0.f, 0.f, 0.f}, sm[4] = {0.f, 0.f, 0.f, 0.f}, sq[4] = {0.f, 0.f, 0.f, 0.f};
#pragma unroll
  for (int j = 0; j < 16; ++j) {
    f32x4 v = *reinterpret_cast<const f32x4*>(xb + (size_t)j * Cn);
#pragma unroll
    for (int i = 0; i < 4; ++i) {
      sm[i] += v[i];
      sq[i] = fmaf(v[i], v[i], sq[i]);
      pr[i] = fmaf(a[i], pr[i], k1[i] * v[i]);
    }
  }
  *reinterpret_cast<f32x4*>(&Psub[(((size_t)b * 64 + s) * 4 + sub) * 64 + c4]) =
      (f32x4){pr[0], pr[1], pr[2], pr[3]};
  __shared__ float lp[4][4][64], ls[4][4][64], lq[4][4][64];   // [wave q][sub][c]
#pragma unroll
  for (int i = 0; i < 4; ++i) { lp[q][sub][c4 + i] = pr[i]; ls[q][sub][c4 + i] = sm[i]; lq[q][sub][c4 + i] = sq[i]; }
  __syncthreads();
  int c = t;
  float av = sigm(alpha[c]);
  float a16 = av * av; a16 *= a16; a16 *= a16; a16 *= a16;   // a^16
  float P = ((lp[q][0][c] * a16 + lp[q][1][c]) * a16 + lp[q][2][c]) * a16 + lp[q][3][c];
  int idx = (b * 64 + s) * 64 + c;
  Pseg[idx] = P;
  Ssum[idx] = ls[q][0][c] + ls[q][1][c] + ls[q][2][c] + ls[q][3][c];
  Ssq[idx]  = lq[q][0][c] + lq[q][1][c] + lq[q][2][c] + lq[q][3][c];
}

// ---------------- kernel 3b: stats finalize + 64-step carry scan ----------------
__global__ void __launch_bounds__(64) k_scanB(const float* __restrict__ x, const float* __restrict__ alpha,
                                              const float* __restrict__ rev_w, const float* __restrict__ rev_b,
                                              const float* __restrict__ Pseg, const float* __restrict__ Ssum,
                                              const float* __restrict__ Ssq,
                                              float* __restrict__ mean, float* __restrict__ rstd,
                                              float* __restrict__ stdv, float* __restrict__ CarryIn) {
  int b = blockIdx.x, c = threadIdx.x;
  float sm = 0.f, sq = 0.f;
#pragma unroll 8
  for (int s = 0; s < 64; ++s) {
    int idx = (b * 64 + s) * 64 + c;
    sm += Ssum[idx]; sq += Ssq[idx];
  }
  float mn = sm * (1.f / 4096.f);
  float var = sq * (1.f / 4096.f) - mn * mn;
  float sd = sqrtf(var + EPSf);
  float rs = 1.f / sd;
  mean[b * 64 + c] = mn; stdv[b * 64 + c] = sd; rstd[b * 64 + c] = rs;

  float w = rev_w[c], rb = rev_b[c];
  float g = rs * w, d = rb - mn * g;         // xn = g*x + d
  float a = sigm(alpha[c]);
  float a2 = a * a, a4 = a2 * a2, a8 = a4 * a4, a16 = a8 * a8, a32 = a16 * a16;
  float a64 = a32 * a32;
  float dk1s = d * (1.f - a64);               // d * sum of (1-a)*a^k
  float carry = fmaf(g, x[((size_t)b * Ln) * Cn + c], d);   // xn[0]
  for (int so = 0; so < 8; ++so) {
    float pv[8];
#pragma unroll
    for (int i = 0; i < 8; ++i)
      pv[i] = Pseg[((size_t)(b * 64 + so * 8 + i)) * 64 + c];   // batched, independent loads
#pragma unroll
    for (int i = 0; i < 8; ++i) {
      CarryIn[((size_t)(b * 64 + so * 8 + i)) * 64 + c] = carry;
      carry = fmaf(a64, carry, fmaf(g, pv[i], dk1s));
    }
  }
}

// ---------------- kernel 3c: 4-wave blocks, apply scan, write transposed bf16 ----------------
__global__ void __launch_bounds__(256) k_scanC(const float* __restrict__ x, const float* __restrict__ alpha,
                                               const float* __restrict__ rev_w, const float* __restrict__ rev_b,
                                               const float* __restrict__ mean, const float* __restrict__ rstd,
                                               const float* __restrict__ CarryIn, const float* __restrict__ Psub,
                                               bf16_t* __restrict__ Zt) {
  int b = blockIdx.x, s = blockIdx.y * 4 + threadIdx.y, t = threadIdx.x;
  int c4 = (t & 15) * 4, sub = t >> 4;
  float g[4], d[4], a[4], k1[4], a16[4], dk[4], tr[4];
#pragma unroll
  for (int i = 0; i < 4; ++i) {
    int c = c4 + i;
    float rs = rstd[b * 64 + c];
    g[i] = rs * rev_w[c]; d[i] = rev_b[c] - mean[b * 64 + c] * g[i];
    a[i] = sigm(alpha[c]); k1[i] = 1.f - a[i];
    float v = a[i] * a[i]; v *= v; v *= v; v *= v;
    a16[i] = v;
    dk[i] = d[i] * (1.f - v);
  }
  f32x4 cs = *reinterpret_cast<const f32x4*>(&CarryIn[((size_t)b * 64 + s) * 64 + c4]);
#pragma unroll
  for (int i = 0; i < 4; ++i) tr[i] = cs[i];
  for (int k = 0; k < sub; ++k) {            // compose prior subs (<=3 iters, masked)
    f32x4 p = *reinterpret_cast<const f32x4*>(&Psub[(((size_t)b * 64 + s) * 4 + k) * 64 + c4]);
#pragma unroll
    for (int i = 0; i < 4; ++i) tr[i] = fmaf(a16[i], tr[i], fmaf(g[i], p[i], dk[i]));
  }
  const float* xb = x + ((size_t)b * Ln + s * 64 + sub * 16) * Cn + c4;
  bf16x8 vs[4][2], vt[4][2];
#pragma unroll
  for (int j = 0; j < 16; ++j) {
    f32x4 v = *reinterpret_cast<const f32x4*>(xb + (size_t)j * Cn);
#pragma unroll
    for (int i = 0; i < 4; ++i) {
      float xn = fmaf(g[i], v[i], d[i]);
      tr[i] = fmaf(a[i], tr[i], k1[i] * xn);
      vs[i][j >> 3][j & 7] = f2bf(xn - tr[i]);
      vt[i][j >> 3][j & 7] = f2bf(tr[i]);
    }
  }
#pragma unroll
  for (int i = 0; i < 4; ++i) {
    int c = c4 + i;
    bf16_t* zs = Zt + ((size_t)b * 64 + c) * Ln + s * 64 + sub * 16;
    bf16_t* zt = zs + (size_t)Bn * Cn * Ln;
    *reinterpret_cast<bf16x8*>(zs) = vs[i][0];
    *reinterpret_cast<bf16x8*>(zs + 8) = vs[i][1];
    *reinterpret_cast<bf16x8*>(zt) = vt[i][0];
    *reinterpret_cast<bf16x8*>(zt + 8) = vt[i][1];
  }
}

// ---------------- kernel 5: bf16 MFMA GEMM ----------------
// 128x128 tile, 4 waves (2x2). A: fragment-major from GLOBAL (reg double-buffered, no LDS);
// B: swizzled triple-buffered LDS (24KB); counted vmcnt(6)/(4). 1D grid with XCD-chunked
// swizzle: each XCD gets one contiguous z-slice -> A/B panel re-reads hit the same L2.
__device__ __forceinline__ void gload16(const bf16_t* g, bf16_t* l) {
  __builtin_amdgcn_global_load_lds((const AS_GLOBAL uint32_t*)g, (AS_LDS uint32_t*)l, 16, 0, 0);
}

template <int KS>
__global__ void __launch_bounds__(256, 3) k_gemm(const bf16_t* __restrict__ Wt, const bf16_t* __restrict__ Zt,
                                                 float* __restrict__ Osr) {
  // XCD-chunked bijective swizzle (gridDim.x % 8 == 0): XCD k owns swz range [k*per, (k+1)*per)
  int per = gridDim.x >> 3;
  int swz = (blockIdx.x & 7) * per + (blockIdx.x >> 3);
  int z = swz / 96, rem = swz % 96;                   // 96 = 16 x-blocks * 6 y-blocks
  int by = rem >> 4, bx = rem & 15;
  int p = z / KS, kq = z % KS;
  const short* AF = (const short*)Wt + (size_t)p * HPn * Ln;  // fragment-major A
  const bf16_t* Bz = Zt + (size_t)p * (Bn * Cn) * Ln;         // [2048][4096]
  int h0 = by * 128, n0 = bx * 128;
  int kbase = kq * (Ln / KS);
  const int NT = (Ln / KS) / 32;                      // K-steps of 32
  __shared__ __align__(16) bf16_t Bl[3][128 * 32];
  int tid = threadIdx.x, wid = tid >> 6, lane = tid & 63;
  int wr = wid >> 1, wc = wid & 1;
  int fr = lane & 15, hi = lane >> 4;
  int kc = (tid & 3) ^ ((tid >> 3) & 3);              // source k-chunk (inverse swizzle)
  const bf16_t* bbase = Bz + (size_t)(n0 + (tid >> 2)) * Ln + kbase + kc * 8;
  const short* abase = AF + ((((size_t)(h0 >> 4) + wr * 4) * 128 + (kbase >> 5)) << 9) + ((size_t)lane << 3);

  f32x4 acc[4][4];
#pragma unroll
  for (int i = 0; i < 4; ++i)
#pragma unroll
    for (int j = 0; j < 4; ++j) acc[i][j] = (f32x4){0.f, 0.f, 0.f, 0.f};

  auto STAGE_B = [&](int bufi, int kt) {
    gload16(bbase + (size_t)kt * 32, &Bl[bufi][tid * 8]);
    gload16(bbase + (size_t)64 * Ln + kt * 32, &Bl[bufi][2048 + tid * 8]);
  };
  auto ALOAD = [&](bf16x8 (&dst)[4], int kt) {
#pragma unroll
    for (int i = 0; i < 4; ++i)
      dst[i] = *reinterpret_cast<const bf16x8*>(abase + (((size_t)i * 128 + kt) << 9));
  };

  int sw8 = (hi ^ ((fr >> 1) & 3)) * 8;               // swizzled chunk position (elements)
  auto COMPUTE = [&](int bufi, const bf16x8 (&af)[4]) {
    bf16x8 bfr[4];
#pragma unroll
    for (int j = 0; j < 4; ++j)
      bfr[j] = *reinterpret_cast<const bf16x8*>(&Bl[bufi][(wc * 64 + j * 16 + fr) * 32 + sw8]);
    __builtin_amdgcn_s_setprio(1);
#pragma unroll
    for (int i = 0; i < 4; ++i)
#pragma unroll
      for (int j = 0; j < 4; ++j)
        acc[i][j] = __builtin_amdgcn_mfma_f32_16x16x32_bf16(af[i], bfr[j], acc[i][j], 0, 0, 0);
    __builtin_amdgcn_s_setprio(0);
  };

  bf16x8 aA[4], aB[4];
  STAGE_B(0, 0);
  STAGE_B(1, 1);
  ALOAD(aA, 0);

  auto ITER = [&](int t, int cur, int nx, const bf16x8 (&acur)[4], bf16x8 (&anxt)[4]) {
    __builtin_amdgcn_sched_barrier(0);
    if (t + 1 < NT) { asm volatile("s_waitcnt vmcnt(6)" ::: "memory"); }   // B(t) landed
    else            { asm volatile("s_waitcnt vmcnt(4)" ::: "memory"); }
    __builtin_amdgcn_s_barrier();
    __builtin_amdgcn_sched_barrier(0);
    if (t + 2 < NT) STAGE_B(nx, t + 2);
    if (t + 1 < NT) ALOAD(anxt, t + 1);
    COMPUTE(cur, acur);
  };

  int cur = 0;
  for (int t = 0; t < NT; t += 2) {
    int c1 = (cur == 2) ? 0 : cur + 1;
    int nx0 = (c1 == 2) ? 0 : c1 + 1;        // (t+2)%3
    int nx1 = cur;                           // (t+3)%3
    ITER(t,     cur, nx0, aA, aB);
    ITER(t + 1, c1,  nx1, aB, aA);
    cur = nx0;
  }

#pragma unroll
  for (int i = 0; i < 4; ++i) {
#pragma unroll
    for (int j = 0; j < 4; ++j) {
#pragma unroll
      for (int r = 0; r < 4; ++r) {
        int m = wr * 64 + i * 16 + hi * 4 + r;
        int h = h0 + m;
        if (h < Hn) {
          int n = n0 + wc * 64 + j * 16 + fr;
          int bidx = n >> 6, c = n & 63;
          Osr[(((size_t)z * Bn + bidx) * Hn + h) * Cn + c] = acc[i][j][r];
        }
      }
    }
  }
}

// ---------------- kernel 6: epilogue — 32 rows/block, 8-row register blocking ----------------
// Per cp: 2 M-reads shared across 8 outputs (vs 2 per output before) -> ~2x fewer LDS instrs.
// fma order identical to previous rounds -> bit-identical output.
template <int KS>
__global__ void __launch_bounds__(256) k_epi(const float* __restrict__ Osr, const float* __restrict__ M,
                                             const float* __restrict__ cvec, const float* __restrict__ S,
                                             const float* __restrict__ st_b, const float* __restrict__ tt_b,
                                             const float* __restrict__ rev_w, const float* __restrict__ rev_b,
                                             const float* __restrict__ mean, const float* __restrict__ stdv,
                                             float* __restrict__ out) {
  __shared__ float Msh[2][64][64];    // 32 KB
  __shared__ float rowS[32][64];      // 8 KB
  __shared__ float rowT[32][64];      // 8 KB
  int t = threadIdx.x;
  for (int i = t; i < 8192; i += 256) ((float*)Msh)[i] = M[i];
  int c = t & 63, grp = t >> 6;       // grp 0..3, 8 rows each
  float w = rev_w[c], rb = rev_b[c];
  float cs = cvec[c], ct = cvec[64 + c];
  int base = blockIdx.x * 32;
  // stage 32 rows (slice-summed) into LDS
#pragma unroll
  for (int k = 0; k < 8; ++k) {
    int rl = grp * 8 + k;
    int r = base + rl;
    int b = r / 720, h = r % 720;
    float vs = 0.f, vt = 0.f;
#pragma unroll
    for (int kq = 0; kq < KS; ++kq) {
      vs += Osr[(((size_t)kq * Bn + b) * Hn + h) * Cn + c];
      vt += Osr[(((size_t)(KS + kq) * Bn + b) * Hn + h) * Cn + c];
    }
    rowS[rl][c] = vs;
    rowT[rl][c] = vt;
  }
  __syncthreads();
  float acc[8];
  int hh[8], bb[8];
#pragma unroll
  for (int k = 0; k < 8; ++k) {
    int r = base + grp * 8 + k;
    bb[k] = r / 720; hh[k] = r % 720;
    acc[k] = cs * S[hh[k]] + ct * S[768 + hh[k]] + st_b[hh[k]] + tt_b[hh[k]];
  }
  int r0 = grp * 8;
#pragma unroll 4
  for (int cp = 0; cp < 64; ++cp) {
    float m0 = Msh[0][cp][c], m1 = Msh[1][cp][c];
#pragma unroll
    for (int k = 0; k < 8; ++k)
      acc[k] = fmaf(rowS[r0 + k][cp], m0, fmaf(rowT[r0 + k][cp], m1, acc[k]));
  }
  float winv = 1.f / (w + EPSf);
#pragma unroll
  for (int k = 0; k < 8; ++k) {
    float o = (acc[k] - rb) * winv * stdv[bb[k] * Cn + c] + mean[bb[k] * Cn + c];
    out[(size_t)(base + r0 + k) * 64 + c] = o;
  }
}

// ---------------- launch ----------------
extern "C" void kernel_launch(void* const* d_in, const int* in_sizes, int n_in,
                              void* d_out, int out_size, void* d_ws, size_t ws_size,
                              hipStream_t stream) {
  const float* x     = (const float*)d_in[0];
  const float* alpha = (const float*)d_in[1];
  const float* rev_w = (const float*)d_in[2];
  const float* rev_b = (const float*)d_in[3];
  const float* se_w  = (const float*)d_in[4];
  const float* se_b  = (const float*)d_in[5];
  const float* sp_w  = (const float*)d_in[6];
  const float* sp_b  = (const float*)d_in[7];
  const float* st_w  = (const float*)d_in[8];
  const float* st_b  = (const float*)d_in[9];
  const float* te_w  = (const float*)d_in[10];
  const float* te_b  = (const float*)d_in[11];
  const float* tp_w  = (const float*)d_in[12];
  const float* tp_b  = (const float*)d_in[13];
  const float* tt_w  = (const float*)d_in[14];
  const float* tt_b  = (const float*)d_in[15];
  float* out = (float*)d_out;

  const size_t SZ_WT  = (size_t)2 * HPn * Ln * 2;          // 12.58 MB (fragment-major AF)
  const size_t SZ_ZT  = (size_t)2 * Bn * Cn * Ln * 2;      // 33.55 MB
  const size_t SZ_SEG = (size_t)Bn * 64 * 64 * 4;          // 0.5 MB seg-level scratch
  const size_t SZ_M   = 2 * 64 * 64 * 4;                   // 32 KB
  const size_t SZ_CV  = 2 * 64 * 4;
  const size_t SZ_S   = 2 * 768 * 4;
  const size_t TAIL   = SZ_M + SZ_CV + SZ_S + 3 * (size_t)Bn * Cn * 4;

  const size_t NEED4 = SZ_WT + SZ_ZT + 8 * OSR_SLICE * 4 + TAIL;
  const int KS = (ws_size >= NEED4) ? 4 : 1;
  const size_t SZ_OSR = (size_t)(2 * KS) * OSR_SLICE * 4;

  char* ws = (char*)d_ws;
  bf16_t* Wt   = (bf16_t*)(ws);
  bf16_t* Zt   = (bf16_t*)(ws + SZ_WT);
  float*  Osr  = (float*)(ws + SZ_WT + SZ_ZT);
  // scan scratch aliases Osr (dead before k_gemm writes Osr)
  float*  Psub  = Osr;                                     // 2 MB
  float*  Pseg  = (float*)((char*)Psub + 4 * SZ_SEG);
  float*  Ssum  = (float*)((char*)Pseg + SZ_SEG);
  float*  Ssq   = (float*)((char*)Ssum + SZ_SEG);
  float*  Carry = (float*)((char*)Ssq + SZ_SEG);
  char* tail = ws + SZ_WT + SZ_ZT + SZ_OSR;
  float* Mbuf = (float*)tail;                 tail += SZ_M;
  float* cvec = (float*)tail;                 tail += SZ_CV;
  float* S    = (float*)tail;                 tail += SZ_S;
  float* mean = (float*)tail;                 tail += (size_t)Bn * Cn * 4;
  float* rstd = (float*)tail;                 tail += (size_t)Bn * Cn * 4;
  float* stdv = (float*)tail;

  // zero M | cvec | S (contiguous) for the atomicAdd accumulations
  hipMemsetAsync(Mbuf, 0, SZ_M + SZ_CV + SZ_S, stream);

  k_prep<<<dim3(8, 2), 256, 0, stream>>>(se_w, sp_w, se_b, sp_b, te_w, tp_w, te_b, tp_b, Mbuf, cvec);
  k_wprep<<<dim3(64, 12, 2), 256, 0, stream>>>(st_w, tt_w, Wt, S);
  k_scanA<<<dim3(32, 16), dim3(64, 4), 0, stream>>>(x, alpha, Psub, Pseg, Ssum, Ssq);
  k_scanB<<<32, 64, 0, stream>>>(x, alpha, rev_w, rev_b, Pseg, Ssum, Ssq, mean, rstd, stdv, Carry);
  k_scanC<<<dim3(32, 16), dim3(64, 4), 0, stream>>>(x, alpha, rev_w, rev_b, mean, rstd, Carry, Psub, Zt);
  if (KS == 4) {
    k_gemm<4><<<768, 256, 0, stream>>>(Wt, Zt, Osr);
    k_epi<4><<<720, 256, 0, stream>>>(Osr, Mbuf, cvec, S, st_b, tt_b, rev_w, rev_b, mean, stdv, out);
  } else {
    k_gemm<1><<<192, 256, 0, stream>>>(Wt, Zt, Osr);
    k_epi<1><<<720, 256, 0, stream>>>(Osr, Mbuf, cvec, S, st_b, tt_b, rev_w, rev_b, mean, stdv, out);
  }
}